// Round 1
// baseline (797.136 us; speedup 1.0000x reference)
//
#include <hip/hip_runtime.h>
#include <math.h>

#define B_  2
#define L_  1024
#define D_  768
#define NH_ 12
#define HD_ 64
#define K_  24
#define R_  768

// ---------------------------------------------------------------------------
// phi2[j][r] = 2 * sum_k stu_filters[j][k] * M_filters[k][r]   (L x R)
// ---------------------------------------------------------------------------
__global__ __launch_bounds__(256) void k_phi2(const float* __restrict__ F,
                                              const float* __restrict__ Mf,
                                              float* __restrict__ phi2) {
    int idx = blockIdx.x * 256 + threadIdx.x;      // j*R + r
    int r = idx % R_;
    int j = idx / R_;
    float acc = 0.f;
#pragma unroll
    for (int kk = 0; kk < K_; ++kk)
        acc += F[j * K_ + kk] * Mf[kk * R_ + r];
    phi2[idx] = 2.f * acc;
}

// ---------------------------------------------------------------------------
// Generic fp32 GEMM: C[M][N] = A[M][Kd] @ B[Kd][N] (+ bias[N])
// 64x64 block tile, 256 threads, 4x4 per-thread micro-tile, K-step 16.
// M,N,Kd all multiples of 64/16 here.
// ---------------------------------------------------------------------------
__global__ __launch_bounds__(256) void k_gemm(const float* __restrict__ A,
                                              const float* __restrict__ Bm,
                                              const float* __restrict__ bias,
                                              float* __restrict__ C,
                                              int M, int N, int Kd) {
    __shared__ float As[16][65];   // As[k][m]
    __shared__ float Bs[16][65];   // Bs[k][n]
    const int bm = blockIdx.y * 64;
    const int bn = blockIdx.x * 64;
    const int tid = threadIdx.x;
    const int tx = tid & 15, ty = tid >> 4;

    float acc[4][4] = {};

    for (int k0 = 0; k0 < Kd; k0 += 16) {
        {
            const int row = tid >> 4;       // 0..15
            const int kc  = tid & 15;       // 0..15
#pragma unroll
            for (int i = 0; i < 4; ++i)
                As[kc][row + i * 16] =
                    A[(size_t)(bm + row + i * 16) * Kd + k0 + kc];
            const int kr = tid >> 6;        // 0..3
            const int n  = tid & 63;        // 0..63
#pragma unroll
            for (int i = 0; i < 4; ++i)
                Bs[kr + i * 4][n] =
                    Bm[(size_t)(k0 + kr + i * 4) * N + bn + n];
        }
        __syncthreads();
#pragma unroll
        for (int kk = 0; kk < 16; ++kk) {
            float a[4], b[4];
#pragma unroll
            for (int i = 0; i < 4; ++i) a[i] = As[kk][ty * 4 + i];
#pragma unroll
            for (int j = 0; j < 4; ++j) b[j] = Bs[kk][tx * 4 + j];
#pragma unroll
            for (int i = 0; i < 4; ++i)
#pragma unroll
                for (int j = 0; j < 4; ++j)
                    acc[i][j] += a[i] * b[j];
        }
        __syncthreads();
    }

#pragma unroll
    for (int i = 0; i < 4; ++i) {
        const int row = bm + ty * 4 + i;
#pragma unroll
        for (int j = 0; j < 4; ++j) {
            const int col = bn + tx * 4 + j;
            float o = acc[i][j];
            if (bias) o += bias[col];
            C[(size_t)row * N + col] = o;
        }
    }
}

// ---------------------------------------------------------------------------
// Parity-masked causal depthwise conv:
// xt[b,t,r] = sum_{j even, j<=t} phi2[j,r] * u[b,t-j,r]
// ---------------------------------------------------------------------------
__global__ __launch_bounds__(256) void k_conv(const float* __restrict__ u,
                                              const float* __restrict__ phi2,
                                              float* __restrict__ xt) {
    const int idx = blockIdx.x * 256 + threadIdx.x;  // b*L*R + t*R + r
    const int r  = idx % R_;
    const int bt = idx / R_;
    const int t  = bt % L_;
    const float* up = u + idx;       // u[b][t][r], walk back by j*R
    const float* pp = phi2 + r;      // phi2[j][r], walk fwd by j*R
    float acc = 0.f;
    for (int j = 0; j <= t; j += 2)
        acc += pp[j * R_] * up[-(j * R_)];
    xt[idx] = acc;
}

// ---------------------------------------------------------------------------
// Causal linear attention, collapsed form:
// Y[b,h,t,:] = sum_{s<=t} (q[t]·v[s]) * k[s,:]
// One block per (b, h, 64-row t-tile); fp32, flash-style over s-tiles.
// ---------------------------------------------------------------------------
__global__ __launch_bounds__(256) void k_attn(const float* __restrict__ q,
                                              const float* __restrict__ k,
                                              const float* __restrict__ v,
                                              float* __restrict__ y) {
    const int b = blockIdx.z, h = blockIdx.y, t0 = blockIdx.x * 64;
    __shared__ float qs[64][65];
    __shared__ float ks[64][65];
    __shared__ float vs[64][65];   // reused to hold the S tile in phase 2
    const int tid = threadIdx.x;
    const int lrow = tid >> 6;     // 0..3
    const int lcol = tid & 63;     // 0..63
    const size_t baseq = ((size_t)(b * L_ + t0)) * D_ + h * HD_;
#pragma unroll
    for (int i = 0; i < 16; ++i)
        qs[lrow + i * 4][lcol] = q[baseq + (size_t)(lrow + i * 4) * D_ + lcol];

    const int tx = tid & 15, ty = tid >> 4;
    float yacc[4][4] = {};

    for (int s0 = 0; s0 <= t0; s0 += 64) {
        const size_t bases = ((size_t)(b * L_ + s0)) * D_ + h * HD_;
        __syncthreads();   // protect ks/vs from previous-iteration readers (also covers qs on iter 0)
#pragma unroll
        for (int i = 0; i < 16; ++i) {
            ks[lrow + i * 4][lcol] = k[bases + (size_t)(lrow + i * 4) * D_ + lcol];
            vs[lrow + i * 4][lcol] = v[bases + (size_t)(lrow + i * 4) * D_ + lcol];
        }
        __syncthreads();

        // S[i][j] = q[t0+i] · v[s0+j]
        float sacc[4][4] = {};
#pragma unroll 8
        for (int d = 0; d < 64; ++d) {
            float a[4], bb[4];
#pragma unroll
            for (int i = 0; i < 4; ++i) a[i] = qs[ty * 4 + i][d];
#pragma unroll
            for (int j = 0; j < 4; ++j) bb[j] = vs[tx * 4 + j][d];
#pragma unroll
            for (int i = 0; i < 4; ++i)
#pragma unroll
                for (int j = 0; j < 4; ++j)
                    sacc[i][j] += a[i] * bb[j];
        }
        if (s0 == t0) {
            // causal mask within diagonal tile: s > t gets zeroed
#pragma unroll
            for (int i = 0; i < 4; ++i)
#pragma unroll
                for (int j = 0; j < 4; ++j)
                    if (tx * 4 + j > ty * 4 + i) sacc[i][j] = 0.f;
        }
        __syncthreads();           // all lanes done reading vs
        // stash S into the vs buffer
#pragma unroll
        for (int i = 0; i < 4; ++i)
#pragma unroll
            for (int j = 0; j < 4; ++j)
                vs[ty * 4 + i][tx * 4 + j] = sacc[i][j];
        __syncthreads();

        // Y[i][n] += sum_j S[i][j] * k[s0+j][n]
#pragma unroll 8
        for (int j = 0; j < 64; ++j) {
            float s[4], kk[4];
#pragma unroll
            for (int i = 0; i < 4; ++i) s[i] = vs[ty * 4 + i][j];
#pragma unroll
            for (int n = 0; n < 4; ++n) kk[n] = ks[j][tx * 4 + n];
#pragma unroll
            for (int i = 0; i < 4; ++i)
#pragma unroll
                for (int n = 0; n < 4; ++n)
                    yacc[i][n] += s[i] * kk[n];
        }
    }

#pragma unroll
    for (int i = 0; i < 4; ++i)
#pragma unroll
        for (int n = 0; n < 4; ++n)
            y[((size_t)(b * L_ + t0 + ty * 4 + i)) * D_ + h * HD_ + tx * 4 + n] =
                yacc[i][n];
}

// ---------------------------------------------------------------------------
// y = x_tilde + (y_attn - x_tilde) * sigmoid(g)
// ---------------------------------------------------------------------------
__global__ __launch_bounds__(256) void k_gate(const float* __restrict__ xt,
                                              const float* __restrict__ ya,
                                              const float* __restrict__ g,
                                              float* __restrict__ y) {
    const int idx = blockIdx.x * 256 + threadIdx.x;
    const float gv = 1.f / (1.f + expf(-g[idx]));
    const float xv = xt[idx];
    y[idx] = xv + (ya[idx] - xv) * gv;
}

// ---------------------------------------------------------------------------
extern "C" void kernel_launch(void* const* d_in, const int* in_sizes, int n_in,
                              void* d_out, int out_size, void* d_ws, size_t ws_size,
                              hipStream_t stream) {
    const float* x    = (const float*)d_in[0];
    const float* stu  = (const float*)d_in[1];
    const float* Mi   = (const float*)d_in[2];
    const float* Mf   = (const float*)d_in[3];
    const float* wq_w = (const float*)d_in[4];
    const float* wq_b = (const float*)d_in[5];
    const float* wk_w = (const float*)d_in[6];
    const float* wk_b = (const float*)d_in[7];
    const float* wv_w = (const float*)d_in[8];
    const float* wv_b = (const float*)d_in[9];
    const float* wg_w = (const float*)d_in[10];
    const float* wg_b = (const float*)d_in[11];
    const float* wo_w = (const float*)d_in[12];
    const float* wo_b = (const float*)d_in[13];
    float* out = (float*)d_out;

    char* ws = (char*)d_ws;
    const size_t SZ = (size_t)B_ * L_ * R_ * sizeof(float);   // 6 MB
    float* xt   = (float*)(ws);            // x_tilde
    float* bufA = (float*)(ws + SZ);       // u -> q -> y
    float* bufB = (float*)(ws + 2 * SZ);   // phi2 -> k
    float* vv   = (float*)(ws + 3 * SZ);   // v
    float* gg   = (float*)(ws + 4 * SZ);   // gate pre-activation
    float* ya   = (float*)(ws + 5 * SZ);   // y_attn

    const dim3 blk(256);
    const dim3 ggrid(D_ / 64, (B_ * L_) / 64);   // (12, 32)

    // phi2 = 2 * stu @ M_filters   -> bufB
    k_phi2<<<dim3(L_ * R_ / 256), blk, 0, stream>>>(stu, Mf, bufB);
    // u = x @ M_inputs             -> bufA
    k_gemm<<<ggrid, blk, 0, stream>>>(x, Mi, nullptr, bufA, B_ * L_, R_, D_);
    // x_tilde                      -> xt
    k_conv<<<dim3(B_ * L_ * R_ / 256), blk, 0, stream>>>(bufA, bufB, xt);
    // projections (q overwrites u after conv; k overwrites phi2)
    k_gemm<<<ggrid, blk, 0, stream>>>(x, wq_w, wq_b, bufA, B_ * L_, D_, D_);
    k_gemm<<<ggrid, blk, 0, stream>>>(x, wk_w, wk_b, bufB, B_ * L_, D_, D_);
    k_gemm<<<ggrid, blk, 0, stream>>>(x, wv_w, wv_b, vv,   B_ * L_, D_, D_);
    k_gemm<<<ggrid, blk, 0, stream>>>(x, wg_w, wg_b, gg,   B_ * L_, D_, D_);
    // attention                    -> ya
    k_attn<<<dim3(L_ / 64, NH_, B_), blk, 0, stream>>>(bufA, bufB, vv, ya);
    // gated combine                -> bufA (q is dead now)
    k_gate<<<dim3(B_ * L_ * D_ / 256), blk, 0, stream>>>(xt, ya, gg, bufA);
    // output projection            -> d_out
    k_gemm<<<ggrid, blk, 0, stream>>>(bufA, wo_w, wo_b, out, B_ * L_, D_, D_);
}

// Round 2
// 344.674 us; speedup vs baseline: 2.3127x; 2.3127x over previous
//
#include <hip/hip_runtime.h>
#include <math.h>

#define B_  2
#define L_  1024
#define D_  768
#define NH_ 12
#define HD_ 64
#define K_  24
#define R_  768
#define NC_ 16   // chunks
#define CS_ 64   // chunk size

typedef __bf16 bf16x8 __attribute__((ext_vector_type(8)));
typedef float f32x4 __attribute__((ext_vector_type(4)));
typedef unsigned short u16x8 __attribute__((ext_vector_type(8)));

__device__ inline unsigned short f2bf(float f) {
    union { float f; unsigned u; } v; v.f = f;
    unsigned r = v.u + 0x7FFFu + ((v.u >> 16) & 1u);
    return (unsigned short)(r >> 16);
}

// ---------------------------------------------------------------------------
// Transpose + convert weight: Wt[n][k] (bf16) = W[k][n] (fp32). 768x768.
// ---------------------------------------------------------------------------
__global__ __launch_bounds__(256) void k_wt(const float* __restrict__ W,
                                            unsigned short* __restrict__ Wt) {
    __shared__ float t[64][65];
    const int n0 = blockIdx.x * 64, k0 = blockIdx.y * 64;
    const int tid = threadIdx.x;
    const int c = tid & 63, rq = tid >> 6;
#pragma unroll
    for (int i = 0; i < 16; ++i)
        t[rq + i * 4][c] = W[(size_t)(k0 + rq + i * 4) * D_ + n0 + c];
    __syncthreads();
#pragma unroll
    for (int i = 0; i < 16; ++i)
        Wt[(size_t)(n0 + rq + i * 4) * D_ + k0 + c] = f2bf(t[c][rq + i * 4]);
}

// ---------------------------------------------------------------------------
// phi2[j][r] = 2 * sum_k stu_filters[j][k] * M_filters[k][r]   (L x R, fp32)
// ---------------------------------------------------------------------------
__global__ __launch_bounds__(256) void k_phi2(const float* __restrict__ F,
                                              const float* __restrict__ Mf,
                                              float* __restrict__ phi2) {
    int idx = blockIdx.x * 256 + threadIdx.x;
    int r = idx % R_;
    int j = idx / R_;
    float acc = 0.f;
#pragma unroll
    for (int kk = 0; kk < K_; ++kk)
        acc += F[j * K_ + kk] * Mf[kk * R_ + r];
    phi2[idx] = 2.f * acc;
}

// ---------------------------------------------------------------------------
// bf16 MFMA GEMM: C[M][N] (fp32) = A[M][Kd] (fp32, converted in staging)
//                               @ Bt[N][Kd] (bf16, pre-transposed)  + bias
// 64x64 tile, 4 waves, each wave 32x32 (2x2 fragments of 16x16x32).
// ---------------------------------------------------------------------------
__global__ __launch_bounds__(256) void k_gemm(const float* __restrict__ A,
                                              const unsigned short* __restrict__ Bt,
                                              const float* __restrict__ bias,
                                              float* __restrict__ C,
                                              int M, int N, int Kd) {
    __shared__ unsigned short As[64][72];   // +8 bf16 pad keeps 16B alignment
    __shared__ unsigned short Bs[64][72];
    const int bm = blockIdx.y * 64, bn = blockIdx.x * 64;
    const int tid = threadIdx.x;
    const int lane = tid & 63, wave = tid >> 6;
    const int wm = (wave >> 1) * 32, wn = (wave & 1) * 32;
    const int l15 = lane & 15, lg = lane >> 4;

    f32x4 acc[2][2] = {};

    for (int k0 = 0; k0 < Kd; k0 += 64) {
        __syncthreads();
#pragma unroll
        for (int it = 0; it < 2; ++it) {
            const int slot = tid + it * 256;      // 512 slots: 64 rows x 8 groups
            const int row = slot >> 3, kg = slot & 7;
            const float* src = A + (size_t)(bm + row) * Kd + k0 + kg * 8;
            float4 f0 = *reinterpret_cast<const float4*>(src);
            float4 f1 = *reinterpret_cast<const float4*>(src + 4);
            u16x8 p;
            p[0] = f2bf(f0.x); p[1] = f2bf(f0.y); p[2] = f2bf(f0.z); p[3] = f2bf(f0.w);
            p[4] = f2bf(f1.x); p[5] = f2bf(f1.y); p[6] = f2bf(f1.z); p[7] = f2bf(f1.w);
            *reinterpret_cast<u16x8*>(&As[row][kg * 8]) = p;
            *reinterpret_cast<u16x8*>(&Bs[row][kg * 8]) =
                *reinterpret_cast<const u16x8*>(Bt + (size_t)(bn + row) * Kd + k0 + kg * 8);
        }
        __syncthreads();
#pragma unroll
        for (int kk = 0; kk < 2; ++kk) {
            const int kb = kk * 32 + lg * 8;
            bf16x8 a0 = *reinterpret_cast<const bf16x8*>(&As[wm + l15][kb]);
            bf16x8 a1 = *reinterpret_cast<const bf16x8*>(&As[wm + 16 + l15][kb]);
            bf16x8 b0 = *reinterpret_cast<const bf16x8*>(&Bs[wn + l15][kb]);
            bf16x8 b1 = *reinterpret_cast<const bf16x8*>(&Bs[wn + 16 + l15][kb]);
            acc[0][0] = __builtin_amdgcn_mfma_f32_16x16x32_bf16(a0, b0, acc[0][0], 0, 0, 0);
            acc[0][1] = __builtin_amdgcn_mfma_f32_16x16x32_bf16(a0, b1, acc[0][1], 0, 0, 0);
            acc[1][0] = __builtin_amdgcn_mfma_f32_16x16x32_bf16(a1, b0, acc[1][0], 0, 0, 0);
            acc[1][1] = __builtin_amdgcn_mfma_f32_16x16x32_bf16(a1, b1, acc[1][1], 0, 0, 0);
        }
    }

#pragma unroll
    for (int fm = 0; fm < 2; ++fm)
#pragma unroll
        for (int fn = 0; fn < 2; ++fn) {
            const int col = bn + wn + fn * 16 + l15;
            const float bv = bias ? bias[col] : 0.f;
#pragma unroll
            for (int j = 0; j < 4; ++j) {
                const int row = bm + wm + fm * 16 + lg * 4 + j;
                C[(size_t)row * N + col] = acc[fm][fn][j] + bv;
            }
        }
}

// ---------------------------------------------------------------------------
// Parity-masked causal conv, float4 over r:
// xt[b,t,r] = sum_{j even, j<=t} phi2[j,r] * u[b,t-j,r]
// ---------------------------------------------------------------------------
__global__ __launch_bounds__(256) void k_conv4(const float* __restrict__ u,
                                               const float* __restrict__ phi2,
                                               float* __restrict__ xt) {
    const int gid = blockIdx.x * 256 + threadIdx.x;
    const int base4 = gid * 4;
    const int r  = base4 % R_;
    const int bt = base4 / R_;
    const int t  = bt % L_;
    const float* ub = u + (size_t)bt * R_ + r;
    const float* pb = phi2 + r;
    float4 acc = {0.f, 0.f, 0.f, 0.f};
    for (int j = 0; j <= t; j += 2) {
        const float4 pv = *reinterpret_cast<const float4*>(pb + (size_t)j * R_);
        const float4 uv = *reinterpret_cast<const float4*>(ub - (size_t)j * R_);
        acc.x += pv.x * uv.x; acc.y += pv.y * uv.y;
        acc.z += pv.z * uv.z; acc.w += pv.w * uv.w;
    }
    *reinterpret_cast<float4*>(xt + (size_t)bt * R_ + r) = acc;
}

// ---------------------------------------------------------------------------
// Z[b,h,c,p,n] = sum_{s in chunk c} v[s][p] * k[s][n]     (64x64 per block)
// ---------------------------------------------------------------------------
__global__ __launch_bounds__(256) void k_zsum(const float* __restrict__ k,
                                              const float* __restrict__ v,
                                              float* __restrict__ Z) {
    const int c = blockIdx.x, h = blockIdx.y, b = blockIdx.z;
    __shared__ float ks[64][65], vs[64][65];
    const int tid = threadIdx.x;
    const int lr = tid >> 6, lc = tid & 63;
    const size_t base = ((size_t)(b * L_ + c * CS_)) * D_ + h * HD_;
#pragma unroll
    for (int i = 0; i < 16; ++i) {
        ks[lr + i * 4][lc] = k[base + (size_t)(lr + i * 4) * D_ + lc];
        vs[lr + i * 4][lc] = v[base + (size_t)(lr + i * 4) * D_ + lc];
    }
    __syncthreads();
    const int tx = tid & 15, ty = tid >> 4;
    float acc[4][4] = {};
#pragma unroll 8
    for (int s = 0; s < 64; ++s) {
        float a[4], bb[4];
#pragma unroll
        for (int i = 0; i < 4; ++i) a[i] = vs[s][ty * 4 + i];
#pragma unroll
        for (int j = 0; j < 4; ++j) bb[j] = ks[s][tx * 4 + j];
#pragma unroll
        for (int i = 0; i < 4; ++i)
#pragma unroll
            for (int j = 0; j < 4; ++j)
                acc[i][j] += a[i] * bb[j];
    }
    float* zp = Z + ((size_t)(b * NH_ + h) * NC_ + c) * (HD_ * HD_);
#pragma unroll
    for (int i = 0; i < 4; ++i)
#pragma unroll
        for (int j = 0; j < 4; ++j)
            zp[(ty * 4 + i) * HD_ + tx * 4 + j] = acc[i][j];
}

// ---------------------------------------------------------------------------
// Exclusive prefix over chunks: H[c] = sum_{c'<c} Z[c']
// ---------------------------------------------------------------------------
__global__ __launch_bounds__(256) void k_prefix(const float* __restrict__ Z,
                                                float* __restrict__ H) {
    const int gid = blockIdx.x * 256 + threadIdx.x;   // over B*NH*4096
    const int bh = gid >> 12, pn = gid & 4095;
    const size_t base = (size_t)bh * NC_ * 4096 + pn;
    float acc = 0.f;
    for (int c = 0; c < NC_; ++c) {
        H[base + (size_t)c * 4096] = acc;
        acc += Z[base + (size_t)c * 4096];
    }
}

// ---------------------------------------------------------------------------
// Per chunk: Y = tril(Q Vt) K  +  Q H_c          (all 64x64x64, fp32)
// ---------------------------------------------------------------------------
__global__ __launch_bounds__(256) void k_attn2(const float* __restrict__ q,
                                               const float* __restrict__ k,
                                               const float* __restrict__ v,
                                               const float* __restrict__ Hst,
                                               float* __restrict__ ya) {
    const int c = blockIdx.x, h = blockIdx.y, b = blockIdx.z;
    __shared__ float qs[64][65], ks[64][65], vs[64][65];   // vs: V -> S -> H
    const int tid = threadIdx.x;
    const int lr = tid >> 6, lc = tid & 63;
    const size_t base = ((size_t)(b * L_ + c * CS_)) * D_ + h * HD_;
#pragma unroll
    for (int i = 0; i < 16; ++i) {
        qs[lr + i * 4][lc] = q[base + (size_t)(lr + i * 4) * D_ + lc];
        ks[lr + i * 4][lc] = k[base + (size_t)(lr + i * 4) * D_ + lc];
        vs[lr + i * 4][lc] = v[base + (size_t)(lr + i * 4) * D_ + lc];
    }
    __syncthreads();

    const int tx = tid & 15, ty = tid >> 4;

    // S[t][s] = q_t . v_s  (causal mask s<=t)
    float sacc[4][4] = {};
#pragma unroll 8
    for (int d = 0; d < 64; ++d) {
        float a[4], bb[4];
#pragma unroll
        for (int i = 0; i < 4; ++i) a[i] = qs[ty * 4 + i][d];
#pragma unroll
        for (int j = 0; j < 4; ++j) bb[j] = vs[tx * 4 + j][d];
#pragma unroll
        for (int i = 0; i < 4; ++i)
#pragma unroll
            for (int j = 0; j < 4; ++j)
                sacc[i][j] += a[i] * bb[j];
    }
#pragma unroll
    for (int i = 0; i < 4; ++i)
#pragma unroll
        for (int j = 0; j < 4; ++j)
            if (tx * 4 + j > ty * 4 + i) sacc[i][j] = 0.f;
    __syncthreads();                   // everyone done reading vs (V)
#pragma unroll
    for (int i = 0; i < 4; ++i)
#pragma unroll
        for (int j = 0; j < 4; ++j)
            vs[ty * 4 + i][tx * 4 + j] = sacc[i][j];
    __syncthreads();

    // Y_intra = S K
    float yacc[4][4] = {};
#pragma unroll 8
    for (int jj = 0; jj < 64; ++jj) {
        float s[4], kk[4];
#pragma unroll
        for (int i = 0; i < 4; ++i) s[i] = vs[ty * 4 + i][jj];
#pragma unroll
        for (int n = 0; n < 4; ++n) kk[n] = ks[jj][tx * 4 + n];
#pragma unroll
        for (int i = 0; i < 4; ++i)
#pragma unroll
            for (int n = 0; n < 4; ++n)
                yacc[i][n] += s[i] * kk[n];
    }
    __syncthreads();                   // everyone done reading vs (S)

    // load H_c (exclusive prefix state) and add Y_inter = Q H
    const float* hp = Hst + ((size_t)(b * NH_ + h) * NC_ + c) * 4096;
#pragma unroll
    for (int i = 0; i < 16; ++i)
        vs[lr + i * 4][lc] = hp[(lr + i * 4) * HD_ + lc];
    __syncthreads();
#pragma unroll 8
    for (int p = 0; p < 64; ++p) {
        float a[4], bb[4];
#pragma unroll
        for (int i = 0; i < 4; ++i) a[i] = qs[ty * 4 + i][p];
#pragma unroll
        for (int n = 0; n < 4; ++n) bb[n] = vs[p][tx * 4 + n];
#pragma unroll
        for (int i = 0; i < 4; ++i)
#pragma unroll
            for (int n = 0; n < 4; ++n)
                yacc[i][n] += a[i] * bb[n];
    }

#pragma unroll
    for (int i = 0; i < 4; ++i)
#pragma unroll
        for (int n = 0; n < 4; ++n)
            ya[base + (size_t)(ty * 4 + i) * D_ + tx * 4 + n] = yacc[i][n];
}

// ---------------------------------------------------------------------------
// y = x_tilde + (y_attn - x_tilde) * sigmoid(g)   (writes over g)
// ---------------------------------------------------------------------------
__global__ __launch_bounds__(256) void k_gate(const float* __restrict__ xt,
                                              const float* __restrict__ ya,
                                              float* __restrict__ g) {
    const int idx = blockIdx.x * 256 + threadIdx.x;
    const float gv = 1.f / (1.f + expf(-g[idx]));
    const float xv = xt[idx];
    g[idx] = xv + (ya[idx] - xv) * gv;
}

// ---------------------------------------------------------------------------
extern "C" void kernel_launch(void* const* d_in, const int* in_sizes, int n_in,
                              void* d_out, int out_size, void* d_ws, size_t ws_size,
                              hipStream_t stream) {
    const float* x    = (const float*)d_in[0];
    const float* stu  = (const float*)d_in[1];
    const float* Mi   = (const float*)d_in[2];
    const float* Mf   = (const float*)d_in[3];
    const float* wq_w = (const float*)d_in[4];
    const float* wq_b = (const float*)d_in[5];
    const float* wk_w = (const float*)d_in[6];
    const float* wk_b = (const float*)d_in[7];
    const float* wv_w = (const float*)d_in[8];
    const float* wv_b = (const float*)d_in[9];
    const float* wg_w = (const float*)d_in[10];
    const float* wg_b = (const float*)d_in[11];
    const float* wo_w = (const float*)d_in[12];
    const float* wo_b = (const float*)d_in[13];
    float* out = (float*)d_out;

    char* ws = (char*)d_ws;
    size_t o = 0;
    const size_t WSZ = (size_t)D_ * D_;             // 589824 elements
    unsigned short* wbf = (unsigned short*)(ws + o); o += 6 * WSZ * 2;   // 6 bf16 weights
    float* ubuf = (float*)(ws + o); o += (size_t)B_ * L_ * R_ * 4;       // u -> q
    float* phi2 = (float*)(ws + o); o += (size_t)L_ * R_ * 4;
    float* xt   = (float*)(ws + o); o += (size_t)B_ * L_ * R_ * 4;
    float* kb   = (float*)(ws + o); o += (size_t)B_ * L_ * D_ * 4;
    float* vb   = (float*)(ws + o); o += (size_t)B_ * L_ * D_ * 4;
    float* gb   = (float*)(ws + o); o += (size_t)B_ * L_ * D_ * 4;
    float* Zb   = (float*)(ws + o); o += (size_t)B_ * NH_ * NC_ * HD_ * HD_ * 4;
    float* Hb   = (float*)(ws + o); o += (size_t)B_ * NH_ * NC_ * HD_ * HD_ * 4;
    float* ya   = Zb;   // Z dead after k_prefix

    unsigned short* Mi_t = wbf + 0 * WSZ;
    unsigned short* wq_t = wbf + 1 * WSZ;
    unsigned short* wk_t = wbf + 2 * WSZ;
    unsigned short* wv_t = wbf + 3 * WSZ;
    unsigned short* wg_t = wbf + 4 * WSZ;
    unsigned short* wo_t = wbf + 5 * WSZ;

    const dim3 blk(256);
    const dim3 wgrid(12, 12);
    const dim3 ggrid(D_ / 64, (B_ * L_) / 64);       // (12, 32)
    const dim3 agrid(NC_, NH_, B_);                  // (16, 12, 2)

    k_wt<<<wgrid, blk, 0, stream>>>(Mi,   Mi_t);
    k_wt<<<wgrid, blk, 0, stream>>>(wq_w, wq_t);
    k_wt<<<wgrid, blk, 0, stream>>>(wk_w, wk_t);
    k_wt<<<wgrid, blk, 0, stream>>>(wv_w, wv_t);
    k_wt<<<wgrid, blk, 0, stream>>>(wg_w, wg_t);
    k_wt<<<wgrid, blk, 0, stream>>>(wo_w, wo_t);

    k_phi2<<<dim3(L_ * R_ / 256), blk, 0, stream>>>(stu, Mf, phi2);

    k_gemm<<<ggrid, blk, 0, stream>>>(x, Mi_t, nullptr, ubuf, B_ * L_, R_, D_);
    k_conv4<<<dim3(B_ * L_ * R_ / 4 / 256), blk, 0, stream>>>(ubuf, phi2, xt);

    k_gemm<<<ggrid, blk, 0, stream>>>(x, wq_t, wq_b, ubuf, B_ * L_, D_, D_);  // q (u dead)
    k_gemm<<<ggrid, blk, 0, stream>>>(x, wk_t, wk_b, kb,   B_ * L_, D_, D_);
    k_gemm<<<ggrid, blk, 0, stream>>>(x, wv_t, wv_b, vb,   B_ * L_, D_, D_);
    k_gemm<<<ggrid, blk, 0, stream>>>(x, wg_t, wg_b, gb,   B_ * L_, D_, D_);

    k_zsum<<<agrid, blk, 0, stream>>>(kb, vb, Zb);
    k_prefix<<<dim3((B_ * NH_ * HD_ * HD_) / 256), blk, 0, stream>>>(Zb, Hb);
    k_attn2<<<agrid, blk, 0, stream>>>(ubuf, kb, vb, Hb, ya);

    k_gate<<<dim3(B_ * L_ * D_ / 256), blk, 0, stream>>>(xt, ya, gb);
    k_gemm<<<ggrid, blk, 0, stream>>>(gb, wo_t, wo_b, out, B_ * L_, D_, D_);
}

// Round 3
// 322.011 us; speedup vs baseline: 2.4755x; 1.0704x over previous
//
#include <hip/hip_runtime.h>
#include <math.h>

#define B_  2
#define L_  1024
#define D_  768
#define NH_ 12
#define HD_ 64
#define K_  24
#define R_  768
#define NC_ 16   // chunks
#define CS_ 64   // chunk size

typedef __bf16 bf16x8 __attribute__((ext_vector_type(8)));
typedef float f32x4 __attribute__((ext_vector_type(4)));
typedef unsigned short u16x8 __attribute__((ext_vector_type(8)));

__device__ inline unsigned short f2bf(float f) {
    union { float f; unsigned u; } v; v.f = f;
    unsigned r = v.u + 0x7FFFu + ((v.u >> 16) & 1u);
    return (unsigned short)(r >> 16);
}

// ---------------------------------------------------------------------------
// Transpose + convert weight: Wt[n][k] (bf16) = W[k][n] (fp32). 768x768.
// ---------------------------------------------------------------------------
__global__ __launch_bounds__(256) void k_wt(const float* __restrict__ W,
                                            unsigned short* __restrict__ Wt) {
    __shared__ float t[64][65];
    const int n0 = blockIdx.x * 64, k0 = blockIdx.y * 64;
    const int tid = threadIdx.x;
    const int c = tid & 63, rq = tid >> 6;
#pragma unroll
    for (int i = 0; i < 16; ++i)
        t[rq + i * 4][c] = W[(size_t)(k0 + rq + i * 4) * D_ + n0 + c];
    __syncthreads();
#pragma unroll
    for (int i = 0; i < 16; ++i)
        Wt[(size_t)(n0 + rq + i * 4) * D_ + k0 + c] = f2bf(t[c][rq + i * 4]);
}

// ---------------------------------------------------------------------------
// phi2[j][r] = 2 * sum_k stu_filters[j][k] * M_filters[k][r]   (L x R, fp32)
// ---------------------------------------------------------------------------
__global__ __launch_bounds__(256) void k_phi2(const float* __restrict__ F,
                                              const float* __restrict__ Mf,
                                              float* __restrict__ phi2) {
    int idx = blockIdx.x * 256 + threadIdx.x;
    int r = idx % R_;
    int j = idx / R_;
    float acc = 0.f;
#pragma unroll
    for (int kk = 0; kk < K_; ++kk)
        acc += F[j * K_ + kk] * Mf[kk * R_ + r];
    phi2[idx] = 2.f * acc;
}

// ---------------------------------------------------------------------------
// bf16 MFMA GEMM: C[M][N] (fp32) = A[M][Kd] (fp32, converted in staging)
//                               @ Bt[N][Kd] (bf16, pre-transposed)  + bias
// ---------------------------------------------------------------------------
__global__ __launch_bounds__(256) void k_gemm(const float* __restrict__ A,
                                              const unsigned short* __restrict__ Bt,
                                              const float* __restrict__ bias,
                                              float* __restrict__ C,
                                              int M, int N, int Kd) {
    __shared__ unsigned short As[64][72];
    __shared__ unsigned short Bs[64][72];
    const int bm = blockIdx.y * 64, bn = blockIdx.x * 64;
    const int tid = threadIdx.x;
    const int lane = tid & 63, wave = tid >> 6;
    const int wm = (wave >> 1) * 32, wn = (wave & 1) * 32;
    const int l15 = lane & 15, lg = lane >> 4;

    f32x4 acc[2][2] = {};

    for (int k0 = 0; k0 < Kd; k0 += 64) {
        __syncthreads();
#pragma unroll
        for (int it = 0; it < 2; ++it) {
            const int slot = tid + it * 256;
            const int row = slot >> 3, kg = slot & 7;
            const float* src = A + (size_t)(bm + row) * Kd + k0 + kg * 8;
            float4 f0 = *reinterpret_cast<const float4*>(src);
            float4 f1 = *reinterpret_cast<const float4*>(src + 4);
            u16x8 p;
            p[0] = f2bf(f0.x); p[1] = f2bf(f0.y); p[2] = f2bf(f0.z); p[3] = f2bf(f0.w);
            p[4] = f2bf(f1.x); p[5] = f2bf(f1.y); p[6] = f2bf(f1.z); p[7] = f2bf(f1.w);
            *reinterpret_cast<u16x8*>(&As[row][kg * 8]) = p;
            *reinterpret_cast<u16x8*>(&Bs[row][kg * 8]) =
                *reinterpret_cast<const u16x8*>(Bt + (size_t)(bn + row) * Kd + k0 + kg * 8);
        }
        __syncthreads();
#pragma unroll
        for (int kk = 0; kk < 2; ++kk) {
            const int kb = kk * 32 + lg * 8;
            bf16x8 a0 = *reinterpret_cast<const bf16x8*>(&As[wm + l15][kb]);
            bf16x8 a1 = *reinterpret_cast<const bf16x8*>(&As[wm + 16 + l15][kb]);
            bf16x8 b0 = *reinterpret_cast<const bf16x8*>(&Bs[wn + l15][kb]);
            bf16x8 b1 = *reinterpret_cast<const bf16x8*>(&Bs[wn + 16 + l15][kb]);
            acc[0][0] = __builtin_amdgcn_mfma_f32_16x16x32_bf16(a0, b0, acc[0][0], 0, 0, 0);
            acc[0][1] = __builtin_amdgcn_mfma_f32_16x16x32_bf16(a0, b1, acc[0][1], 0, 0, 0);
            acc[1][0] = __builtin_amdgcn_mfma_f32_16x16x32_bf16(a1, b0, acc[1][0], 0, 0, 0);
            acc[1][1] = __builtin_amdgcn_mfma_f32_16x16x32_bf16(a1, b1, acc[1][1], 0, 0, 0);
        }
    }

#pragma unroll
    for (int fm = 0; fm < 2; ++fm)
#pragma unroll
        for (int fn = 0; fn < 2; ++fn) {
            const int col = bn + wn + fn * 16 + l15;
            const float bv = bias ? bias[col] : 0.f;
#pragma unroll
            for (int j = 0; j < 4; ++j) {
                const int row = bm + wm + fm * 16 + lg * 4 + j;
                C[(size_t)row * N + col] = acc[fm][fn][j] + bv;
            }
        }
}

// ---------------------------------------------------------------------------
// Parity-split causal conv with register sliding window.
// xt[2m+p, r] = sum_{n<=m} phi2[2n, r] * u[2(m-n)+p, r]
// Thread: 8 consecutive m-outputs x float4 of r. One new u4 + one new phi4
// load per step, 8 float4 FMAs against a rotating 8-deep phi window.
// Rotation uses static (k+a+1)&7 indices -> pure register renaming, no moves.
// ---------------------------------------------------------------------------
__global__ __launch_bounds__(192) void k_conv8(const float* __restrict__ u,
                                               const float* __restrict__ phi2,
                                               float* __restrict__ xt) {
    const int tid = threadIdx.x;          // 0..191 -> r in steps of 4
    const int r   = tid * 4;
    const int m0  = blockIdx.x * 8;       // m-group
    const int bp  = blockIdx.y;
    const int b   = bp >> 1, p = bp & 1;

    f32x4 acc[8] = {};                    // acc[a] -> output m0+a
    f32x4 w[8]   = {};                    // rotating phi window (zero = causal pad)

    // u walker: uh[s] = u[b, 2s+p, r], start s = m0+7, descend
    const float* up = u + ((size_t)(b * L_) + (size_t)(2 * (m0 + 7) + p)) * R_ + r;
    const float* pp = phi2 + r;           // phiev[i] = phi2[2i, r], ascend
    const int steps = m0 + 8;             // multiple of 8

    for (int I = 0; I < steps; I += 8) {
#pragma unroll
        for (int k = 0; k < 8; ++k) {
            const f32x4 wn = *reinterpret_cast<const f32x4*>(pp);   // phiev[I+k]
            const f32x4 un = *reinterpret_cast<const f32x4*>(up);   // uh[m0+7-(I+k)]
            w[k] = wn;   // phys slot (i)&7 == k since I%8==0
#pragma unroll
            for (int a = 0; a < 8; ++a) {
                // logical phi index i-(7-a) lives in phys slot (k+a+1)&7
                const f32x4 ww = w[(k + a + 1) & 7];
                acc[a] += ww * un;
            }
            pp += 2 * R_;
            up -= 2 * R_;
        }
    }

    float* op = xt + ((size_t)(b * L_) + (size_t)(2 * m0 + p)) * R_ + r;
#pragma unroll
    for (int a = 0; a < 8; ++a) {
        *reinterpret_cast<f32x4*>(op) = acc[a];
        op += 2 * R_;
    }
}

// ---------------------------------------------------------------------------
// Z[b,h,c,p,n] = sum_{s in chunk c} v[s][p] * k[s][n]     (64x64 per block)
// ---------------------------------------------------------------------------
__global__ __launch_bounds__(256) void k_zsum(const float* __restrict__ k,
                                              const float* __restrict__ v,
                                              float* __restrict__ Z) {
    const int c = blockIdx.x, h = blockIdx.y, b = blockIdx.z;
    __shared__ float ks[64][65], vs[64][65];
    const int tid = threadIdx.x;
    const int lr = tid >> 6, lc = tid & 63;
    const size_t base = ((size_t)(b * L_ + c * CS_)) * D_ + h * HD_;
#pragma unroll
    for (int i = 0; i < 16; ++i) {
        ks[lr + i * 4][lc] = k[base + (size_t)(lr + i * 4) * D_ + lc];
        vs[lr + i * 4][lc] = v[base + (size_t)(lr + i * 4) * D_ + lc];
    }
    __syncthreads();
    const int tx = tid & 15, ty = tid >> 4;
    float acc[4][4] = {};
#pragma unroll 8
    for (int s = 0; s < 64; ++s) {
        float a[4], bb[4];
#pragma unroll
        for (int i = 0; i < 4; ++i) a[i] = vs[s][ty * 4 + i];
#pragma unroll
        for (int j = 0; j < 4; ++j) bb[j] = ks[s][tx * 4 + j];
#pragma unroll
        for (int i = 0; i < 4; ++i)
#pragma unroll
            for (int j = 0; j < 4; ++j)
                acc[i][j] += a[i] * bb[j];
    }
    float* zp = Z + ((size_t)(b * NH_ + h) * NC_ + c) * (HD_ * HD_);
#pragma unroll
    for (int i = 0; i < 4; ++i)
#pragma unroll
        for (int j = 0; j < 4; ++j)
            zp[(ty * 4 + i) * HD_ + tx * 4 + j] = acc[i][j];
}

// ---------------------------------------------------------------------------
// Exclusive prefix over chunks: H[c] = sum_{c'<c} Z[c']
// ---------------------------------------------------------------------------
__global__ __launch_bounds__(256) void k_prefix(const float* __restrict__ Z,
                                                float* __restrict__ H) {
    const int gid = blockIdx.x * 256 + threadIdx.x;   // over B*NH*4096
    const int bh = gid >> 12, pn = gid & 4095;
    const size_t base = (size_t)bh * NC_ * 4096 + pn;
    float acc = 0.f;
    for (int c = 0; c < NC_; ++c) {
        H[base + (size_t)c * 4096] = acc;
        acc += Z[base + (size_t)c * 4096];
    }
}

// ---------------------------------------------------------------------------
// Per chunk: Y = tril(Q Vt) K  +  Q H_c          (all 64x64x64, fp32)
// ---------------------------------------------------------------------------
__global__ __launch_bounds__(256) void k_attn2(const float* __restrict__ q,
                                               const float* __restrict__ k,
                                               const float* __restrict__ v,
                                               const float* __restrict__ Hst,
                                               float* __restrict__ ya) {
    const int c = blockIdx.x, h = blockIdx.y, b = blockIdx.z;
    __shared__ float qs[64][65], ks[64][65], vs[64][65];   // vs: V -> S -> H
    const int tid = threadIdx.x;
    const int lr = tid >> 6, lc = tid & 63;
    const size_t base = ((size_t)(b * L_ + c * CS_)) * D_ + h * HD_;
#pragma unroll
    for (int i = 0; i < 16; ++i) {
        qs[lr + i * 4][lc] = q[base + (size_t)(lr + i * 4) * D_ + lc];
        ks[lr + i * 4][lc] = k[base + (size_t)(lr + i * 4) * D_ + lc];
        vs[lr + i * 4][lc] = v[base + (size_t)(lr + i * 4) * D_ + lc];
    }
    __syncthreads();

    const int tx = tid & 15, ty = tid >> 4;

    // S[t][s] = q_t . v_s  (causal mask s<=t)
    float sacc[4][4] = {};
#pragma unroll 8
    for (int d = 0; d < 64; ++d) {
        float a[4], bb[4];
#pragma unroll
        for (int i = 0; i < 4; ++i) a[i] = qs[ty * 4 + i][d];
#pragma unroll
        for (int j = 0; j < 4; ++j) bb[j] = vs[tx * 4 + j][d];
#pragma unroll
        for (int i = 0; i < 4; ++i)
#pragma unroll
            for (int j = 0; j < 4; ++j)
                sacc[i][j] += a[i] * bb[j];
    }
#pragma unroll
    for (int i = 0; i < 4; ++i)
#pragma unroll
        for (int j = 0; j < 4; ++j)
            if (tx * 4 + j > ty * 4 + i) sacc[i][j] = 0.f;
    __syncthreads();
#pragma unroll
    for (int i = 0; i < 4; ++i)
#pragma unroll
        for (int j = 0; j < 4; ++j)
            vs[ty * 4 + i][tx * 4 + j] = sacc[i][j];
    __syncthreads();

    // Y_intra = S K
    float yacc[4][4] = {};
#pragma unroll 8
    for (int jj = 0; jj < 64; ++jj) {
        float s[4], kk[4];
#pragma unroll
        for (int i = 0; i < 4; ++i) s[i] = vs[ty * 4 + i][jj];
#pragma unroll
        for (int n = 0; n < 4; ++n) kk[n] = ks[jj][tx * 4 + n];
#pragma unroll
        for (int i = 0; i < 4; ++i)
#pragma unroll
            for (int n = 0; n < 4; ++n)
                yacc[i][n] += s[i] * kk[n];
    }
    __syncthreads();

    // load H_c (exclusive prefix state) and add Y_inter = Q H
    const float* hp = Hst + ((size_t)(b * NH_ + h) * NC_ + c) * 4096;
#pragma unroll
    for (int i = 0; i < 16; ++i)
        vs[lr + i * 4][lc] = hp[(lr + i * 4) * HD_ + lc];
    __syncthreads();
#pragma unroll 8
    for (int p = 0; p < 64; ++p) {
        float a[4], bb[4];
#pragma unroll
        for (int i = 0; i < 4; ++i) a[i] = qs[ty * 4 + i][p];
#pragma unroll
        for (int n = 0; n < 4; ++n) bb[n] = vs[p][tx * 4 + n];
#pragma unroll
        for (int i = 0; i < 4; ++i)
#pragma unroll
            for (int n = 0; n < 4; ++n)
                yacc[i][n] += a[i] * bb[n];
    }

#pragma unroll
    for (int i = 0; i < 4; ++i)
#pragma unroll
        for (int n = 0; n < 4; ++n)
            ya[base + (size_t)(ty * 4 + i) * D_ + tx * 4 + n] = yacc[i][n];
}

// ---------------------------------------------------------------------------
// y = x_tilde + (y_attn - x_tilde) * sigmoid(g)   (writes over g)
// ---------------------------------------------------------------------------
__global__ __launch_bounds__(256) void k_gate(const float* __restrict__ xt,
                                              const float* __restrict__ ya,
                                              float* __restrict__ g) {
    const int idx = blockIdx.x * 256 + threadIdx.x;
    const float gv = 1.f / (1.f + expf(-g[idx]));
    const float xv = xt[idx];
    g[idx] = xv + (ya[idx] - xv) * gv;
}

// ---------------------------------------------------------------------------
extern "C" void kernel_launch(void* const* d_in, const int* in_sizes, int n_in,
                              void* d_out, int out_size, void* d_ws, size_t ws_size,
                              hipStream_t stream) {
    const float* x    = (const float*)d_in[0];
    const float* stu  = (const float*)d_in[1];
    const float* Mi   = (const float*)d_in[2];
    const float* Mf   = (const float*)d_in[3];
    const float* wq_w = (const float*)d_in[4];
    const float* wq_b = (const float*)d_in[5];
    const float* wk_w = (const float*)d_in[6];
    const float* wk_b = (const float*)d_in[7];
    const float* wv_w = (const float*)d_in[8];
    const float* wv_b = (const float*)d_in[9];
    const float* wg_w = (const float*)d_in[10];
    const float* wg_b = (const float*)d_in[11];
    const float* wo_w = (const float*)d_in[12];
    const float* wo_b = (const float*)d_in[13];
    float* out = (float*)d_out;

    char* ws = (char*)d_ws;
    size_t o = 0;
    const size_t WSZ = (size_t)D_ * D_;
    unsigned short* wbf = (unsigned short*)(ws + o); o += 6 * WSZ * 2;
    float* ubuf = (float*)(ws + o); o += (size_t)B_ * L_ * R_ * 4;       // u -> q
    float* phi2 = (float*)(ws + o); o += (size_t)L_ * R_ * 4;
    float* xt   = (float*)(ws + o); o += (size_t)B_ * L_ * R_ * 4;
    float* kb   = (float*)(ws + o); o += (size_t)B_ * L_ * D_ * 4;
    float* vb   = (float*)(ws + o); o += (size_t)B_ * L_ * D_ * 4;
    float* gb   = (float*)(ws + o); o += (size_t)B_ * L_ * D_ * 4;
    float* Zb   = (float*)(ws + o); o += (size_t)B_ * NH_ * NC_ * HD_ * HD_ * 4;
    float* Hb   = (float*)(ws + o); o += (size_t)B_ * NH_ * NC_ * HD_ * HD_ * 4;
    float* ya   = Zb;   // Z dead after k_prefix

    unsigned short* Mi_t = wbf + 0 * WSZ;
    unsigned short* wq_t = wbf + 1 * WSZ;
    unsigned short* wk_t = wbf + 2 * WSZ;
    unsigned short* wv_t = wbf + 3 * WSZ;
    unsigned short* wg_t = wbf + 4 * WSZ;
    unsigned short* wo_t = wbf + 5 * WSZ;

    const dim3 blk(256);
    const dim3 wgrid(12, 12);
    const dim3 ggrid(D_ / 64, (B_ * L_) / 64);       // (12, 32)
    const dim3 agrid(NC_, NH_, B_);                  // (16, 12, 2)

    k_wt<<<wgrid, blk, 0, stream>>>(Mi,   Mi_t);
    k_wt<<<wgrid, blk, 0, stream>>>(wq_w, wq_t);
    k_wt<<<wgrid, blk, 0, stream>>>(wk_w, wk_t);
    k_wt<<<wgrid, blk, 0, stream>>>(wv_w, wv_t);
    k_wt<<<wgrid, blk, 0, stream>>>(wg_w, wg_t);
    k_wt<<<wgrid, blk, 0, stream>>>(wo_w, wo_t);

    k_phi2<<<dim3(L_ * R_ / 256), blk, 0, stream>>>(stu, Mf, phi2);

    k_gemm<<<ggrid, blk, 0, stream>>>(x, Mi_t, nullptr, ubuf, B_ * L_, R_, D_);
    k_conv8<<<dim3(L_ / 2 / 8, B_ * 2), dim3(192), 0, stream>>>(ubuf, phi2, xt);

    k_gemm<<<ggrid, blk, 0, stream>>>(x, wq_t, wq_b, ubuf, B_ * L_, D_, D_);  // q (u dead)
    k_gemm<<<ggrid, blk, 0, stream>>>(x, wk_t, wk_b, kb,   B_ * L_, D_, D_);
    k_gemm<<<ggrid, blk, 0, stream>>>(x, wv_t, wv_b, vb,   B_ * L_, D_, D_);
    k_gemm<<<ggrid, blk, 0, stream>>>(x, wg_t, wg_b, gb,   B_ * L_, D_, D_);

    k_zsum<<<agrid, blk, 0, stream>>>(kb, vb, Zb);
    k_prefix<<<dim3((B_ * NH_ * HD_ * HD_) / 256), blk, 0, stream>>>(Zb, Hb);
    k_attn2<<<agrid, blk, 0, stream>>>(ubuf, kb, vb, Hb, ya);

    k_gate<<<dim3(B_ * L_ * D_ / 256), blk, 0, stream>>>(xt, ya, gb);
    k_gemm<<<ggrid, blk, 0, stream>>>(gb, wo_t, wo_b, out, B_ * L_, D_, D_);
}

// Round 4
// 157.140 us; speedup vs baseline: 5.0728x; 2.0492x over previous
//
#include <hip/hip_runtime.h>
#include <math.h>

#define B_  2
#define L_  1024
#define D_  768
#define NH_ 12
#define HD_ 64
#define K_  24
#define R_  768
#define NC_ 16   // chunks
#define CS_ 64   // chunk size

typedef __bf16 bf16x8 __attribute__((ext_vector_type(8)));
typedef float f32x4 __attribute__((ext_vector_type(4)));
typedef unsigned short u16x8 __attribute__((ext_vector_type(8)));

__device__ inline unsigned short f2bf(float f) {
    union { float f; unsigned u; } v; v.f = f;
    unsigned r = v.u + 0x7FFFu + ((v.u >> 16) & 1u);
    return (unsigned short)(r >> 16);
}

// ---------------------------------------------------------------------------
// All six weight transposes in one launch: Wt[z][n][k] = W_z[k][n] (bf16)
// ---------------------------------------------------------------------------
__global__ __launch_bounds__(256) void k_wt6(const float* __restrict__ w0,
                                             const float* __restrict__ w1,
                                             const float* __restrict__ w2,
                                             const float* __restrict__ w3,
                                             const float* __restrict__ w4,
                                             const float* __restrict__ w5,
                                             unsigned short* __restrict__ Wt) {
    const float* W;
    switch (blockIdx.z) {
        case 0: W = w0; break;
        case 1: W = w1; break;
        case 2: W = w2; break;
        case 3: W = w3; break;
        case 4: W = w4; break;
        default: W = w5; break;
    }
    unsigned short* o = Wt + (size_t)blockIdx.z * D_ * D_;
    __shared__ float t[64][65];
    const int n0 = blockIdx.x * 64, k0 = blockIdx.y * 64;
    const int tid = threadIdx.x;
    const int c = tid & 63, rq = tid >> 6;
#pragma unroll
    for (int i = 0; i < 16; ++i)
        t[rq + i * 4][c] = W[(size_t)(k0 + rq + i * 4) * D_ + n0 + c];
    __syncthreads();
#pragma unroll
    for (int i = 0; i < 16; ++i)
        o[(size_t)(n0 + rq + i * 4) * D_ + k0 + c] = f2bf(t[c][rq + i * 4]);
}

// ---------------------------------------------------------------------------
// phi2[j][r] = 2 * sum_k stu_filters[j][k] * M_filters[k][r]   (L x R, fp32)
// ---------------------------------------------------------------------------
__global__ __launch_bounds__(256) void k_phi2(const float* __restrict__ F,
                                              const float* __restrict__ Mf,
                                              float* __restrict__ phi2) {
    int idx = blockIdx.x * 256 + threadIdx.x;
    int r = idx % R_;
    int j = idx / R_;
    float acc = 0.f;
#pragma unroll
    for (int kk = 0; kk < K_; ++kk)
        acc += F[j * K_ + kk] * Mf[kk * R_ + r];
    phi2[idx] = 2.f * acc;
}

// ---------------------------------------------------------------------------
// bf16 MFMA GEMM body (shared by single and 4-way kernels)
// ---------------------------------------------------------------------------
__device__ __forceinline__ void gemm_body(const float* __restrict__ A,
                                          const unsigned short* __restrict__ Bt,
                                          const float* __restrict__ bias,
                                          float* __restrict__ C,
                                          int M, int N, int Kd,
                                          int bm, int bn, int tid) {
    __shared__ unsigned short As[64][72];
    __shared__ unsigned short Bs[64][72];
    const int lane = tid & 63, wave = tid >> 6;
    const int wm = (wave >> 1) * 32, wn = (wave & 1) * 32;
    const int l15 = lane & 15, lg = lane >> 4;

    f32x4 acc[2][2] = {};

    for (int k0 = 0; k0 < Kd; k0 += 64) {
        __syncthreads();
#pragma unroll
        for (int it = 0; it < 2; ++it) {
            const int slot = tid + it * 256;
            const int row = slot >> 3, kg = slot & 7;
            const float* src = A + (size_t)(bm + row) * Kd + k0 + kg * 8;
            float4 f0 = *reinterpret_cast<const float4*>(src);
            float4 f1 = *reinterpret_cast<const float4*>(src + 4);
            u16x8 p;
            p[0] = f2bf(f0.x); p[1] = f2bf(f0.y); p[2] = f2bf(f0.z); p[3] = f2bf(f0.w);
            p[4] = f2bf(f1.x); p[5] = f2bf(f1.y); p[6] = f2bf(f1.z); p[7] = f2bf(f1.w);
            *reinterpret_cast<u16x8*>(&As[row][kg * 8]) = p;
            *reinterpret_cast<u16x8*>(&Bs[row][kg * 8]) =
                *reinterpret_cast<const u16x8*>(Bt + (size_t)(bn + row) * Kd + k0 + kg * 8);
        }
        __syncthreads();
#pragma unroll
        for (int kk = 0; kk < 2; ++kk) {
            const int kb = kk * 32 + lg * 8;
            bf16x8 a0 = *reinterpret_cast<const bf16x8*>(&As[wm + l15][kb]);
            bf16x8 a1 = *reinterpret_cast<const bf16x8*>(&As[wm + 16 + l15][kb]);
            bf16x8 b0 = *reinterpret_cast<const bf16x8*>(&Bs[wn + l15][kb]);
            bf16x8 b1 = *reinterpret_cast<const bf16x8*>(&Bs[wn + 16 + l15][kb]);
            acc[0][0] = __builtin_amdgcn_mfma_f32_16x16x32_bf16(a0, b0, acc[0][0], 0, 0, 0);
            acc[0][1] = __builtin_amdgcn_mfma_f32_16x16x32_bf16(a0, b1, acc[0][1], 0, 0, 0);
            acc[1][0] = __builtin_amdgcn_mfma_f32_16x16x32_bf16(a1, b0, acc[1][0], 0, 0, 0);
            acc[1][1] = __builtin_amdgcn_mfma_f32_16x16x32_bf16(a1, b1, acc[1][1], 0, 0, 0);
        }
    }

#pragma unroll
    for (int fm = 0; fm < 2; ++fm)
#pragma unroll
        for (int fn = 0; fn < 2; ++fn) {
            const int col = bn + wn + fn * 16 + l15;
            const float bv = bias ? bias[col] : 0.f;
#pragma unroll
            for (int j = 0; j < 4; ++j) {
                const int row = bm + wm + fm * 16 + lg * 4 + j;
                C[(size_t)row * N + col] = acc[fm][fn][j] + bv;
            }
        }
}

__global__ __launch_bounds__(256) void k_gemm(const float* __restrict__ A,
                                              const unsigned short* __restrict__ Bt,
                                              const float* __restrict__ bias,
                                              float* __restrict__ C,
                                              int M, int N, int Kd) {
    gemm_body(A, Bt, bias, C, M, N, Kd, blockIdx.y * 64, blockIdx.x * 64, threadIdx.x);
}

// 4 projections (q,k,v,g) share A=x; blockIdx.z selects weight/bias/output.
__global__ __launch_bounds__(256) void k_gemm4(const float* __restrict__ A,
                                               const unsigned short* __restrict__ wt,   // 4 contiguous
                                               const float* __restrict__ b0,
                                               const float* __restrict__ b1,
                                               const float* __restrict__ b2,
                                               const float* __restrict__ b3,
                                               float* __restrict__ c0,
                                               float* __restrict__ c1,
                                               float* __restrict__ c2,
                                               float* __restrict__ c3) {
    const float* bias; float* C;
    switch (blockIdx.z) {
        case 0: bias = b0; C = c0; break;
        case 1: bias = b1; C = c1; break;
        case 2: bias = b2; C = c2; break;
        default: bias = b3; C = c3; break;
    }
    const unsigned short* Bt = wt + (size_t)blockIdx.z * D_ * D_;
    gemm_body(A, Bt, bias, C, B_ * L_, D_, D_, blockIdx.y * 64, blockIdx.x * 64, threadIdx.x);
}

// ---------------------------------------------------------------------------
// Parity-split causal conv, register sliding window, 4-way n-split per block.
// Terms (a, n) <-> i = n+7-a; group s covers i in [128s, min(128s+128, m0+8)).
// Groups s>=1 preload the 7-deep phi window (phi[ns-7..ns-1]); group 0 zero.
// LDS reduce across the 4 groups at the end.
// ---------------------------------------------------------------------------
__global__ __launch_bounds__(768) void k_conv(const float* __restrict__ u,
                                              const float* __restrict__ phi2,
                                              float* __restrict__ xt) {
    __shared__ f32x4 red[4][8][192];            // 98304 B
    const int tid = threadIdx.x;                // 0..767
    const int g   = tid / 192;                  // n-split group
    const int lr  = tid % 192;                  // r4 channel
    const int r   = lr * 4;
    const int m0  = blockIdx.x * 8;
    const int bp  = blockIdx.y;
    const int b   = bp >> 1, p = bp & 1;

    f32x4 acc[8] = {};
    f32x4 w[8]   = {};

    const int ns = g * 128;
    const int ne = min(ns + 128, m0 + 8);

    if (ns < ne) {
        if (g > 0) {
#pragma unroll
            for (int j = 1; j <= 7; ++j)
                w[(8 - j) & 7] =
                    *reinterpret_cast<const f32x4*>(phi2 + (size_t)(2 * (ns - j)) * R_ + r);
        }
        const float* pp = phi2 + (size_t)(2 * ns) * R_ + r;
        const float* up = u + ((size_t)(b * L_) + (size_t)(2 * (m0 + 7 - ns) + p)) * R_ + r;
        for (int i = ns; i < ne; i += 8) {
#pragma unroll
            for (int k = 0; k < 8; ++k) {
                const f32x4 wn = *reinterpret_cast<const f32x4*>(pp);   // phi[i+k]
                const f32x4 un = *reinterpret_cast<const f32x4*>(up);   // u[m0+7-(i+k)]
                w[k] = wn;
#pragma unroll
                for (int a = 0; a < 8; ++a)
                    acc[a] += w[(k + a + 1) & 7] * un;
                pp += 2 * R_;
                up -= 2 * R_;
            }
        }
    }

#pragma unroll
    for (int a = 0; a < 8; ++a) red[g][a][lr] = acc[a];
    __syncthreads();

#pragma unroll
    for (int q2 = 0; q2 < 2; ++q2) {
        const int sl = q2 * 768 + tid;          // 0..1535
        const int a  = sl / 192, l = sl % 192;
        const f32x4 s = red[0][a][l] + red[1][a][l] + red[2][a][l] + red[3][a][l];
        *reinterpret_cast<f32x4*>(
            xt + ((size_t)(b * L_) + (size_t)(2 * (m0 + a) + p)) * R_ + l * 4) = s;
    }
}

// ---------------------------------------------------------------------------
// Z[b,h,c,p,n] = sum_{s in chunk c} v[s][p] * k[s][n]     (64x64 per block)
// ---------------------------------------------------------------------------
__global__ __launch_bounds__(256) void k_zsum(const float* __restrict__ k,
                                              const float* __restrict__ v,
                                              float* __restrict__ Z) {
    const int c = blockIdx.x, h = blockIdx.y, b = blockIdx.z;
    __shared__ float ks[64][65], vs[64][65];
    const int tid = threadIdx.x;
    const int lr = tid >> 6, lc = tid & 63;
    const size_t base = ((size_t)(b * L_ + c * CS_)) * D_ + h * HD_;
#pragma unroll
    for (int i = 0; i < 16; ++i) {
        ks[lr + i * 4][lc] = k[base + (size_t)(lr + i * 4) * D_ + lc];
        vs[lr + i * 4][lc] = v[base + (size_t)(lr + i * 4) * D_ + lc];
    }
    __syncthreads();
    const int tx = tid & 15, ty = tid >> 4;
    float acc[4][4] = {};
#pragma unroll 8
    for (int s = 0; s < 64; ++s) {
        float a[4], bb[4];
#pragma unroll
        for (int i = 0; i < 4; ++i) a[i] = vs[s][ty * 4 + i];
#pragma unroll
        for (int j = 0; j < 4; ++j) bb[j] = ks[s][tx * 4 + j];
#pragma unroll
        for (int i = 0; i < 4; ++i)
#pragma unroll
            for (int j = 0; j < 4; ++j)
                acc[i][j] += a[i] * bb[j];
    }
    float* zp = Z + ((size_t)(b * NH_ + h) * NC_ + c) * (HD_ * HD_);
#pragma unroll
    for (int i = 0; i < 4; ++i)
#pragma unroll
        for (int j = 0; j < 4; ++j)
            zp[(ty * 4 + i) * HD_ + tx * 4 + j] = acc[i][j];
}

// ---------------------------------------------------------------------------
// Exclusive prefix over chunks: H[c] = sum_{c'<c} Z[c']
// ---------------------------------------------------------------------------
__global__ __launch_bounds__(256) void k_prefix(const float* __restrict__ Z,
                                                float* __restrict__ H) {
    const int gid = blockIdx.x * 256 + threadIdx.x;
    const int bh = gid >> 12, pn = gid & 4095;
    const size_t base = (size_t)bh * NC_ * 4096 + pn;
    float acc = 0.f;
    for (int c = 0; c < NC_; ++c) {
        H[base + (size_t)c * 4096] = acc;
        acc += Z[base + (size_t)c * 4096];
    }
}

// ---------------------------------------------------------------------------
// Per chunk: Y = tril(Q Vt) K + Q H_c, then fused gate:
// g <- xt + (Y - xt) * sigmoid(g)      (in place on g)
// ---------------------------------------------------------------------------
__global__ __launch_bounds__(256) void k_attn2g(const float* __restrict__ q,
                                                const float* __restrict__ k,
                                                const float* __restrict__ v,
                                                const float* __restrict__ Hst,
                                                const float* __restrict__ xt,
                                                float* __restrict__ g) {
    const int c = blockIdx.x, h = blockIdx.y, b = blockIdx.z;
    __shared__ float qs[64][65], ks[64][65], vs[64][65];   // vs: V -> S -> H
    const int tid = threadIdx.x;
    const int lr = tid >> 6, lc = tid & 63;
    const size_t base = ((size_t)(b * L_ + c * CS_)) * D_ + h * HD_;
#pragma unroll
    for (int i = 0; i < 16; ++i) {
        qs[lr + i * 4][lc] = q[base + (size_t)(lr + i * 4) * D_ + lc];
        ks[lr + i * 4][lc] = k[base + (size_t)(lr + i * 4) * D_ + lc];
        vs[lr + i * 4][lc] = v[base + (size_t)(lr + i * 4) * D_ + lc];
    }
    __syncthreads();

    const int tx = tid & 15, ty = tid >> 4;

    float sacc[4][4] = {};
#pragma unroll 8
    for (int d = 0; d < 64; ++d) {
        float a[4], bb[4];
#pragma unroll
        for (int i = 0; i < 4; ++i) a[i] = qs[ty * 4 + i][d];
#pragma unroll
        for (int j = 0; j < 4; ++j) bb[j] = vs[tx * 4 + j][d];
#pragma unroll
        for (int i = 0; i < 4; ++i)
#pragma unroll
            for (int j = 0; j < 4; ++j)
                sacc[i][j] += a[i] * bb[j];
    }
#pragma unroll
    for (int i = 0; i < 4; ++i)
#pragma unroll
        for (int j = 0; j < 4; ++j)
            if (tx * 4 + j > ty * 4 + i) sacc[i][j] = 0.f;
    __syncthreads();
#pragma unroll
    for (int i = 0; i < 4; ++i)
#pragma unroll
        for (int j = 0; j < 4; ++j)
            vs[ty * 4 + i][tx * 4 + j] = sacc[i][j];
    __syncthreads();

    float yacc[4][4] = {};
#pragma unroll 8
    for (int jj = 0; jj < 64; ++jj) {
        float s[4], kk[4];
#pragma unroll
        for (int i = 0; i < 4; ++i) s[i] = vs[ty * 4 + i][jj];
#pragma unroll
        for (int n = 0; n < 4; ++n) kk[n] = ks[jj][tx * 4 + n];
#pragma unroll
        for (int i = 0; i < 4; ++i)
#pragma unroll
            for (int n = 0; n < 4; ++n)
                yacc[i][n] += s[i] * kk[n];
    }
    __syncthreads();

    const float* hp = Hst + ((size_t)(b * NH_ + h) * NC_ + c) * 4096;
#pragma unroll
    for (int i = 0; i < 16; ++i)
        vs[lr + i * 4][lc] = hp[(lr + i * 4) * HD_ + lc];
    __syncthreads();
#pragma unroll 8
    for (int p = 0; p < 64; ++p) {
        float a[4], bb[4];
#pragma unroll
        for (int i = 0; i < 4; ++i) a[i] = qs[ty * 4 + i][p];
#pragma unroll
        for (int n = 0; n < 4; ++n) bb[n] = vs[p][tx * 4 + n];
#pragma unroll
        for (int i = 0; i < 4; ++i)
#pragma unroll
            for (int n = 0; n < 4; ++n)
                yacc[i][n] += a[i] * bb[n];
    }

#pragma unroll
    for (int i = 0; i < 4; ++i)
#pragma unroll
        for (int n = 0; n < 4; ++n) {
            const size_t idx = base + (size_t)(ty * 4 + i) * D_ + tx * 4 + n;
            const float gv = 1.f / (1.f + expf(-g[idx]));
            const float xv = xt[idx];
            g[idx] = xv + (yacc[i][n] - xv) * gv;
        }
}

// ---------------------------------------------------------------------------
extern "C" void kernel_launch(void* const* d_in, const int* in_sizes, int n_in,
                              void* d_out, int out_size, void* d_ws, size_t ws_size,
                              hipStream_t stream) {
    const float* x    = (const float*)d_in[0];
    const float* stu  = (const float*)d_in[1];
    const float* Mi   = (const float*)d_in[2];
    const float* Mf   = (const float*)d_in[3];
    const float* wq_w = (const float*)d_in[4];
    const float* wq_b = (const float*)d_in[5];
    const float* wk_w = (const float*)d_in[6];
    const float* wk_b = (const float*)d_in[7];
    const float* wv_w = (const float*)d_in[8];
    const float* wv_b = (const float*)d_in[9];
    const float* wg_w = (const float*)d_in[10];
    const float* wg_b = (const float*)d_in[11];
    const float* wo_w = (const float*)d_in[12];
    const float* wo_b = (const float*)d_in[13];
    float* out = (float*)d_out;

    char* ws = (char*)d_ws;
    size_t o = 0;
    const size_t WSZ = (size_t)D_ * D_;
    unsigned short* wbf = (unsigned short*)(ws + o); o += 6 * WSZ * 2;
    float* ubuf = (float*)(ws + o); o += (size_t)B_ * L_ * R_ * 4;       // u -> q
    float* phi2 = (float*)(ws + o); o += (size_t)L_ * R_ * 4;
    float* xt   = (float*)(ws + o); o += (size_t)B_ * L_ * R_ * 4;
    float* kb   = (float*)(ws + o); o += (size_t)B_ * L_ * D_ * 4;
    float* vb   = (float*)(ws + o); o += (size_t)B_ * L_ * D_ * 4;
    float* gb   = (float*)(ws + o); o += (size_t)B_ * L_ * D_ * 4;
    float* Zb   = (float*)(ws + o); o += (size_t)B_ * NH_ * NC_ * HD_ * HD_ * 4;
    float* Hb   = (float*)(ws + o); o += (size_t)B_ * NH_ * NC_ * HD_ * HD_ * 4;

    // weight order in wbf: Mi, wq, wk, wv, wg, wo  (wq..wg contiguous for k_gemm4)
    unsigned short* Mi_t = wbf + 0 * WSZ;
    unsigned short* wp_t = wbf + 1 * WSZ;   // q,k,v,g block
    unsigned short* wo_t = wbf + 5 * WSZ;

    const dim3 blk(256);
    const dim3 ggrid(D_ / 64, (B_ * L_) / 64);       // (12, 32)
    const dim3 agrid(NC_, NH_, B_);                  // (16, 12, 2)

    k_wt6<<<dim3(12, 12, 6), blk, 0, stream>>>(Mi, wq_w, wk_w, wv_w, wg_w, wo_w, wbf);
    k_phi2<<<dim3(L_ * R_ / 256), blk, 0, stream>>>(stu, Mf, phi2);

    k_gemm<<<ggrid, blk, 0, stream>>>(x, Mi_t, nullptr, ubuf, B_ * L_, R_, D_);
    k_conv<<<dim3(L_ / 2 / 8, B_ * 2), dim3(768), 0, stream>>>(ubuf, phi2, xt);

    k_gemm4<<<dim3(12, 32, 4), blk, 0, stream>>>(x, wp_t,
                                                 wq_b, wk_b, wv_b, wg_b,
                                                 ubuf, kb, vb, gb);

    k_zsum<<<agrid, blk, 0, stream>>>(kb, vb, Zb);
    k_prefix<<<dim3((B_ * NH_ * HD_ * HD_) / 256), blk, 0, stream>>>(Zb, Hb);
    k_attn2g<<<agrid, blk, 0, stream>>>(ubuf, kb, vb, Hb, xt, gb);

    k_gemm<<<ggrid, blk, 0, stream>>>(gb, wo_t, wo_b, out, B_ * L_, D_, D_);
}

// Round 5
// 140.159 us; speedup vs baseline: 5.6874x; 1.1212x over previous
//
#include <hip/hip_runtime.h>
#include <math.h>

#define B_  2
#define L_  1024
#define D_  768
#define NH_ 12
#define HD_ 64
#define K_  24
#define R_  768
#define NC_ 16   // chunks
#define CS_ 64   // chunk size

typedef __bf16 bf16x8 __attribute__((ext_vector_type(8)));
typedef float f32x4 __attribute__((ext_vector_type(4)));
typedef unsigned short u16x8 __attribute__((ext_vector_type(8)));

__device__ inline unsigned short f2bf(float f) {
    union { float f; unsigned u; } v; v.f = f;
    unsigned r = v.u + 0x7FFFu + ((v.u >> 16) & 1u);
    return (unsigned short)(r >> 16);
}

// async global->LDS, 16 B per lane (literal size per guide)
#define GLD_LDS16(g, l)                                                     \
    __builtin_amdgcn_global_load_lds(                                       \
        (const __attribute__((address_space(1))) void*)(g),                 \
        (__attribute__((address_space(3))) void*)(l), 16, 0, 0)

// ---------------------------------------------------------------------------
// All six weight transposes in one launch: Wt[z][n][k] = W_z[k][n] (bf16)
// ---------------------------------------------------------------------------
__global__ __launch_bounds__(256) void k_wt6(const float* __restrict__ w0,
                                             const float* __restrict__ w1,
                                             const float* __restrict__ w2,
                                             const float* __restrict__ w3,
                                             const float* __restrict__ w4,
                                             const float* __restrict__ w5,
                                             unsigned short* __restrict__ Wt) {
    const float* W;
    switch (blockIdx.z) {
        case 0: W = w0; break;
        case 1: W = w1; break;
        case 2: W = w2; break;
        case 3: W = w3; break;
        case 4: W = w4; break;
        default: W = w5; break;
    }
    unsigned short* o = Wt + (size_t)blockIdx.z * D_ * D_;
    __shared__ float t[64][65];
    const int n0 = blockIdx.x * 64, k0 = blockIdx.y * 64;
    const int tid = threadIdx.x;
    const int c = tid & 63, rq = tid >> 6;
#pragma unroll
    for (int i = 0; i < 16; ++i)
        t[rq + i * 4][c] = W[(size_t)(k0 + rq + i * 4) * D_ + n0 + c];
    __syncthreads();
#pragma unroll
    for (int i = 0; i < 16; ++i)
        o[(size_t)(n0 + rq + i * 4) * D_ + k0 + c] = f2bf(t[c][rq + i * 4]);
}

// ---------------------------------------------------------------------------
// x (fp32) -> xbf (bf16), 8 elems/thread
// ---------------------------------------------------------------------------
__global__ __launch_bounds__(256) void k_xbf(const float* __restrict__ x,
                                             unsigned short* __restrict__ xb) {
    const int i8 = (blockIdx.x * 256 + threadIdx.x) * 8;
    float4 f0 = *reinterpret_cast<const float4*>(x + i8);
    float4 f1 = *reinterpret_cast<const float4*>(x + i8 + 4);
    u16x8 p;
    p[0] = f2bf(f0.x); p[1] = f2bf(f0.y); p[2] = f2bf(f0.z); p[3] = f2bf(f0.w);
    p[4] = f2bf(f1.x); p[5] = f2bf(f1.y); p[6] = f2bf(f1.z); p[7] = f2bf(f1.w);
    *reinterpret_cast<u16x8*>(xb + i8) = p;
}

// ---------------------------------------------------------------------------
// phi2[j][r] = 2 * sum_k stu_filters[j][k] * M_filters[k][r]   (L x R, fp32)
// ---------------------------------------------------------------------------
__global__ __launch_bounds__(256) void k_phi2(const float* __restrict__ F,
                                              const float* __restrict__ Mf,
                                              float* __restrict__ phi2) {
    int idx = blockIdx.x * 256 + threadIdx.x;
    int r = idx % R_;
    int j = idx / R_;
    float acc = 0.f;
#pragma unroll
    for (int kk = 0; kk < K_; ++kk)
        acc += F[j * K_ + kk] * Mf[kk * R_ + r];
    phi2[idx] = 2.f * acc;
}

// ---------------------------------------------------------------------------
// bf16 MFMA GEMM, m97 structure: A[M][Kd] bf16 row-major, Bt[N][Kd] bf16,
// C fp32 (+bias). Tile 128x64, BK=64, 4 waves x (64x32) = 4x2 fragments.
// Staging via global_load_lds width 16, linear LDS.
// ---------------------------------------------------------------------------
__device__ __forceinline__ void gemm_body(const unsigned short* __restrict__ A,
                                          const unsigned short* __restrict__ Bt,
                                          const float* __restrict__ bias,
                                          float* __restrict__ C,
                                          int N, int Kd,
                                          int bm, int bn, int tid) {
    __shared__ unsigned short As[128 * 64];   // 16 KB
    __shared__ unsigned short Bs[64 * 64];    //  8 KB
    const int lane = tid & 63, wave = tid >> 6;
    const int wm = (wave >> 1) * 64, wn = (wave & 1) * 32;
    const int l15 = lane & 15, lg = lane >> 4;

    f32x4 acc[4][2] = {};

    for (int k0 = 0; k0 < Kd; k0 += 64) {
        __syncthreads();
#pragma unroll
        for (int q = 0; q < 4; ++q) {
            const int s = q * 256 + tid;           // 0..1023
            const int row = s >> 3, c8 = s & 7;
            GLD_LDS16(A + (size_t)(bm + row) * Kd + k0 + c8 * 8, As + s * 8);
        }
#pragma unroll
        for (int q = 0; q < 2; ++q) {
            const int s = q * 256 + tid;           // 0..511
            const int row = s >> 3, c8 = s & 7;
            GLD_LDS16(Bt + (size_t)(bn + row) * Kd + k0 + c8 * 8, Bs + s * 8);
        }
        __syncthreads();                           // drains vmcnt before barrier
#pragma unroll
        for (int ks = 0; ks < 2; ++ks) {
            const int kb = ks * 32 + lg * 8;
            bf16x8 a[4], b[2];
#pragma unroll
            for (int f = 0; f < 4; ++f)
                a[f] = *reinterpret_cast<const bf16x8*>(&As[(wm + f * 16 + l15) * 64 + kb]);
#pragma unroll
            for (int f = 0; f < 2; ++f)
                b[f] = *reinterpret_cast<const bf16x8*>(&Bs[(wn + f * 16 + l15) * 64 + kb]);
#pragma unroll
            for (int fm = 0; fm < 4; ++fm)
#pragma unroll
                for (int fn = 0; fn < 2; ++fn)
                    acc[fm][fn] = __builtin_amdgcn_mfma_f32_16x16x32_bf16(
                        a[fm], b[fn], acc[fm][fn], 0, 0, 0);
        }
    }

#pragma unroll
    for (int fm = 0; fm < 4; ++fm)
#pragma unroll
        for (int fn = 0; fn < 2; ++fn) {
            const int col = bn + wn + fn * 16 + l15;
            const float bv = bias ? bias[col] : 0.f;
#pragma unroll
            for (int j = 0; j < 4; ++j) {
                const int row = bm + wm + fm * 16 + lg * 4 + j;
                C[(size_t)row * N + col] = acc[fm][fn][j] + bv;
            }
        }
}

__global__ __launch_bounds__(256) void k_gemm(const unsigned short* __restrict__ A,
                                              const unsigned short* __restrict__ Bt,
                                              const float* __restrict__ bias,
                                              float* __restrict__ C,
                                              int N, int Kd) {
    gemm_body(A, Bt, bias, C, N, Kd, blockIdx.y * 128, blockIdx.x * 64, threadIdx.x);
}

// 4 projections (q,k,v,g) share A=xbf; blockIdx.z selects weight/bias/output.
__global__ __launch_bounds__(256) void k_gemm4(const unsigned short* __restrict__ A,
                                               const unsigned short* __restrict__ wt,
                                               const float* __restrict__ b0,
                                               const float* __restrict__ b1,
                                               const float* __restrict__ b2,
                                               const float* __restrict__ b3,
                                               float* __restrict__ c0,
                                               float* __restrict__ c1,
                                               float* __restrict__ c2,
                                               float* __restrict__ c3) {
    const float* bias; float* C;
    switch (blockIdx.z) {
        case 0: bias = b0; C = c0; break;
        case 1: bias = b1; C = c1; break;
        case 2: bias = b2; C = c2; break;
        default: bias = b3; C = c3; break;
    }
    const unsigned short* Bt = wt + (size_t)blockIdx.z * D_ * D_;
    gemm_body(A, Bt, bias, C, D_, D_, blockIdx.y * 128, blockIdx.x * 64, threadIdx.x);
}

// ---------------------------------------------------------------------------
// Parity-split causal conv, register sliding window, 4-way n-split per block.
// ---------------------------------------------------------------------------
__global__ __launch_bounds__(768) void k_conv(const float* __restrict__ u,
                                              const float* __restrict__ phi2,
                                              float* __restrict__ xt) {
    __shared__ f32x4 red[4][8][192];            // 98304 B
    const int tid = threadIdx.x;
    const int g   = tid / 192;
    const int lr  = tid % 192;
    const int r   = lr * 4;
    const int m0  = blockIdx.x * 8;
    const int bp  = blockIdx.y;
    const int b   = bp >> 1, p = bp & 1;

    f32x4 acc[8] = {};
    f32x4 w[8]   = {};

    const int ns = g * 128;
    const int ne = min(ns + 128, m0 + 8);

    if (ns < ne) {
        if (g > 0) {
#pragma unroll
            for (int j = 1; j <= 7; ++j)
                w[(8 - j) & 7] =
                    *reinterpret_cast<const f32x4*>(phi2 + (size_t)(2 * (ns - j)) * R_ + r);
        }
        const float* pp = phi2 + (size_t)(2 * ns) * R_ + r;
        const float* up = u + ((size_t)(b * L_) + (size_t)(2 * (m0 + 7 - ns) + p)) * R_ + r;
        for (int i = ns; i < ne; i += 8) {
#pragma unroll
            for (int k = 0; k < 8; ++k) {
                const f32x4 wn = *reinterpret_cast<const f32x4*>(pp);
                const f32x4 un = *reinterpret_cast<const f32x4*>(up);
                w[k] = wn;
#pragma unroll
                for (int a = 0; a < 8; ++a)
                    acc[a] += w[(k + a + 1) & 7] * un;
                pp += 2 * R_;
                up -= 2 * R_;
            }
        }
    }

#pragma unroll
    for (int a = 0; a < 8; ++a) red[g][a][lr] = acc[a];
    __syncthreads();

#pragma unroll
    for (int q2 = 0; q2 < 2; ++q2) {
        const int sl = q2 * 768 + tid;
        const int a  = sl / 192, l = sl % 192;
        const f32x4 s = red[0][a][l] + red[1][a][l] + red[2][a][l] + red[3][a][l];
        *reinterpret_cast<f32x4*>(
            xt + ((size_t)(b * L_) + (size_t)(2 * (m0 + a) + p)) * R_ + l * 4) = s;
    }
}

// ---------------------------------------------------------------------------
// Z[b,h,c,p,n] = sum_{s in chunk c} v[s][p] * k[s][n]
// ---------------------------------------------------------------------------
__global__ __launch_bounds__(256) void k_zsum(const float* __restrict__ k,
                                              const float* __restrict__ v,
                                              float* __restrict__ Z) {
    const int c = blockIdx.x, h = blockIdx.y, b = blockIdx.z;
    __shared__ float ks[64][65], vs[64][65];
    const int tid = threadIdx.x;
    const int lr = tid >> 6, lc = tid & 63;
    const size_t base = ((size_t)(b * L_ + c * CS_)) * D_ + h * HD_;
#pragma unroll
    for (int i = 0; i < 16; ++i) {
        ks[lr + i * 4][lc] = k[base + (size_t)(lr + i * 4) * D_ + lc];
        vs[lr + i * 4][lc] = v[base + (size_t)(lr + i * 4) * D_ + lc];
    }
    __syncthreads();
    const int tx = tid & 15, ty = tid >> 4;
    float acc[4][4] = {};
#pragma unroll 8
    for (int s = 0; s < 64; ++s) {
        float a[4], bb[4];
#pragma unroll
        for (int i = 0; i < 4; ++i) a[i] = vs[s][ty * 4 + i];
#pragma unroll
        for (int j = 0; j < 4; ++j) bb[j] = ks[s][tx * 4 + j];
#pragma unroll
        for (int i = 0; i < 4; ++i)
#pragma unroll
            for (int j = 0; j < 4; ++j)
                acc[i][j] += a[i] * bb[j];
    }
    float* zp = Z + ((size_t)(b * NH_ + h) * NC_ + c) * (HD_ * HD_);
#pragma unroll
    for (int i = 0; i < 4; ++i)
#pragma unroll
        for (int j = 0; j < 4; ++j)
            zp[(ty * 4 + i) * HD_ + tx * 4 + j] = acc[i][j];
}

// ---------------------------------------------------------------------------
// Exclusive prefix over chunks: H[c] = sum_{c'<c} Z[c']
// ---------------------------------------------------------------------------
__global__ __launch_bounds__(256) void k_prefix(const float* __restrict__ Z,
                                                float* __restrict__ H) {
    const int gid = blockIdx.x * 256 + threadIdx.x;
    const int bh = gid >> 12, pn = gid & 4095;
    const size_t base = (size_t)bh * NC_ * 4096 + pn;
    float acc = 0.f;
    for (int c = 0; c < NC_; ++c) {
        H[base + (size_t)c * 4096] = acc;
        acc += Z[base + (size_t)c * 4096];
    }
}

// ---------------------------------------------------------------------------
// Per chunk: Y = tril(Q Vt) K + Q H_c, fused gate, bf16 output:
// gx <- bf16( xt + (Y - xt) * sigmoid(g) )
// ---------------------------------------------------------------------------
__global__ __launch_bounds__(256) void k_attn2g(const float* __restrict__ q,
                                                const float* __restrict__ k,
                                                const float* __restrict__ v,
                                                const float* __restrict__ Hst,
                                                const float* __restrict__ xt,
                                                const float* __restrict__ g,
                                                unsigned short* __restrict__ gx) {
    const int c = blockIdx.x, h = blockIdx.y, b = blockIdx.z;
    __shared__ float qs[64][65], ks[64][65], vs[64][65];   // vs: V -> S -> H
    const int tid = threadIdx.x;
    const int lr = tid >> 6, lc = tid & 63;
    const size_t base = ((size_t)(b * L_ + c * CS_)) * D_ + h * HD_;
#pragma unroll
    for (int i = 0; i < 16; ++i) {
        qs[lr + i * 4][lc] = q[base + (size_t)(lr + i * 4) * D_ + lc];
        ks[lr + i * 4][lc] = k[base + (size_t)(lr + i * 4) * D_ + lc];
        vs[lr + i * 4][lc] = v[base + (size_t)(lr + i * 4) * D_ + lc];
    }
    __syncthreads();

    const int tx = tid & 15, ty = tid >> 4;

    float sacc[4][4] = {};
#pragma unroll 8
    for (int d = 0; d < 64; ++d) {
        float a[4], bb[4];
#pragma unroll
        for (int i = 0; i < 4; ++i) a[i] = qs[ty * 4 + i][d];
#pragma unroll
        for (int j = 0; j < 4; ++j) bb[j] = vs[tx * 4 + j][d];
#pragma unroll
        for (int i = 0; i < 4; ++i)
#pragma unroll
            for (int j = 0; j < 4; ++j)
                sacc[i][j] += a[i] * bb[j];
    }
#pragma unroll
    for (int i = 0; i < 4; ++i)
#pragma unroll
        for (int j = 0; j < 4; ++j)
            if (tx * 4 + j > ty * 4 + i) sacc[i][j] = 0.f;
    __syncthreads();
#pragma unroll
    for (int i = 0; i < 4; ++i)
#pragma unroll
        for (int j = 0; j < 4; ++j)
            vs[ty * 4 + i][tx * 4 + j] = sacc[i][j];
    __syncthreads();

    float yacc[4][4] = {};
#pragma unroll 8
    for (int jj = 0; jj < 64; ++jj) {
        float s[4], kk[4];
#pragma unroll
        for (int i = 0; i < 4; ++i) s[i] = vs[ty * 4 + i][jj];
#pragma unroll
        for (int n = 0; n < 4; ++n) kk[n] = ks[jj][tx * 4 + n];
#pragma unroll
        for (int i = 0; i < 4; ++i)
#pragma unroll
            for (int n = 0; n < 4; ++n)
                yacc[i][n] += s[i] * kk[n];
    }
    __syncthreads();

    const float* hp = Hst + ((size_t)(b * NH_ + h) * NC_ + c) * 4096;
#pragma unroll
    for (int i = 0; i < 16; ++i)
        vs[lr + i * 4][lc] = hp[(lr + i * 4) * HD_ + lc];
    __syncthreads();
#pragma unroll 8
    for (int p = 0; p < 64; ++p) {
        float a[4], bb[4];
#pragma unroll
        for (int i = 0; i < 4; ++i) a[i] = qs[ty * 4 + i][p];
#pragma unroll
        for (int n = 0; n < 4; ++n) bb[n] = vs[p][tx * 4 + n];
#pragma unroll
        for (int i = 0; i < 4; ++i)
#pragma unroll
            for (int n = 0; n < 4; ++n)
                yacc[i][n] += a[i] * bb[n];
    }

#pragma unroll
    for (int i = 0; i < 4; ++i)
#pragma unroll
        for (int n = 0; n < 4; ++n) {
            const size_t idx = base + (size_t)(ty * 4 + i) * D_ + tx * 4 + n;
            const float gv = 1.f / (1.f + expf(-g[idx]));
            const float xv = xt[idx];
            gx[idx] = f2bf(xv + (yacc[i][n] - xv) * gv);
        }
}

// ---------------------------------------------------------------------------
extern "C" void kernel_launch(void* const* d_in, const int* in_sizes, int n_in,
                              void* d_out, int out_size, void* d_ws, size_t ws_size,
                              hipStream_t stream) {
    const float* x    = (const float*)d_in[0];
    const float* stu  = (const float*)d_in[1];
    const float* Mi   = (const float*)d_in[2];
    const float* Mf   = (const float*)d_in[3];
    const float* wq_w = (const float*)d_in[4];
    const float* wq_b = (const float*)d_in[5];
    const float* wk_w = (const float*)d_in[6];
    const float* wk_b = (const float*)d_in[7];
    const float* wv_w = (const float*)d_in[8];
    const float* wv_b = (const float*)d_in[9];
    const float* wg_w = (const float*)d_in[10];
    const float* wg_b = (const float*)d_in[11];
    const float* wo_w = (const float*)d_in[12];
    const float* wo_b = (const float*)d_in[13];
    float* out = (float*)d_out;

    char* ws = (char*)d_ws;
    size_t o = 0;
    const size_t WSZ = (size_t)D_ * D_;
    unsigned short* wbf = (unsigned short*)(ws + o); o += 6 * WSZ * 2;
    unsigned short* xbf = (unsigned short*)(ws + o); o += (size_t)B_ * L_ * D_ * 2;
    unsigned short* gx  = (unsigned short*)(ws + o); o += (size_t)B_ * L_ * D_ * 2;
    float* ubuf = (float*)(ws + o); o += (size_t)B_ * L_ * R_ * 4;       // u -> q
    float* phi2 = (float*)(ws + o); o += (size_t)L_ * R_ * 4;
    float* xt   = (float*)(ws + o); o += (size_t)B_ * L_ * R_ * 4;
    float* kb   = (float*)(ws + o); o += (size_t)B_ * L_ * D_ * 4;
    float* vb   = (float*)(ws + o); o += (size_t)B_ * L_ * D_ * 4;
    float* gb   = (float*)(ws + o); o += (size_t)B_ * L_ * D_ * 4;
    float* Zb   = (float*)(ws + o); o += (size_t)B_ * NH_ * NC_ * HD_ * HD_ * 4;
    float* Hb   = (float*)(ws + o); o += (size_t)B_ * NH_ * NC_ * HD_ * HD_ * 4;

    // weight order in wbf: Mi, wq, wk, wv, wg, wo  (wq..wg contiguous)
    unsigned short* Mi_t = wbf + 0 * WSZ;
    unsigned short* wp_t = wbf + 1 * WSZ;
    unsigned short* wo_t = wbf + 5 * WSZ;

    const dim3 blk(256);
    const dim3 ggrid(D_ / 64, (B_ * L_) / 128);      // (12, 16)
    const dim3 agrid(NC_, NH_, B_);                  // (16, 12, 2)

    k_wt6<<<dim3(12, 12, 6), blk, 0, stream>>>(Mi, wq_w, wk_w, wv_w, wg_w, wo_w, wbf);
    k_xbf<<<dim3((B_ * L_ * D_ / 8) / 256), blk, 0, stream>>>(x, xbf);
    k_phi2<<<dim3(L_ * R_ / 256), blk, 0, stream>>>(stu, Mf, phi2);

    k_gemm<<<ggrid, blk, 0, stream>>>(xbf, Mi_t, nullptr, ubuf, R_, D_);
    k_conv<<<dim3(L_ / 2 / 8, B_ * 2), dim3(768), 0, stream>>>(ubuf, phi2, xt);

    k_gemm4<<<dim3(12, 16, 4), blk, 0, stream>>>(xbf, wp_t,
                                                 wq_b, wk_b, wv_b, wg_b,
                                                 ubuf, kb, vb, gb);

    k_zsum<<<agrid, blk, 0, stream>>>(kb, vb, Zb);
    k_prefix<<<dim3((B_ * NH_ * HD_ * HD_) / 256), blk, 0, stream>>>(Zb, Hb);
    k_attn2g<<<agrid, blk, 0, stream>>>(ubuf, kb, vb, Hb, xt, gb, gx);

    k_gemm<<<ggrid, blk, 0, stream>>>(gx, wo_t, wo_b, out, D_, D_);
}

// Round 6
// 127.370 us; speedup vs baseline: 6.2584x; 1.1004x over previous
//
#include <hip/hip_runtime.h>
#include <math.h>

#define B_  2
#define L_  1024
#define D_  768
#define NH_ 12
#define HD_ 64
#define K_  24
#define R_  768
#define NC_ 16   // chunks
#define CS_ 64   // chunk size

typedef __bf16 bf16x8 __attribute__((ext_vector_type(8)));
typedef float f32x4 __attribute__((ext_vector_type(4)));
typedef unsigned short u16x8 __attribute__((ext_vector_type(8)));

__device__ inline unsigned short f2bf(float f) {
    union { float f; unsigned u; } v; v.f = f;
    unsigned r = v.u + 0x7FFFu + ((v.u >> 16) & 1u);
    return (unsigned short)(r >> 16);
}

// async global->LDS, 16 B per lane (literal size per guide)
#define GLD_LDS16(g, l)                                                     \
    __builtin_amdgcn_global_load_lds(                                       \
        (const __attribute__((address_space(1))) void*)(g),                 \
        (__attribute__((address_space(3))) void*)(l), 16, 0, 0)

// ---------------------------------------------------------------------------
// Fused prep: [0,864) weight transposes (6x 768x768 fp32 -> bf16 T),
//             [864,1632) x fp32 -> bf16, [1632,4704) phi2 = 2*stu@Mf (fp32)
// ---------------------------------------------------------------------------
__global__ __launch_bounds__(256) void k_prep(const float* __restrict__ w0,
                                              const float* __restrict__ w1,
                                              const float* __restrict__ w2,
                                              const float* __restrict__ w3,
                                              const float* __restrict__ w4,
                                              const float* __restrict__ w5,
                                              unsigned short* __restrict__ Wt,
                                              const float* __restrict__ x,
                                              unsigned short* __restrict__ xb,
                                              const float* __restrict__ F,
                                              const float* __restrict__ Mf,
                                              float* __restrict__ phi2) {
    const int bid = blockIdx.x;
    const int tid = threadIdx.x;
    if (bid < 864) {
        const int z = bid / 144, rem = bid % 144;
        const float* W;
        switch (z) {
            case 0: W = w0; break;
            case 1: W = w1; break;
            case 2: W = w2; break;
            case 3: W = w3; break;
            case 4: W = w4; break;
            default: W = w5; break;
        }
        unsigned short* o = Wt + (size_t)z * D_ * D_;
        __shared__ float t[64][65];
        const int n0 = (rem % 12) * 64, k0 = (rem / 12) * 64;
        const int c = tid & 63, rq = tid >> 6;
#pragma unroll
        for (int i = 0; i < 16; ++i)
            t[rq + i * 4][c] = W[(size_t)(k0 + rq + i * 4) * D_ + n0 + c];
        __syncthreads();
#pragma unroll
        for (int i = 0; i < 16; ++i)
            o[(size_t)(n0 + rq + i * 4) * D_ + k0 + c] = f2bf(t[c][rq + i * 4]);
    } else if (bid < 1632) {
        const int i8 = ((bid - 864) * 256 + tid) * 8;
        float4 f0 = *reinterpret_cast<const float4*>(x + i8);
        float4 f1 = *reinterpret_cast<const float4*>(x + i8 + 4);
        u16x8 p;
        p[0] = f2bf(f0.x); p[1] = f2bf(f0.y); p[2] = f2bf(f0.z); p[3] = f2bf(f0.w);
        p[4] = f2bf(f1.x); p[5] = f2bf(f1.y); p[6] = f2bf(f1.z); p[7] = f2bf(f1.w);
        *reinterpret_cast<u16x8*>(xb + i8) = p;
    } else {
        const int idx = (bid - 1632) * 256 + tid;
        const int r = idx % R_;
        const int j = idx / R_;
        float acc = 0.f;
#pragma unroll
        for (int kk = 0; kk < K_; ++kk)
            acc += F[j * K_ + kk] * Mf[kk * R_ + r];
        phi2[idx] = 2.f * acc;
    }
}

// ---------------------------------------------------------------------------
// bf16 MFMA GEMM, 2-phase pipelined (double-buffered LDS, loads for tile t+1
// issued before computing tile t, ONE barrier per K-tile).
// Tile 128x64, BK=64, 4 waves x (64x32) = 4x2 fragments of 16x16x32.
// ---------------------------------------------------------------------------
__device__ __forceinline__ void gemm_body(const unsigned short* __restrict__ A,
                                          const unsigned short* __restrict__ Bt,
                                          const float* __restrict__ bias,
                                          float* __restrict__ C,
                                          int N, int Kd,
                                          int bm, int bn, int tid) {
    __shared__ unsigned short As[2][128 * 64];   // 2 x 16 KB
    __shared__ unsigned short Bs[2][64 * 64];    // 2 x  8 KB
    const int lane = tid & 63, wave = tid >> 6;
    const int wm = (wave >> 1) * 64, wn = (wave & 1) * 32;
    const int l15 = lane & 15, lg = lane >> 4;

    f32x4 acc[4][2] = {};

    auto stage = [&](int buf, int k0) {
#pragma unroll
        for (int q = 0; q < 4; ++q) {
            const int s = q * 256 + tid;           // 0..1023
            GLD_LDS16(A + (size_t)(bm + (s >> 3)) * Kd + k0 + (s & 7) * 8,
                      &As[buf][s * 8]);
        }
#pragma unroll
        for (int q = 0; q < 2; ++q) {
            const int s = q * 256 + tid;           // 0..511
            GLD_LDS16(Bt + (size_t)(bn + (s >> 3)) * Kd + k0 + (s & 7) * 8,
                      &Bs[buf][s * 8]);
        }
    };

    stage(0, 0);
    __syncthreads();                               // drain prologue loads
    int cur = 0;
    const int nt = Kd / 64;
    for (int t = 0; t < nt; ++t) {
        if (t + 1 < nt) stage(cur ^ 1, (t + 1) * 64);   // prefetch in flight
#pragma unroll
        for (int ks = 0; ks < 2; ++ks) {
            const int kb = ks * 32 + lg * 8;
            bf16x8 a[4], b[2];
#pragma unroll
            for (int f = 0; f < 4; ++f)
                a[f] = *reinterpret_cast<const bf16x8*>(
                    &As[cur][(wm + f * 16 + l15) * 64 + kb]);
#pragma unroll
            for (int f = 0; f < 2; ++f)
                b[f] = *reinterpret_cast<const bf16x8*>(
                    &Bs[cur][(wn + f * 16 + l15) * 64 + kb]);
#pragma unroll
            for (int fm = 0; fm < 4; ++fm)
#pragma unroll
                for (int fn = 0; fn < 2; ++fn)
                    acc[fm][fn] = __builtin_amdgcn_mfma_f32_16x16x32_bf16(
                        a[fm], b[fn], acc[fm][fn], 0, 0, 0);
        }
        __syncthreads();                           // drains prefetch + read fence
        cur ^= 1;
    }

#pragma unroll
    for (int fm = 0; fm < 4; ++fm)
#pragma unroll
        for (int fn = 0; fn < 2; ++fn) {
            const int col = bn + wn + fn * 16 + l15;
            const float bv = bias ? bias[col] : 0.f;
#pragma unroll
            for (int j = 0; j < 4; ++j) {
                const int row = bm + wm + fm * 16 + lg * 4 + j;
                C[(size_t)row * N + col] = acc[fm][fn][j] + bv;
            }
        }
}

__global__ __launch_bounds__(256) void k_gemm(const unsigned short* __restrict__ A,
                                              const unsigned short* __restrict__ Bt,
                                              const float* __restrict__ bias,
                                              float* __restrict__ C,
                                              int N, int Kd) {
    gemm_body(A, Bt, bias, C, N, Kd, blockIdx.y * 128, blockIdx.x * 64, threadIdx.x);
}

// all 5 x-projections (u,q,k,v,g) share A=xbf; blockIdx.z selects weight/bias/out
__global__ __launch_bounds__(256) void k_gemm5(const unsigned short* __restrict__ A,
                                               const unsigned short* __restrict__ wt,
                                               const float* __restrict__ bq,
                                               const float* __restrict__ bk,
                                               const float* __restrict__ bv,
                                               const float* __restrict__ bg,
                                               float* __restrict__ cu,
                                               float* __restrict__ cq,
                                               float* __restrict__ ck,
                                               float* __restrict__ cv,
                                               float* __restrict__ cg) {
    const float* bias; float* C;
    switch (blockIdx.z) {
        case 0: bias = nullptr; C = cu; break;
        case 1: bias = bq; C = cq; break;
        case 2: bias = bk; C = ck; break;
        case 3: bias = bv; C = cv; break;
        default: bias = bg; C = cg; break;
    }
    const unsigned short* Bt = wt + (size_t)blockIdx.z * D_ * D_;
    gemm_body(A, Bt, bias, C, D_, D_, blockIdx.y * 128, blockIdx.x * 64, threadIdx.x);
}

// ---------------------------------------------------------------------------
// Parity-split causal conv, register sliding window, 4-way n-split per block.
// ---------------------------------------------------------------------------
__global__ __launch_bounds__(768) void k_conv(const float* __restrict__ u,
                                              const float* __restrict__ phi2,
                                              float* __restrict__ xt) {
    __shared__ f32x4 red[4][8][192];            // 98304 B
    const int tid = threadIdx.x;
    const int g   = tid / 192;
    const int lr  = tid % 192;
    const int r   = lr * 4;
    const int m0  = blockIdx.x * 8;
    const int bp  = blockIdx.y;
    const int b   = bp >> 1, p = bp & 1;

    f32x4 acc[8] = {};
    f32x4 w[8]   = {};

    const int ns = g * 128;
    const int ne = min(ns + 128, m0 + 8);

    if (ns < ne) {
        if (g > 0) {
#pragma unroll
            for (int j = 1; j <= 7; ++j)
                w[(8 - j) & 7] =
                    *reinterpret_cast<const f32x4*>(phi2 + (size_t)(2 * (ns - j)) * R_ + r);
        }
        const float* pp = phi2 + (size_t)(2 * ns) * R_ + r;
        const float* up = u + ((size_t)(b * L_) + (size_t)(2 * (m0 + 7 - ns) + p)) * R_ + r;
        for (int i = ns; i < ne; i += 8) {
#pragma unroll
            for (int k = 0; k < 8; ++k) {
                const f32x4 wn = *reinterpret_cast<const f32x4*>(pp);
                const f32x4 un = *reinterpret_cast<const f32x4*>(up);
                w[k] = wn;
#pragma unroll
                for (int a = 0; a < 8; ++a)
                    acc[a] += w[(k + a + 1) & 7] * un;
                pp += 2 * R_;
                up -= 2 * R_;
            }
        }
    }

#pragma unroll
    for (int a = 0; a < 8; ++a) red[g][a][lr] = acc[a];
    __syncthreads();

#pragma unroll
    for (int q2 = 0; q2 < 2; ++q2) {
        const int sl = q2 * 768 + tid;
        const int a  = sl / 192, l = sl % 192;
        const f32x4 s = red[0][a][l] + red[1][a][l] + red[2][a][l] + red[3][a][l];
        *reinterpret_cast<f32x4*>(
            xt + ((size_t)(b * L_) + (size_t)(2 * (m0 + a) + p)) * R_ + l * 4) = s;
    }
}

// ---------------------------------------------------------------------------
// Z[b,h,c,p,n] = sum_{s in chunk c} v[s][p] * k[s][n]
// ---------------------------------------------------------------------------
__global__ __launch_bounds__(256) void k_zsum(const float* __restrict__ k,
                                              const float* __restrict__ v,
                                              float* __restrict__ Z) {
    const int c = blockIdx.x, h = blockIdx.y, b = blockIdx.z;
    __shared__ float ks[64][65], vs[64][65];
    const int tid = threadIdx.x;
    const int lr = tid >> 6, lc = tid & 63;
    const size_t base = ((size_t)(b * L_ + c * CS_)) * D_ + h * HD_;
#pragma unroll
    for (int i = 0; i < 16; ++i) {
        ks[lr + i * 4][lc] = k[base + (size_t)(lr + i * 4) * D_ + lc];
        vs[lr + i * 4][lc] = v[base + (size_t)(lr + i * 4) * D_ + lc];
    }
    __syncthreads();
    const int tx = tid & 15, ty = tid >> 4;
    float acc[4][4] = {};
#pragma unroll 8
    for (int s = 0; s < 64; ++s) {
        float a[4], bb[4];
#pragma unroll
        for (int i = 0; i < 4; ++i) a[i] = vs[s][ty * 4 + i];
#pragma unroll
        for (int j = 0; j < 4; ++j) bb[j] = ks[s][tx * 4 + j];
#pragma unroll
        for (int i = 0; i < 4; ++i)
#pragma unroll
            for (int j = 0; j < 4; ++j)
                acc[i][j] += a[i] * bb[j];
    }
    float* zp = Z + ((size_t)(b * NH_ + h) * NC_ + c) * (HD_ * HD_);
#pragma unroll
    for (int i = 0; i < 4; ++i)
#pragma unroll
        for (int j = 0; j < 4; ++j)
            zp[(ty * 4 + i) * HD_ + tx * 4 + j] = acc[i][j];
}

// ---------------------------------------------------------------------------
// Per chunk: H_c = sum_{c'<c} Z[c'] (fused prefix), Y = tril(Q Vt) K + Q H_c,
// fused gate, bf16 output: gx <- bf16( xt + (Y - xt) * sigmoid(g) )
// ---------------------------------------------------------------------------
__global__ __launch_bounds__(256) void k_attn2g(const float* __restrict__ q,
                                                const float* __restrict__ k,
                                                const float* __restrict__ v,
                                                const float* __restrict__ Zb,
                                                const float* __restrict__ xt,
                                                const float* __restrict__ g,
                                                unsigned short* __restrict__ gx) {
    const int c = blockIdx.x, h = blockIdx.y, b = blockIdx.z;
    __shared__ float qs[64][65], ks[64][65], vs[64][65];   // vs: V -> S -> H
    const int tid = threadIdx.x;
    const int lr = tid >> 6, lc = tid & 63;
    const size_t base = ((size_t)(b * L_ + c * CS_)) * D_ + h * HD_;
#pragma unroll
    for (int i = 0; i < 16; ++i) {
        qs[lr + i * 4][lc] = q[base + (size_t)(lr + i * 4) * D_ + lc];
        ks[lr + i * 4][lc] = k[base + (size_t)(lr + i * 4) * D_ + lc];
        vs[lr + i * 4][lc] = v[base + (size_t)(lr + i * 4) * D_ + lc];
    }
    __syncthreads();

    const int tx = tid & 15, ty = tid >> 4;

    float sacc[4][4] = {};
#pragma unroll 8
    for (int d = 0; d < 64; ++d) {
        float a[4], bb[4];
#pragma unroll
        for (int i = 0; i < 4; ++i) a[i] = qs[ty * 4 + i][d];
#pragma unroll
        for (int j = 0; j < 4; ++j) bb[j] = vs[tx * 4 + j][d];
#pragma unroll
        for (int i = 0; i < 4; ++i)
#pragma unroll
            for (int j = 0; j < 4; ++j)
                sacc[i][j] += a[i] * bb[j];
    }
#pragma unroll
    for (int i = 0; i < 4; ++i)
#pragma unroll
        for (int j = 0; j < 4; ++j)
            if (tx * 4 + j > ty * 4 + i) sacc[i][j] = 0.f;

    // fused exclusive prefix of Z while S is still in registers
    float hreg[16] = {};
    const float* zb = Zb + (size_t)(b * NH_ + h) * NC_ * 4096;
    for (int c2 = 0; c2 < c; ++c2) {
        const float* zp = zb + (size_t)c2 * 4096;
#pragma unroll
        for (int i = 0; i < 16; ++i)
            hreg[i] += zp[(lr + i * 4) * HD_ + lc];
    }

    __syncthreads();                   // everyone done reading vs (V)
#pragma unroll
    for (int i = 0; i < 4; ++i)
#pragma unroll
        for (int j = 0; j < 4; ++j)
            vs[ty * 4 + i][tx * 4 + j] = sacc[i][j];
    __syncthreads();

    float yacc[4][4] = {};
#pragma unroll 8
    for (int jj = 0; jj < 64; ++jj) {
        float s[4], kk[4];
#pragma unroll
        for (int i = 0; i < 4; ++i) s[i] = vs[ty * 4 + i][jj];
#pragma unroll
        for (int n = 0; n < 4; ++n) kk[n] = ks[jj][tx * 4 + n];
#pragma unroll
        for (int i = 0; i < 4; ++i)
#pragma unroll
            for (int n = 0; n < 4; ++n)
                yacc[i][n] += s[i] * kk[n];
    }
    __syncthreads();                   // everyone done reading vs (S)

#pragma unroll
    for (int i = 0; i < 16; ++i)
        vs[lr + i * 4][lc] = hreg[i];
    __syncthreads();
#pragma unroll 8
    for (int p = 0; p < 64; ++p) {
        float a[4], bb[4];
#pragma unroll
        for (int i = 0; i < 4; ++i) a[i] = qs[ty * 4 + i][p];
#pragma unroll
        for (int n = 0; n < 4; ++n) bb[n] = vs[p][tx * 4 + n];
#pragma unroll
        for (int i = 0; i < 4; ++i)
#pragma unroll
            for (int n = 0; n < 4; ++n)
                yacc[i][n] += a[i] * bb[n];
    }

#pragma unroll
    for (int i = 0; i < 4; ++i)
#pragma unroll
        for (int n = 0; n < 4; ++n) {
            const size_t idx = base + (size_t)(ty * 4 + i) * D_ + tx * 4 + n;
            const float gv = 1.f / (1.f + expf(-g[idx]));
            const float xv = xt[idx];
            gx[idx] = f2bf(xv + (yacc[i][n] - xv) * gv);
        }
}

// ---------------------------------------------------------------------------
extern "C" void kernel_launch(void* const* d_in, const int* in_sizes, int n_in,
                              void* d_out, int out_size, void* d_ws, size_t ws_size,
                              hipStream_t stream) {
    const float* x    = (const float*)d_in[0];
    const float* stu  = (const float*)d_in[1];
    const float* Mi   = (const float*)d_in[2];
    const float* Mf   = (const float*)d_in[3];
    const float* wq_w = (const float*)d_in[4];
    const float* wq_b = (const float*)d_in[5];
    const float* wk_w = (const float*)d_in[6];
    const float* wk_b = (const float*)d_in[7];
    const float* wv_w = (const float*)d_in[8];
    const float* wv_b = (const float*)d_in[9];
    const float* wg_w = (const float*)d_in[10];
    const float* wg_b = (const float*)d_in[11];
    const float* wo_w = (const float*)d_in[12];
    const float* wo_b = (const float*)d_in[13];
    float* out = (float*)d_out;

    char* ws = (char*)d_ws;
    size_t o = 0;
    const size_t WSZ = (size_t)D_ * D_;
    unsigned short* wbf = (unsigned short*)(ws + o); o += 6 * WSZ * 2;
    unsigned short* xbf = (unsigned short*)(ws + o); o += (size_t)B_ * L_ * D_ * 2;
    unsigned short* gx  = (unsigned short*)(ws + o); o += (size_t)B_ * L_ * D_ * 2;
    float* ubuf = (float*)(ws + o); o += (size_t)B_ * L_ * R_ * 4;
    float* qb   = (float*)(ws + o); o += (size_t)B_ * L_ * D_ * 4;
    float* phi2 = (float*)(ws + o); o += (size_t)L_ * R_ * 4;
    float* xt   = (float*)(ws + o); o += (size_t)B_ * L_ * R_ * 4;
    float* kb   = (float*)(ws + o); o += (size_t)B_ * L_ * D_ * 4;
    float* vb   = (float*)(ws + o); o += (size_t)B_ * L_ * D_ * 4;
    float* gb   = (float*)(ws + o); o += (size_t)B_ * L_ * D_ * 4;
    float* Zb   = (float*)(ws + o); o += (size_t)B_ * NH_ * NC_ * HD_ * HD_ * 4;

    // weight order in wbf: Mi, wq, wk, wv, wg, wo (Mi..wg contiguous for gemm5)
    unsigned short* wo_t = wbf + 5 * WSZ;

    const dim3 blk(256);
    const dim3 ggrid(D_ / 64, (B_ * L_) / 128);      // (12, 16)
    const dim3 agrid(NC_, NH_, B_);                  // (16, 12, 2)

    k_prep<<<dim3(4704), blk, 0, stream>>>(Mi, wq_w, wk_w, wv_w, wg_w, wo_w, wbf,
                                           x, xbf, stu, Mf, phi2);

    k_gemm5<<<dim3(12, 16, 5), blk, 0, stream>>>(xbf, wbf,
                                                 wq_b, wk_b, wv_b, wg_b,
                                                 ubuf, qb, kb, vb, gb);

    k_conv<<<dim3(L_ / 2 / 8, B_ * 2), dim3(768), 0, stream>>>(ubuf, phi2, xt);

    k_zsum<<<agrid, blk, 0, stream>>>(kb, vb, Zb);
    k_attn2g<<<agrid, blk, 0, stream>>>(qb, kb, vb, Zb, xt, gb, gx);

    k_gemm<<<ggrid, blk, 0, stream>>>(gx, wo_t, wo_b, out, D_, D_);
}

// Round 7
// 124.589 us; speedup vs baseline: 6.3981x; 1.0223x over previous
//
#include <hip/hip_runtime.h>
#include <math.h>

#define B_  2
#define L_  1024
#define D_  768
#define NH_ 12
#define HD_ 64
#define K_  24
#define R_  768
#define NC_ 16   // chunks
#define CS_ 64   // chunk size

typedef __bf16 bf16x8 __attribute__((ext_vector_type(8)));
typedef float f32x4 __attribute__((ext_vector_type(4)));
typedef unsigned short u16x8 __attribute__((ext_vector_type(8)));

__device__ inline unsigned short f2bf(float f) {
    union { float f; unsigned u; } v; v.f = f;
    unsigned r = v.u + 0x7FFFu + ((v.u >> 16) & 1u);
    return (unsigned short)(r >> 16);
}

// async global->LDS, 16 B per lane (literal size per guide)
#define GLD_LDS16(g, l)                                                     \
    __builtin_amdgcn_global_load_lds(                                       \
        (const __attribute__((address_space(1))) void*)(g),                 \
        (__attribute__((address_space(3))) void*)(l), 16, 0, 0)

// ---------------------------------------------------------------------------
// Fused prep: [0,864) weight transposes (6x 768x768 fp32 -> bf16 T),
//             [864,1632) x fp32 -> bf16, [1632,4704) phi2 = 2*stu@Mf (fp32)
// ---------------------------------------------------------------------------
__global__ __launch_bounds__(256) void k_prep(const float* __restrict__ w0,
                                              const float* __restrict__ w1,
                                              const float* __restrict__ w2,
                                              const float* __restrict__ w3,
                                              const float* __restrict__ w4,
                                              const float* __restrict__ w5,
                                              unsigned short* __restrict__ Wt,
                                              const float* __restrict__ x,
                                              unsigned short* __restrict__ xb,
                                              const float* __restrict__ F,
                                              const float* __restrict__ Mf,
                                              float* __restrict__ phi2) {
    const int bid = blockIdx.x;
    const int tid = threadIdx.x;
    if (bid < 864) {
        const int z = bid / 144, rem = bid % 144;
        const float* W;
        switch (z) {
            case 0: W = w0; break;
            case 1: W = w1; break;
            case 2: W = w2; break;
            case 3: W = w3; break;
            case 4: W = w4; break;
            default: W = w5; break;
        }
        unsigned short* o = Wt + (size_t)z * D_ * D_;
        __shared__ float t[64][65];
        const int n0 = (rem % 12) * 64, k0 = (rem / 12) * 64;
        const int c = tid & 63, rq = tid >> 6;
#pragma unroll
        for (int i = 0; i < 16; ++i)
            t[rq + i * 4][c] = W[(size_t)(k0 + rq + i * 4) * D_ + n0 + c];
        __syncthreads();
#pragma unroll
        for (int i = 0; i < 16; ++i)
            o[(size_t)(n0 + rq + i * 4) * D_ + k0 + c] = f2bf(t[c][rq + i * 4]);
    } else if (bid < 1632) {
        const int i8 = ((bid - 864) * 256 + tid) * 8;
        float4 f0 = *reinterpret_cast<const float4*>(x + i8);
        float4 f1 = *reinterpret_cast<const float4*>(x + i8 + 4);
        u16x8 p;
        p[0] = f2bf(f0.x); p[1] = f2bf(f0.y); p[2] = f2bf(f0.z); p[3] = f2bf(f0.w);
        p[4] = f2bf(f1.x); p[5] = f2bf(f1.y); p[6] = f2bf(f1.z); p[7] = f2bf(f1.w);
        *reinterpret_cast<u16x8*>(xb + i8) = p;
    } else {
        const int idx = (bid - 1632) * 256 + tid;
        const int r = idx % R_;
        const int j = idx / R_;
        float acc = 0.f;
#pragma unroll
        for (int kk = 0; kk < K_; ++kk)
            acc += F[j * K_ + kk] * Mf[kk * R_ + r];
        phi2[idx] = 2.f * acc;
    }
}

// ---------------------------------------------------------------------------
// bf16 MFMA GEMM, m97 structure: single-buffer LDS, 2 barriers per K-tile,
// global_load_lds width-16 staging. BM=128, BK=64, BN = 32*NBF.
// 4 waves, each owning 64 x (16*NBF): 4 x NBF fragments of 16x16x32.
// NBF=4 -> MFMA:ds_read = 2:1 (m97 ratio); NBF=2 kept for small-N grids.
// ---------------------------------------------------------------------------
template <int NBF>
__device__ __forceinline__ void gemm_body(const unsigned short* __restrict__ A,
                                          const unsigned short* __restrict__ Bt,
                                          const float* __restrict__ bias,
                                          float* __restrict__ C,
                                          int N, int Kd,
                                          int bm, int bn, int tid) {
    __shared__ unsigned short As[128 * 64];          // 16 KB
    __shared__ unsigned short Bs[NBF * 32 * 64];     // 16 KB (NBF=4) / 8 KB
    const int lane = tid & 63, wave = tid >> 6;
    const int wm = (wave >> 1) * 64, wn = (wave & 1) * (NBF * 16);
    const int l15 = lane & 15, lg = lane >> 4;

    f32x4 acc[4][NBF] = {};

    const int nt = Kd / 64;
    for (int t = 0; t < nt; ++t) {
        const int k0 = t * 64;
        __syncthreads();                             // prev compute done reading
#pragma unroll
        for (int q = 0; q < 4; ++q) {
            const int s = q * 256 + tid;             // 0..1023
            GLD_LDS16(A + (size_t)(bm + (s >> 3)) * Kd + k0 + (s & 7) * 8,
                      &As[s * 8]);
        }
#pragma unroll
        for (int q = 0; q < NBF; ++q) {
            const int s = q * 256 + tid;             // 0..NBF*256-1
            GLD_LDS16(Bt + (size_t)(bn + (s >> 3)) * Kd + k0 + (s & 7) * 8,
                      &Bs[s * 8]);
        }
        __syncthreads();                             // drains vmcnt before barrier
#pragma unroll
        for (int ks = 0; ks < 2; ++ks) {
            const int kb = ks * 32 + lg * 8;
            bf16x8 a[4], b[NBF];
#pragma unroll
            for (int f = 0; f < 4; ++f)
                a[f] = *reinterpret_cast<const bf16x8*>(
                    &As[(wm + f * 16 + l15) * 64 + kb]);
#pragma unroll
            for (int f = 0; f < NBF; ++f)
                b[f] = *reinterpret_cast<const bf16x8*>(
                    &Bs[(wn + f * 16 + l15) * 64 + kb]);
#pragma unroll
            for (int fm = 0; fm < 4; ++fm)
#pragma unroll
                for (int fn = 0; fn < NBF; ++fn)
                    acc[fm][fn] = __builtin_amdgcn_mfma_f32_16x16x32_bf16(
                        a[fm], b[fn], acc[fm][fn], 0, 0, 0);
        }
    }

#pragma unroll
    for (int fm = 0; fm < 4; ++fm)
#pragma unroll
        for (int fn = 0; fn < NBF; ++fn) {
            const int col = bn + wn + fn * 16 + l15;
            const float bv = bias ? bias[col] : 0.f;
#pragma unroll
            for (int j = 0; j < 4; ++j) {
                const int row = bm + wm + fm * 16 + lg * 4 + j;
                C[(size_t)row * N + col] = acc[fm][fn][j] + bv;
            }
        }
}

__global__ __launch_bounds__(256) void k_gemm(const unsigned short* __restrict__ A,
                                              const unsigned short* __restrict__ Bt,
                                              const float* __restrict__ bias,
                                              float* __restrict__ C,
                                              int N, int Kd) {
    gemm_body<2>(A, Bt, bias, C, N, Kd, blockIdx.y * 128, blockIdx.x * 64, threadIdx.x);
}

// all 5 x-projections (u,q,k,v,g) share A=xbf; blockIdx.z selects weight/bias/out
__global__ __launch_bounds__(256) void k_gemm5(const unsigned short* __restrict__ A,
                                               const unsigned short* __restrict__ wt,
                                               const float* __restrict__ bq,
                                               const float* __restrict__ bk,
                                               const float* __restrict__ bv,
                                               const float* __restrict__ bg,
                                               float* __restrict__ cu,
                                               float* __restrict__ cq,
                                               float* __restrict__ ck,
                                               float* __restrict__ cv,
                                               float* __restrict__ cg) {
    const float* bias; float* C;
    switch (blockIdx.z) {
        case 0: bias = nullptr; C = cu; break;
        case 1: bias = bq; C = cq; break;
        case 2: bias = bk; C = ck; break;
        case 3: bias = bv; C = cv; break;
        default: bias = bg; C = cg; break;
    }
    const unsigned short* Bt = wt + (size_t)blockIdx.z * D_ * D_;
    gemm_body<4>(A, Bt, bias, C, D_, D_, blockIdx.y * 128, blockIdx.x * 128, threadIdx.x);
}

// ---------------------------------------------------------------------------
// Parity-split causal conv, register sliding window, 4-way n-split per block.
// ---------------------------------------------------------------------------
__global__ __launch_bounds__(768) void k_conv(const float* __restrict__ u,
                                              const float* __restrict__ phi2,
                                              float* __restrict__ xt) {
    __shared__ f32x4 red[4][8][192];            // 98304 B
    const int tid = threadIdx.x;
    const int g   = tid / 192;
    const int lr  = tid % 192;
    const int r   = lr * 4;
    const int m0  = blockIdx.x * 8;
    const int bp  = blockIdx.y;
    const int b   = bp >> 1, p = bp & 1;

    f32x4 acc[8] = {};
    f32x4 w[8]   = {};

    const int ns = g * 128;
    const int ne = min(ns + 128, m0 + 8);

    if (ns < ne) {
        if (g > 0) {
#pragma unroll
            for (int j = 1; j <= 7; ++j)
                w[(8 - j) & 7] =
                    *reinterpret_cast<const f32x4*>(phi2 + (size_t)(2 * (ns - j)) * R_ + r);
        }
        const float* pp = phi2 + (size_t)(2 * ns) * R_ + r;
        const float* up = u + ((size_t)(b * L_) + (size_t)(2 * (m0 + 7 - ns) + p)) * R_ + r;
        for (int i = ns; i < ne; i += 8) {
#pragma unroll
            for (int k = 0; k < 8; ++k) {
                const f32x4 wn = *reinterpret_cast<const f32x4*>(pp);
                const f32x4 un = *reinterpret_cast<const f32x4*>(up);
                w[k] = wn;
#pragma unroll
                for (int a = 0; a < 8; ++a)
                    acc[a] += w[(k + a + 1) & 7] * un;
                pp += 2 * R_;
                up -= 2 * R_;
            }
        }
    }

#pragma unroll
    for (int a = 0; a < 8; ++a) red[g][a][lr] = acc[a];
    __syncthreads();

#pragma unroll
    for (int q2 = 0; q2 < 2; ++q2) {
        const int sl = q2 * 768 + tid;
        const int a  = sl / 192, l = sl % 192;
        const f32x4 s = red[0][a][l] + red[1][a][l] + red[2][a][l] + red[3][a][l];
        *reinterpret_cast<f32x4*>(
            xt + ((size_t)(b * L_) + (size_t)(2 * (m0 + a) + p)) * R_ + l * 4) = s;
    }
}

// ---------------------------------------------------------------------------
// Z[b,h,c,p,n] = sum_{s in chunk c} v[s][p] * k[s][n]
// ---------------------------------------------------------------------------
__global__ __launch_bounds__(256) void k_zsum(const float* __restrict__ k,
                                              const float* __restrict__ v,
                                              float* __restrict__ Z) {
    const int c = blockIdx.x, h = blockIdx.y, b = blockIdx.z;
    __shared__ float ks[64][65], vs[64][65];
    const int tid = threadIdx.x;
    const int lr = tid >> 6, lc = tid & 63;
    const size_t base = ((size_t)(b * L_ + c * CS_)) * D_ + h * HD_;
#pragma unroll
    for (int i = 0; i < 16; ++i) {
        ks[lr + i * 4][lc] = k[base + (size_t)(lr + i * 4) * D_ + lc];
        vs[lr + i * 4][lc] = v[base + (size_t)(lr + i * 4) * D_ + lc];
    }
    __syncthreads();
    const int tx = tid & 15, ty = tid >> 4;
    float acc[4][4] = {};
#pragma unroll 8
    for (int s = 0; s < 64; ++s) {
        float a[4], bb[4];
#pragma unroll
        for (int i = 0; i < 4; ++i) a[i] = vs[s][ty * 4 + i];
#pragma unroll
        for (int j = 0; j < 4; ++j) bb[j] = ks[s][tx * 4 + j];
#pragma unroll
        for (int i = 0; i < 4; ++i)
#pragma unroll
            for (int j = 0; j < 4; ++j)
                acc[i][j] += a[i] * bb[j];
    }
    float* zp = Z + ((size_t)(b * NH_ + h) * NC_ + c) * (HD_ * HD_);
#pragma unroll
    for (int i = 0; i < 4; ++i)
#pragma unroll
        for (int j = 0; j < 4; ++j)
            zp[(ty * 4 + i) * HD_ + tx * 4 + j] = acc[i][j];
}

// ---------------------------------------------------------------------------
// Per chunk: H_c = sum_{c'<c} Z[c'] (fused prefix), Y = tril(Q Vt) K + Q H_c,
// fused gate, bf16 output: gx <- bf16( xt + (Y - xt) * sigmoid(g) )
// ---------------------------------------------------------------------------
__global__ __launch_bounds__(256) void k_attn2g(const float* __restrict__ q,
                                                const float* __restrict__ k,
                                                const float* __restrict__ v,
                                                const float* __restrict__ Zb,
                                                const float* __restrict__ xt,
                                                const float* __restrict__ g,
                                                unsigned short* __restrict__ gx) {
    const int c = blockIdx.x, h = blockIdx.y, b = blockIdx.z;
    __shared__ float qs[64][65], ks[64][65], vs[64][65];   // vs: V -> S -> H
    const int tid = threadIdx.x;
    const int lr = tid >> 6, lc = tid & 63;
    const size_t base = ((size_t)(b * L_ + c * CS_)) * D_ + h * HD_;
#pragma unroll
    for (int i = 0; i < 16; ++i) {
        qs[lr + i * 4][lc] = q[base + (size_t)(lr + i * 4) * D_ + lc];
        ks[lr + i * 4][lc] = k[base + (size_t)(lr + i * 4) * D_ + lc];
        vs[lr + i * 4][lc] = v[base + (size_t)(lr + i * 4) * D_ + lc];
    }
    __syncthreads();

    const int tx = tid & 15, ty = tid >> 4;

    float sacc[4][4] = {};
#pragma unroll 8
    for (int d = 0; d < 64; ++d) {
        float a[4], bb[4];
#pragma unroll
        for (int i = 0; i < 4; ++i) a[i] = qs[ty * 4 + i][d];
#pragma unroll
        for (int j = 0; j < 4; ++j) bb[j] = vs[tx * 4 + j][d];
#pragma unroll
        for (int i = 0; i < 4; ++i)
#pragma unroll
            for (int j = 0; j < 4; ++j)
                sacc[i][j] += a[i] * bb[j];
    }
#pragma unroll
    for (int i = 0; i < 4; ++i)
#pragma unroll
        for (int j = 0; j < 4; ++j)
            if (tx * 4 + j > ty * 4 + i) sacc[i][j] = 0.f;

    // fused exclusive prefix of Z while S is still in registers
    float hreg[16] = {};
    const float* zb = Zb + (size_t)(b * NH_ + h) * NC_ * 4096;
    for (int c2 = 0; c2 < c; ++c2) {
        const float* zp = zb + (size_t)c2 * 4096;
#pragma unroll
        for (int i = 0; i < 16; ++i)
            hreg[i] += zp[(lr + i * 4) * HD_ + lc];
    }

    __syncthreads();                   // everyone done reading vs (V)
#pragma unroll
    for (int i = 0; i < 4; ++i)
#pragma unroll
        for (int j = 0; j < 4; ++j)
            vs[ty * 4 + i][tx * 4 + j] = sacc[i][j];
    __syncthreads();

    float yacc[4][4] = {};
#pragma unroll 8
    for (int jj = 0; jj < 64; ++jj) {
        float s[4], kk[4];
#pragma unroll
        for (int i = 0; i < 4; ++i) s[i] = vs[ty * 4 + i][jj];
#pragma unroll
        for (int n = 0; n < 4; ++n) kk[n] = ks[jj][tx * 4 + n];
#pragma unroll
        for (int i = 0; i < 4; ++i)
#pragma unroll
            for (int n = 0; n < 4; ++n)
                yacc[i][n] += s[i] * kk[n];
    }
    __syncthreads();                   // everyone done reading vs (S)

#pragma unroll
    for (int i = 0; i < 16; ++i)
        vs[lr + i * 4][lc] = hreg[i];
    __syncthreads();
#pragma unroll 8
    for (int p = 0; p < 64; ++p) {
        float a[4], bb[4];
#pragma unroll
        for (int i = 0; i < 4; ++i) a[i] = qs[ty * 4 + i][p];
#pragma unroll
        for (int n = 0; n < 4; ++n) bb[n] = vs[p][tx * 4 + n];
#pragma unroll
        for (int i = 0; i < 4; ++i)
#pragma unroll
            for (int n = 0; n < 4; ++n)
                yacc[i][n] += a[i] * bb[n];
    }

#pragma unroll
    for (int i = 0; i < 4; ++i)
#pragma unroll
        for (int n = 0; n < 4; ++n) {
            const size_t idx = base + (size_t)(ty * 4 + i) * D_ + tx * 4 + n;
            const float gv = 1.f / (1.f + expf(-g[idx]));
            const float xv = xt[idx];
            gx[idx] = f2bf(xv + (yacc[i][n] - xv) * gv);
        }
}

// ---------------------------------------------------------------------------
extern "C" void kernel_launch(void* const* d_in, const int* in_sizes, int n_in,
                              void* d_out, int out_size, void* d_ws, size_t ws_size,
                              hipStream_t stream) {
    const float* x    = (const float*)d_in[0];
    const float* stu  = (const float*)d_in[1];
    const float* Mi   = (const float*)d_in[2];
    const float* Mf   = (const float*)d_in[3];
    const float* wq_w = (const float*)d_in[4];
    const float* wq_b = (const float*)d_in[5];
    const float* wk_w = (const float*)d_in[6];
    const float* wk_b = (const float*)d_in[7];
    const float* wv_w = (const float*)d_in[8];
    const float* wv_b = (const float*)d_in[9];
    const float* wg_w = (const float*)d_in[10];
    const float* wg_b = (const float*)d_in[11];
    const float* wo_w = (const float*)d_in[12];
    const float* wo_b = (const float*)d_in[13];
    float* out = (float*)d_out;

    char* ws = (char*)d_ws;
    size_t o = 0;
    const size_t WSZ = (size_t)D_ * D_;
    unsigned short* wbf = (unsigned short*)(ws + o); o += 6 * WSZ * 2;
    unsigned short* xbf = (unsigned short*)(ws + o); o += (size_t)B_ * L_ * D_ * 2;
    unsigned short* gx  = (unsigned short*)(ws + o); o += (size_t)B_ * L_ * D_ * 2;
    float* ubuf = (float*)(ws + o); o += (size_t)B_ * L_ * R_ * 4;
    float* qb   = (float*)(ws + o); o += (size_t)B_ * L_ * D_ * 4;
    float* phi2 = (float*)(ws + o); o += (size_t)L_ * R_ * 4;
    float* xt   = (float*)(ws + o); o += (size_t)B_ * L_ * R_ * 4;
    float* kb   = (float*)(ws + o); o += (size_t)B_ * L_ * D_ * 4;
    float* vb   = (float*)(ws + o); o += (size_t)B_ * L_ * D_ * 4;
    float* gb   = (float*)(ws + o); o += (size_t)B_ * L_ * D_ * 4;
    float* Zb   = (float*)(ws + o); o += (size_t)B_ * NH_ * NC_ * HD_ * HD_ * 4;

    // weight order in wbf: Mi, wq, wk, wv, wg, wo (Mi..wg contiguous for gemm5)
    unsigned short* wo_t = wbf + 5 * WSZ;

    const dim3 blk(256);
    const dim3 agrid(NC_, NH_, B_);                  // (16, 12, 2)

    k_prep<<<dim3(4704), blk, 0, stream>>>(Mi, wq_w, wk_w, wv_w, wg_w, wo_w, wbf,
                                           x, xbf, stu, Mf, phi2);

    k_gemm5<<<dim3(D_ / 128, (B_ * L_) / 128, 5), blk, 0, stream>>>(
        xbf, wbf, wq_b, wk_b, wv_b, wg_b, ubuf, qb, kb, vb, gb);

    k_conv<<<dim3(L_ / 2 / 8, B_ * 2), dim3(768), 0, stream>>>(ubuf, phi2, xt);

    k_zsum<<<agrid, blk, 0, stream>>>(kb, vb, Zb);
    k_attn2g<<<agrid, blk, 0, stream>>>(qb, kb, vb, Zb, xt, gb, gx);

    k_gemm<<<dim3(D_ / 64, (B_ * L_) / 128), blk, 0, stream>>>(gx, wo_t, wo_b, out, D_, D_);
}

// Round 8
// 109.172 us; speedup vs baseline: 7.3017x; 1.1412x over previous
//
#include <hip/hip_runtime.h>
#include <math.h>

#define B_  2
#define L_  1024
#define D_  768
#define NH_ 12
#define HD_ 64
#define K_  24
#define R_  768
#define NC_ 16   // chunks
#define CS_ 64   // chunk size

typedef __bf16 bf16x8 __attribute__((ext_vector_type(8)));
typedef float f32x4 __attribute__((ext_vector_type(4)));
typedef unsigned short u16x8 __attribute__((ext_vector_type(8)));

__device__ inline unsigned short f2bf(float f) {
    union { float f; unsigned u; } v; v.f = f;
    unsigned r = v.u + 0x7FFFu + ((v.u >> 16) & 1u);
    return (unsigned short)(r >> 16);
}

__device__ inline ushort4 pack4(const f32x4 v) {
    ushort4 r;
    r.x = f2bf(v[0]); r.y = f2bf(v[1]); r.z = f2bf(v[2]); r.w = f2bf(v[3]);
    return r;
}

// async global->LDS, 16 B per lane (literal size per guide)
#define GLD_LDS16(g, l)                                                     \
    __builtin_amdgcn_global_load_lds(                                       \
        (const __attribute__((address_space(1))) void*)(g),                 \
        (__attribute__((address_space(3))) void*)(l), 16, 0, 0)

// ---------------------------------------------------------------------------
// Fused prep: [0,864) weight transposes (6x 768x768 fp32 -> bf16 T),
//             [864,1632) x fp32 -> bf16, [1632,4704) phi2 = 2*stu@Mf (fp32)
// ---------------------------------------------------------------------------
__global__ __launch_bounds__(256) void k_prep(const float* __restrict__ w0,
                                              const float* __restrict__ w1,
                                              const float* __restrict__ w2,
                                              const float* __restrict__ w3,
                                              const float* __restrict__ w4,
                                              const float* __restrict__ w5,
                                              unsigned short* __restrict__ Wt,
                                              const float* __restrict__ x,
                                              unsigned short* __restrict__ xb,
                                              const float* __restrict__ F,
                                              const float* __restrict__ Mf,
                                              float* __restrict__ phi2) {
    const int bid = blockIdx.x;
    const int tid = threadIdx.x;
    if (bid < 864) {
        const int z = bid / 144, rem = bid % 144;
        const float* W;
        switch (z) {
            case 0: W = w0; break;
            case 1: W = w1; break;
            case 2: W = w2; break;
            case 3: W = w3; break;
            case 4: W = w4; break;
            default: W = w5; break;
        }
        unsigned short* o = Wt + (size_t)z * D_ * D_;
        __shared__ float t[64][65];
        const int n0 = (rem % 12) * 64, k0 = (rem / 12) * 64;
        const int c = tid & 63, rq = tid >> 6;
#pragma unroll
        for (int i = 0; i < 16; ++i)
            t[rq + i * 4][c] = W[(size_t)(k0 + rq + i * 4) * D_ + n0 + c];
        __syncthreads();
#pragma unroll
        for (int i = 0; i < 16; ++i)
            o[(size_t)(n0 + rq + i * 4) * D_ + k0 + c] = f2bf(t[c][rq + i * 4]);
    } else if (bid < 1632) {
        const int i8 = ((bid - 864) * 256 + tid) * 8;
        float4 f0 = *reinterpret_cast<const float4*>(x + i8);
        float4 f1 = *reinterpret_cast<const float4*>(x + i8 + 4);
        u16x8 p;
        p[0] = f2bf(f0.x); p[1] = f2bf(f0.y); p[2] = f2bf(f0.z); p[3] = f2bf(f0.w);
        p[4] = f2bf(f1.x); p[5] = f2bf(f1.y); p[6] = f2bf(f1.z); p[7] = f2bf(f1.w);
        *reinterpret_cast<u16x8*>(xb + i8) = p;
    } else {
        const int idx = (bid - 1632) * 256 + tid;
        const int r = idx % R_;
        const int j = idx / R_;
        float acc = 0.f;
#pragma unroll
        for (int kk = 0; kk < K_; ++kk)
            acc += F[j * K_ + kk] * Mf[kk * R_ + r];
        phi2[idx] = 2.f * acc;
    }
}

// ---------------------------------------------------------------------------
// bf16 MFMA GEMM core. BM=128, BK=64, BN=32*NBF; 4 waves x (64 x 16*NBF).
// mode 0: fp32 C[row*N+col] (+bias)
// mode 1: bf16 row-major cbf[row*768+col] (+bias)
// mode 2: bf16 transposed ct[((b*12+h)*64+n)*1024 + l] (+bias), packed ushort4
// mode 3: mode1 + mode2
// ---------------------------------------------------------------------------
template <int NBF>
__device__ __forceinline__ void gemm_core(const unsigned short* __restrict__ A,
                                          const unsigned short* __restrict__ Bt,
                                          const float* __restrict__ bias,
                                          int mode,
                                          float* __restrict__ cf,
                                          unsigned short* __restrict__ cbf,
                                          unsigned short* __restrict__ ct,
                                          int N, int Kd,
                                          int bm, int bn, int tid) {
    __shared__ unsigned short As[128 * 64];
    __shared__ unsigned short Bs[NBF * 32 * 64];
    const int lane = tid & 63, wave = tid >> 6;
    const int wm = (wave >> 1) * 64, wn = (wave & 1) * (NBF * 16);
    const int l15 = lane & 15, lg = lane >> 4;

    f32x4 acc[4][NBF] = {};

    const int nt = Kd / 64;
    for (int t = 0; t < nt; ++t) {
        const int k0 = t * 64;
        __syncthreads();
#pragma unroll
        for (int q = 0; q < 4; ++q) {
            const int s = q * 256 + tid;
            GLD_LDS16(A + (size_t)(bm + (s >> 3)) * Kd + k0 + (s & 7) * 8,
                      &As[s * 8]);
        }
#pragma unroll
        for (int q = 0; q < NBF; ++q) {
            const int s = q * 256 + tid;
            GLD_LDS16(Bt + (size_t)(bn + (s >> 3)) * Kd + k0 + (s & 7) * 8,
                      &Bs[s * 8]);
        }
        __syncthreads();
#pragma unroll
        for (int ks = 0; ks < 2; ++ks) {
            const int kb = ks * 32 + lg * 8;
            bf16x8 a[4], b[NBF];
#pragma unroll
            for (int f = 0; f < 4; ++f)
                a[f] = *reinterpret_cast<const bf16x8*>(
                    &As[(wm + f * 16 + l15) * 64 + kb]);
#pragma unroll
            for (int f = 0; f < NBF; ++f)
                b[f] = *reinterpret_cast<const bf16x8*>(
                    &Bs[(wn + f * 16 + l15) * 64 + kb]);
#pragma unroll
            for (int fm = 0; fm < 4; ++fm)
#pragma unroll
                for (int fn = 0; fn < NBF; ++fn)
                    acc[fm][fn] = __builtin_amdgcn_mfma_f32_16x16x32_bf16(
                        a[fm], b[fn], acc[fm][fn], 0, 0, 0);
        }
    }

#pragma unroll
    for (int fm = 0; fm < 4; ++fm)
#pragma unroll
        for (int fn = 0; fn < NBF; ++fn) {
            const int col = bn + wn + fn * 16 + l15;
            const float bv = bias ? bias[col] : 0.f;
            const int r0 = bm + wm + fm * 16 + lg * 4;
            f32x4 v = acc[fm][fn];
            v[0] += bv; v[1] += bv; v[2] += bv; v[3] += bv;
            if (mode == 0) {
#pragma unroll
                for (int j = 0; j < 4; ++j)
                    cf[(size_t)(r0 + j) * N + col] = v[j];
            }
            if (mode & 1) {
#pragma unroll
                for (int j = 0; j < 4; ++j)
                    cbf[(size_t)(r0 + j) * D_ + col] = f2bf(v[j]);
            }
            if (mode & 2) {
                const int h = col >> 6, n = col & 63;
                const int bI = r0 >> 10, l0 = r0 & 1023;
                *reinterpret_cast<ushort4*>(
                    ct + (((size_t)bI * NH_ + h) * 64 + n) * (size_t)L_ + l0) =
                    pack4(v);
            }
        }
}

// output projection: fp32 out
__global__ __launch_bounds__(256) void k_gemm(const unsigned short* __restrict__ A,
                                              const unsigned short* __restrict__ Bt,
                                              const float* __restrict__ bias,
                                              float* __restrict__ C,
                                              int N, int Kd) {
    gemm_core<2>(A, Bt, bias, 0, C, nullptr, nullptr, N, Kd,
                 blockIdx.y * 128, blockIdx.x * 64, threadIdx.x);
}

// 5 x-projections; z selects output format:
// z=0: u fp32; z=1: q bf16 row; z=2: kt transposed; z=3: v bf16 row + vt; z=4: g fp32
__global__ __launch_bounds__(256) void k_gemm5(const unsigned short* __restrict__ A,
                                               const unsigned short* __restrict__ wt,
                                               const float* __restrict__ bq,
                                               const float* __restrict__ bk,
                                               const float* __restrict__ bv,
                                               const float* __restrict__ bg,
                                               float* __restrict__ ubuf,
                                               unsigned short* __restrict__ qbf,
                                               unsigned short* __restrict__ ktb,
                                               unsigned short* __restrict__ vbf,
                                               unsigned short* __restrict__ vtb,
                                               float* __restrict__ gb) {
    const int z = blockIdx.z;
    const float* bias = nullptr;
    int mode = 0;
    float* cf = nullptr; unsigned short* cbf = nullptr; unsigned short* ct = nullptr;
    switch (z) {
        case 0: mode = 0; cf = ubuf; bias = nullptr; break;
        case 1: mode = 1; cbf = qbf; bias = bq; break;
        case 2: mode = 2; ct = ktb; bias = bk; break;
        case 3: mode = 3; cbf = vbf; ct = vtb; bias = bv; break;
        default: mode = 0; cf = gb; bias = bg; break;
    }
    const unsigned short* Bt = wt + (size_t)z * D_ * D_;
    gemm_core<4>(A, Bt, bias, mode, cf, cbf, ct, D_, D_,
                 blockIdx.y * 128, blockIdx.x * 128, threadIdx.x);
}

// ---------------------------------------------------------------------------
// Parity-split causal conv, register sliding window, 4-way n-split per block.
// ---------------------------------------------------------------------------
__global__ __launch_bounds__(768) void k_conv(const float* __restrict__ u,
                                              const float* __restrict__ phi2,
                                              float* __restrict__ xt) {
    __shared__ f32x4 red[4][8][192];            // 98304 B
    const int tid = threadIdx.x;
    const int g   = tid / 192;
    const int lr  = tid % 192;
    const int r   = lr * 4;
    const int m0  = blockIdx.x * 8;
    const int bp  = blockIdx.y;
    const int b   = bp >> 1, p = bp & 1;

    f32x4 acc[8] = {};
    f32x4 w[8]   = {};

    const int ns = g * 128;
    const int ne = min(ns + 128, m0 + 8);

    if (ns < ne) {
        if (g > 0) {
#pragma unroll
            for (int j = 1; j <= 7; ++j)
                w[(8 - j) & 7] =
                    *reinterpret_cast<const f32x4*>(phi2 + (size_t)(2 * (ns - j)) * R_ + r);
        }
        const float* pp = phi2 + (size_t)(2 * ns) * R_ + r;
        const float* up = u + ((size_t)(b * L_) + (size_t)(2 * (m0 + 7 - ns) + p)) * R_ + r;
        for (int i = ns; i < ne; i += 8) {
#pragma unroll
            for (int k = 0; k < 8; ++k) {
                const f32x4 wn = *reinterpret_cast<const f32x4*>(pp);
                const f32x4 un = *reinterpret_cast<const f32x4*>(up);
                w[k] = wn;
#pragma unroll
                for (int a = 0; a < 8; ++a)
                    acc[a] += w[(k + a + 1) & 7] * un;
                pp += 2 * R_;
                up -= 2 * R_;
            }
        }
    }

#pragma unroll
    for (int a = 0; a < 8; ++a) red[g][a][lr] = acc[a];
    __syncthreads();

#pragma unroll
    for (int q2 = 0; q2 < 2; ++q2) {
        const int sl = q2 * 768 + tid;
        const int a  = sl / 192, l = sl % 192;
        const f32x4 s = red[0][a][l] + red[1][a][l] + red[2][a][l] + red[3][a][l];
        *reinterpret_cast<f32x4*>(
            xt + ((size_t)(b * L_) + (size_t)(2 * (m0 + a) + p)) * R_ + l * 4) = s;
    }
}

// ---------------------------------------------------------------------------
// MFMA chunked linear attention, self-contained per block (c,h,b):
//   H = sum_{c'<c} V_c'^T K_c'        (bf16 MFMA from kt/vt, fp32 acc)
//   St[s][t] = mfma(V, Q), masked s<=t; packed -> Sl[t][s]
//   Yt[n][t] = mfma(Kc, Sl-rows-t) + mfma(Hl-rows-n, Q)
//   gate fused: gx = bf16( xt + (Y - xt) * sigmoid(g) )
// mfma(A,B) computes D[rowA][rowB] = sum_k A[rowA][k]*B[rowB][k].
// ---------------------------------------------------------------------------
__global__ __launch_bounds__(256) void k_attn(const unsigned short* __restrict__ qbf,
                                              const unsigned short* __restrict__ vbf,
                                              const unsigned short* __restrict__ ktb,
                                              const unsigned short* __restrict__ vtb,
                                              const float* __restrict__ xt,
                                              const float* __restrict__ g,
                                              unsigned short* __restrict__ gx) {
    const int c = blockIdx.x, h = blockIdx.y, b = blockIdx.z;
    __shared__ unsigned short Qs[64 * 64];   // Q rows t, k=d
    __shared__ unsigned short Vs[64 * 64];   // V rows s, k=d
    __shared__ unsigned short Kc[64 * 64];   // Kt own chunk: rows n, k=s
    __shared__ unsigned short Tk[64 * 64];   // prefix Kt tile
    __shared__ unsigned short Tv[64 * 64];   // prefix Vt tile
    __shared__ unsigned short Sl[64 * 72];   // S[t][s] padded
    __shared__ unsigned short Hl[64 * 72];   // Ht[n][p] padded

    const int tid = threadIdx.x;
    const int lane = tid & 63, wave = tid >> 6;
    const int wr = (wave >> 1) * 32, wc = (wave & 1) * 32;
    const int l15 = lane & 15, lg = lane >> 4;

    // stage Q, V (row-major) and own-chunk Kt
    {
        const size_t rowbase = ((size_t)(b * L_ + c * CS_)) * D_ + h * HD_;
        const size_t tbase = ((size_t)(b * NH_ + h)) * 64 * (size_t)L_ + c * 64;
#pragma unroll
        for (int q2 = 0; q2 < 2; ++q2) {
            const int s = q2 * 256 + tid;
            const int row = s >> 3, c8 = s & 7;
            GLD_LDS16(qbf + rowbase + (size_t)row * D_ + c8 * 8, &Qs[s * 8]);
            GLD_LDS16(vbf + rowbase + (size_t)row * D_ + c8 * 8, &Vs[s * 8]);
            GLD_LDS16(ktb + tbase + (size_t)row * L_ + c8 * 8, &Kc[s * 8]);
        }
    }

    // prefix H = sum_{cc<c} V^T K  via kt/vt tiles
    f32x4 hacc[2][2] = {};
    for (int cc = 0; cc < c; ++cc) {
        __syncthreads();                       // Tk/Tv free
        const size_t tb2 = ((size_t)(b * NH_ + h)) * 64 * (size_t)L_ + cc * 64;
#pragma unroll
        for (int q2 = 0; q2 < 2; ++q2) {
            const int s = q2 * 256 + tid;
            const int row = s >> 3, c8 = s & 7;
            GLD_LDS16(ktb + tb2 + (size_t)row * L_ + c8 * 8, &Tk[s * 8]);
            GLD_LDS16(vtb + tb2 + (size_t)row * L_ + c8 * 8, &Tv[s * 8]);
        }
        __syncthreads();                       // drain (covers Q/V/Kc on iter 0)
#pragma unroll
        for (int ks = 0; ks < 2; ++ks) {
            const int kb = ks * 32 + lg * 8;
            bf16x8 av[2], bk[2];
#pragma unroll
            for (int f = 0; f < 2; ++f) {
                av[f] = *reinterpret_cast<const bf16x8*>(&Tv[(wr + f * 16 + l15) * 64 + kb]);
                bk[f] = *reinterpret_cast<const bf16x8*>(&Tk[(wc + f * 16 + l15) * 64 + kb]);
            }
#pragma unroll
            for (int fm = 0; fm < 2; ++fm)
#pragma unroll
                for (int fn = 0; fn < 2; ++fn)
                    hacc[fm][fn] = __builtin_amdgcn_mfma_f32_16x16x32_bf16(
                        av[fm], bk[fn], hacc[fm][fn], 0, 0, 0);
        }
    }
    __syncthreads();                           // c==0: drains staging; else harmless

    // write Ht[n][p] (packed: lane holds 4 consecutive p at fixed n)
    if (c > 0) {
#pragma unroll
        for (int fm = 0; fm < 2; ++fm)
#pragma unroll
            for (int fn = 0; fn < 2; ++fn) {
                const int n = wc + fn * 16 + l15;
                const int p0 = wr + fm * 16 + lg * 4;
                *reinterpret_cast<ushort4*>(&Hl[n * 72 + p0]) = pack4(hacc[fm][fn]);
            }
    }

    // St[s][t] = mfma(V rows s, Q rows t); mask s>t; pack to Sl[t][s]
    {
        f32x4 sacc[2][2] = {};
#pragma unroll
        for (int ks = 0; ks < 2; ++ks) {
            const int kb = ks * 32 + lg * 8;
            bf16x8 av[2], bq[2];
#pragma unroll
            for (int f = 0; f < 2; ++f) {
                av[f] = *reinterpret_cast<const bf16x8*>(&Vs[(wr + f * 16 + l15) * 64 + kb]);
                bq[f] = *reinterpret_cast<const bf16x8*>(&Qs[(wc + f * 16 + l15) * 64 + kb]);
            }
#pragma unroll
            for (int fm = 0; fm < 2; ++fm)
#pragma unroll
                for (int fn = 0; fn < 2; ++fn)
                    sacc[fm][fn] = __builtin_amdgcn_mfma_f32_16x16x32_bf16(
                        av[fm], bq[fn], sacc[fm][fn], 0, 0, 0);
        }
#pragma unroll
        for (int fm = 0; fm < 2; ++fm)
#pragma unroll
            for (int fn = 0; fn < 2; ++fn) {
                const int t = wc + fn * 16 + l15;
                const int s0 = wr + fm * 16 + lg * 4;
#pragma unroll
                for (int j = 0; j < 4; ++j)
                    if (s0 + j > t) sacc[fm][fn][j] = 0.f;
                *reinterpret_cast<ushort4*>(&Sl[t * 72 + s0]) = pack4(sacc[fm][fn]);
            }
    }
    __syncthreads();                           // Sl, Hl visible

    // Yt[n][t] = mfma(Kc rows n, Sl rows t) (+ mfma(Hl rows n, Qs rows t))
    f32x4 yacc[2][2] = {};
#pragma unroll
    for (int ks = 0; ks < 2; ++ks) {
        const int kb = ks * 32 + lg * 8;
        bf16x8 ak[2], bs[2];
#pragma unroll
        for (int f = 0; f < 2; ++f) {
            ak[f] = *reinterpret_cast<const bf16x8*>(&Kc[(wr + f * 16 + l15) * 64 + kb]);
            bs[f] = *reinterpret_cast<const bf16x8*>(&Sl[(wc + f * 16 + l15) * 72 + kb]);
        }
#pragma unroll
        for (int fm = 0; fm < 2; ++fm)
#pragma unroll
            for (int fn = 0; fn < 2; ++fn)
                yacc[fm][fn] = __builtin_amdgcn_mfma_f32_16x16x32_bf16(
                    ak[fm], bs[fn], yacc[fm][fn], 0, 0, 0);
    }
    if (c > 0) {
#pragma unroll
        for (int ks = 0; ks < 2; ++ks) {
            const int kb = ks * 32 + lg * 8;
            bf16x8 ah[2], bq[2];
#pragma unroll
            for (int f = 0; f < 2; ++f) {
                ah[f] = *reinterpret_cast<const bf16x8*>(&Hl[(wr + f * 16 + l15) * 72 + kb]);
                bq[f] = *reinterpret_cast<const bf16x8*>(&Qs[(wc + f * 16 + l15) * 64 + kb]);
            }
#pragma unroll
            for (int fm = 0; fm < 2; ++fm)
#pragma unroll
                for (int fn = 0; fn < 2; ++fn)
                    yacc[fm][fn] = __builtin_amdgcn_mfma_f32_16x16x32_bf16(
                        ah[fm], bq[fn], yacc[fm][fn], 0, 0, 0);
        }
    }

    // gate + bf16 out: lane holds 4 consecutive n at fixed t
#pragma unroll
    for (int fm = 0; fm < 2; ++fm)
#pragma unroll
        for (int fn = 0; fn < 2; ++fn) {
            const int n0 = wr + fm * 16 + lg * 4;
            const int t = wc + fn * 16 + l15;
            const size_t idx = ((size_t)(b * L_ + c * CS_ + t)) * D_ + h * HD_ + n0;
            const float4 gv = *reinterpret_cast<const float4*>(g + idx);
            const float4 xv = *reinterpret_cast<const float4*>(xt + idx);
            f32x4 y = yacc[fm][fn];
            ushort4 o;
            {
                const float s0 = 1.f / (1.f + expf(-gv.x));
                o.x = f2bf(xv.x + (y[0] - xv.x) * s0);
                const float s1 = 1.f / (1.f + expf(-gv.y));
                o.y = f2bf(xv.y + (y[1] - xv.y) * s1);
                const float s2 = 1.f / (1.f + expf(-gv.z));
                o.z = f2bf(xv.z + (y[2] - xv.z) * s2);
                const float s3 = 1.f / (1.f + expf(-gv.w));
                o.w = f2bf(xv.w + (y[3] - xv.w) * s3);
            }
            *reinterpret_cast<ushort4*>(gx + idx) = o;
        }
}

// ---------------------------------------------------------------------------
extern "C" void kernel_launch(void* const* d_in, const int* in_sizes, int n_in,
                              void* d_out, int out_size, void* d_ws, size_t ws_size,
                              hipStream_t stream) {
    const float* x    = (const float*)d_in[0];
    const float* stu  = (const float*)d_in[1];
    const float* Mi   = (const float*)d_in[2];
    const float* Mf   = (const float*)d_in[3];
    const float* wq_w = (const float*)d_in[4];
    const float* wq_b = (const float*)d_in[5];
    const float* wk_w = (const float*)d_in[6];
    const float* wk_b = (const float*)d_in[7];
    const float* wv_w = (const float*)d_in[8];
    const float* wv_b = (const float*)d_in[9];
    const float* wg_w = (const float*)d_in[10];
    const float* wg_b = (const float*)d_in[11];
    const float* wo_w = (const float*)d_in[12];
    const float* wo_b = (const float*)d_in[13];
    float* out = (float*)d_out;

    char* ws = (char*)d_ws;
    size_t o = 0;
    const size_t WSZ = (size_t)D_ * D_;
    unsigned short* wbf = (unsigned short*)(ws + o); o += 6 * WSZ * 2;
    unsigned short* xbf = (unsigned short*)(ws + o); o += (size_t)B_ * L_ * D_ * 2;
    unsigned short* gx  = (unsigned short*)(ws + o); o += (size_t)B_ * L_ * D_ * 2;
    unsigned short* qbf = (unsigned short*)(ws + o); o += (size_t)B_ * L_ * D_ * 2;
    unsigned short* vbf = (unsigned short*)(ws + o); o += (size_t)B_ * L_ * D_ * 2;
    unsigned short* ktb = (unsigned short*)(ws + o); o += (size_t)B_ * NH_ * 64 * L_ * 2;
    unsigned short* vtb = (unsigned short*)(ws + o); o += (size_t)B_ * NH_ * 64 * L_ * 2;
    float* ubuf = (float*)(ws + o); o += (size_t)B_ * L_ * R_ * 4;
    float* phi2 = (float*)(ws + o); o += (size_t)L_ * R_ * 4;
    float* xt   = (float*)(ws + o); o += (size_t)B_ * L_ * R_ * 4;
    float* gb   = (float*)(ws + o); o += (size_t)B_ * L_ * D_ * 4;

    unsigned short* wo_t = wbf + 5 * WSZ;

    const dim3 blk(256);

    k_prep<<<dim3(4704), blk, 0, stream>>>(Mi, wq_w, wk_w, wv_w, wg_w, wo_w, wbf,
                                           x, xbf, stu, Mf, phi2);

    k_gemm5<<<dim3(D_ / 128, (B_ * L_) / 128, 5), blk, 0, stream>>>(
        xbf, wbf, wq_b, wk_b, wv_b, wg_b, ubuf, qbf, ktb, vbf, vtb, gb);

    k_conv<<<dim3(L_ / 2 / 8, B_ * 2), dim3(768), 0, stream>>>(ubuf, phi2, xt);

    k_attn<<<dim3(NC_, NH_, B_), blk, 0, stream>>>(qbf, vbf, ktb, vtb, xt, gb, gx);

    k_gemm<<<dim3(D_ / 64, (B_ * L_) / 128), blk, 0, stream>>>(gx, wo_t, wo_b, out, D_, D_);
}

// Round 9
// 100.050 us; speedup vs baseline: 7.9674x; 1.0912x over previous
//
#include <hip/hip_runtime.h>
#include <math.h>

#define B_  2
#define L_  1024
#define D_  768
#define NH_ 12
#define HD_ 64
#define K_  24
#define R_  768
#define NC_ 16   // chunks
#define CS_ 64   // chunk size

typedef __bf16 bf16x8 __attribute__((ext_vector_type(8)));
typedef float f32x4 __attribute__((ext_vector_type(4)));
typedef unsigned short u16x8 __attribute__((ext_vector_type(8)));

__device__ inline unsigned short f2bf(float f) {
    union { float f; unsigned u; } v; v.f = f;
    unsigned r = v.u + 0x7FFFu + ((v.u >> 16) & 1u);
    return (unsigned short)(r >> 16);
}

__device__ inline ushort4 pack4(const f32x4 v) {
    ushort4 r;
    r.x = f2bf(v[0]); r.y = f2bf(v[1]); r.z = f2bf(v[2]); r.w = f2bf(v[3]);
    return r;
}

// async global->LDS, 16 B per lane (literal size per guide)
#define GLD_LDS16(g, l)                                                     \
    __builtin_amdgcn_global_load_lds(                                       \
        (const __attribute__((address_space(1))) void*)(g),                 \
        (__attribute__((address_space(3))) void*)(l), 16, 0, 0)

// ---------------------------------------------------------------------------
// Fused prep: [0,864) weight transposes (6x 768x768 fp32 -> bf16 T),
//             [864,1632) x fp32 -> bf16, [1632,4704) phi2 = 2*stu@Mf (fp32)
// ---------------------------------------------------------------------------
__global__ __launch_bounds__(256) void k_prep(const float* __restrict__ w0,
                                              const float* __restrict__ w1,
                                              const float* __restrict__ w2,
                                              const float* __restrict__ w3,
                                              const float* __restrict__ w4,
                                              const float* __restrict__ w5,
                                              unsigned short* __restrict__ Wt,
                                              const float* __restrict__ x,
                                              unsigned short* __restrict__ xb,
                                              const float* __restrict__ F,
                                              const float* __restrict__ Mf,
                                              float* __restrict__ phi2) {
    const int bid = blockIdx.x;
    const int tid = threadIdx.x;
    if (bid < 864) {
        const int z = bid / 144, rem = bid % 144;
        const float* W;
        switch (z) {
            case 0: W = w0; break;
            case 1: W = w1; break;
            case 2: W = w2; break;
            case 3: W = w3; break;
            case 4: W = w4; break;
            default: W = w5; break;
        }
        unsigned short* o = Wt + (size_t)z * D_ * D_;
        __shared__ float t[64][65];
        const int n0 = (rem % 12) * 64, k0 = (rem / 12) * 64;
        const int c = tid & 63, rq = tid >> 6;
#pragma unroll
        for (int i = 0; i < 16; ++i)
            t[rq + i * 4][c] = W[(size_t)(k0 + rq + i * 4) * D_ + n0 + c];
        __syncthreads();
#pragma unroll
        for (int i = 0; i < 16; ++i)
            o[(size_t)(n0 + rq + i * 4) * D_ + k0 + c] = f2bf(t[c][rq + i * 4]);
    } else if (bid < 1632) {
        const int i8 = ((bid - 864) * 256 + tid) * 8;
        float4 f0 = *reinterpret_cast<const float4*>(x + i8);
        float4 f1 = *reinterpret_cast<const float4*>(x + i8 + 4);
        u16x8 p;
        p[0] = f2bf(f0.x); p[1] = f2bf(f0.y); p[2] = f2bf(f0.z); p[3] = f2bf(f0.w);
        p[4] = f2bf(f1.x); p[5] = f2bf(f1.y); p[6] = f2bf(f1.z); p[7] = f2bf(f1.w);
        *reinterpret_cast<u16x8*>(xb + i8) = p;
    } else {
        const int idx = (bid - 1632) * 256 + tid;
        const int r = idx % R_;
        const int j = idx / R_;
        float acc = 0.f;
#pragma unroll
        for (int kk = 0; kk < K_; ++kk)
            acc += F[j * K_ + kk] * Mf[kk * R_ + r];
        phi2[idx] = 2.f * acc;
    }
}

// ---------------------------------------------------------------------------
// bf16 MFMA GEMM core, 2-phase double-buffered (stage t+1 before compute t,
// one barrier per K-tile). BM = 2*FM*16, BN = 2*FN*16, BK = 64.
// 4 waves in 2x2, wave owns (FM*16) x (FN*16), FMxFN frags of 16x16x32.
// mode 0: fp32 C[row*N+col] (+bias)
// mode 1: bf16 row-major cbf[row*768+col] (+bias)
// mode 2: bf16 transposed ct[((b*12+h)*64+n)*1024 + l] (+bias), packed ushort4
// mode 3: mode1 + mode2
// ---------------------------------------------------------------------------
template <int FM, int FN>
__device__ __forceinline__ void gemm_core(const unsigned short* __restrict__ A,
                                          const unsigned short* __restrict__ Bt,
                                          const float* __restrict__ bias,
                                          int mode,
                                          float* __restrict__ cf,
                                          unsigned short* __restrict__ cbf,
                                          unsigned short* __restrict__ ct,
                                          int N, int Kd,
                                          int bm, int bn, int tid) {
    constexpr int BM = 2 * FM * 16;
    constexpr int BN = 2 * FN * 16;
    __shared__ unsigned short As[2][BM * 64];
    __shared__ unsigned short Bs[2][BN * 64];
    const int lane = tid & 63, wave = tid >> 6;
    const int wm = (wave >> 1) * (FM * 16), wn = (wave & 1) * (FN * 16);
    const int l15 = lane & 15, lg = lane >> 4;

    f32x4 acc[FM][FN] = {};

    auto stage = [&](int buf, int k0) {
#pragma unroll
        for (int q = 0; q < FM; ++q) {
            const int s = q * 256 + tid;           // 0..BM*8-1
            GLD_LDS16(A + (size_t)(bm + (s >> 3)) * Kd + k0 + (s & 7) * 8,
                      &As[buf][s * 8]);
        }
#pragma unroll
        for (int q = 0; q < FN; ++q) {
            const int s = q * 256 + tid;           // 0..BN*8-1
            GLD_LDS16(Bt + (size_t)(bn + (s >> 3)) * Kd + k0 + (s & 7) * 8,
                      &Bs[buf][s * 8]);
        }
    };

    stage(0, 0);
    __syncthreads();                               // drain prologue
    int cur = 0;
    const int nt = Kd / 64;
    for (int t = 0; t < nt; ++t) {
        if (t + 1 < nt) stage(cur ^ 1, (t + 1) * 64);   // prefetch in flight
#pragma unroll
        for (int ks = 0; ks < 2; ++ks) {
            const int kb = ks * 32 + lg * 8;
            bf16x8 a[FM], b[FN];
#pragma unroll
            for (int f = 0; f < FM; ++f)
                a[f] = *reinterpret_cast<const bf16x8*>(
                    &As[cur][(wm + f * 16 + l15) * 64 + kb]);
#pragma unroll
            for (int f = 0; f < FN; ++f)
                b[f] = *reinterpret_cast<const bf16x8*>(
                    &Bs[cur][(wn + f * 16 + l15) * 64 + kb]);
#pragma unroll
            for (int fm = 0; fm < FM; ++fm)
#pragma unroll
                for (int fn = 0; fn < FN; ++fn)
                    acc[fm][fn] = __builtin_amdgcn_mfma_f32_16x16x32_bf16(
                        a[fm], b[fn], acc[fm][fn], 0, 0, 0);
        }
        __syncthreads();                           // prefetch landed + read fence
        cur ^= 1;
    }

#pragma unroll
    for (int fm = 0; fm < FM; ++fm)
#pragma unroll
        for (int fn = 0; fn < FN; ++fn) {
            const int col = bn + wn + fn * 16 + l15;
            const float bv = bias ? bias[col] : 0.f;
            const int r0 = bm + wm + fm * 16 + lg * 4;
            f32x4 v = acc[fm][fn];
            v[0] += bv; v[1] += bv; v[2] += bv; v[3] += bv;
            if (mode == 0) {
#pragma unroll
                for (int j = 0; j < 4; ++j)
                    cf[(size_t)(r0 + j) * N + col] = v[j];
            }
            if (mode & 1) {
#pragma unroll
                for (int j = 0; j < 4; ++j)
                    cbf[(size_t)(r0 + j) * D_ + col] = f2bf(v[j]);
            }
            if (mode & 2) {
                const int h = col >> 6, n = col & 63;
                const int bI = r0 >> 10, l0 = r0 & 1023;
                *reinterpret_cast<ushort4*>(
                    ct + (((size_t)bI * NH_ + h) * 64 + n) * (size_t)L_ + l0) =
                    pack4(v);
            }
        }
}

// output projection: fp32 out, 64x64 tile (384 blocks -> 1.5/CU)
__global__ __launch_bounds__(256) void k_gemm(const unsigned short* __restrict__ A,
                                              const unsigned short* __restrict__ Bt,
                                              const float* __restrict__ bias,
                                              float* __restrict__ C,
                                              int N, int Kd) {
    gemm_core<2, 2>(A, Bt, bias, 0, C, nullptr, nullptr, N, Kd,
                    blockIdx.y * 64, blockIdx.x * 64, threadIdx.x);
}

// 5 x-projections; z selects output format:
// z=0: u fp32; z=1: q bf16 row; z=2: kt transposed; z=3: v bf16 row + vt; z=4: g fp32
__global__ __launch_bounds__(256) void k_gemm5(const unsigned short* __restrict__ A,
                                               const unsigned short* __restrict__ wt,
                                               const float* __restrict__ bq,
                                               const float* __restrict__ bk,
                                               const float* __restrict__ bv,
                                               const float* __restrict__ bg,
                                               float* __restrict__ ubuf,
                                               unsigned short* __restrict__ qbf,
                                               unsigned short* __restrict__ ktb,
                                               unsigned short* __restrict__ vbf,
                                               unsigned short* __restrict__ vtb,
                                               float* __restrict__ gb) {
    const int z = blockIdx.z;
    const float* bias = nullptr;
    int mode = 0;
    float* cf = nullptr; unsigned short* cbf = nullptr; unsigned short* ct = nullptr;
    switch (z) {
        case 0: mode = 0; cf = ubuf; bias = nullptr; break;
        case 1: mode = 1; cbf = qbf; bias = bq; break;
        case 2: mode = 2; ct = ktb; bias = bk; break;
        case 3: mode = 3; cbf = vbf; ct = vtb; bias = bv; break;
        default: mode = 0; cf = gb; bias = bg; break;
    }
    const unsigned short* Bt = wt + (size_t)z * D_ * D_;
    gemm_core<4, 4>(A, Bt, bias, mode, cf, cbf, ct, D_, D_,
                    blockIdx.y * 128, blockIdx.x * 128, threadIdx.x);
}

// ---------------------------------------------------------------------------
// Parity-split causal conv, register sliding window, 4-way n-split per block.
// ---------------------------------------------------------------------------
__global__ __launch_bounds__(768) void k_conv(const float* __restrict__ u,
                                              const float* __restrict__ phi2,
                                              float* __restrict__ xt) {
    __shared__ f32x4 red[4][8][192];            // 98304 B
    const int tid = threadIdx.x;
    const int g   = tid / 192;
    const int lr  = tid % 192;
    const int r   = lr * 4;
    const int m0  = blockIdx.x * 8;
    const int bp  = blockIdx.y;
    const int b   = bp >> 1, p = bp & 1;

    f32x4 acc[8] = {};
    f32x4 w[8]   = {};

    const int ns = g * 128;
    const int ne = min(ns + 128, m0 + 8);

    if (ns < ne) {
        if (g > 0) {
#pragma unroll
            for (int j = 1; j <= 7; ++j)
                w[(8 - j) & 7] =
                    *reinterpret_cast<const f32x4*>(phi2 + (size_t)(2 * (ns - j)) * R_ + r);
        }
        const float* pp = phi2 + (size_t)(2 * ns) * R_ + r;
        const float* up = u + ((size_t)(b * L_) + (size_t)(2 * (m0 + 7 - ns) + p)) * R_ + r;
        for (int i = ns; i < ne; i += 8) {
#pragma unroll
            for (int k = 0; k < 8; ++k) {
                const f32x4 wn = *reinterpret_cast<const f32x4*>(pp);
                const f32x4 un = *reinterpret_cast<const f32x4*>(up);
                w[k] = wn;
#pragma unroll
                for (int a = 0; a < 8; ++a)
                    acc[a] += w[(k + a + 1) & 7] * un;
                pp += 2 * R_;
                up -= 2 * R_;
            }
        }
    }

#pragma unroll
    for (int a = 0; a < 8; ++a) red[g][a][lr] = acc[a];
    __syncthreads();

#pragma unroll
    for (int q2 = 0; q2 < 2; ++q2) {
        const int sl = q2 * 768 + tid;
        const int a  = sl / 192, l = sl % 192;
        const f32x4 s = red[0][a][l] + red[1][a][l] + red[2][a][l] + red[3][a][l];
        *reinterpret_cast<f32x4*>(
            xt + ((size_t)(b * L_) + (size_t)(2 * (m0 + a) + p)) * R_ + l * 4) = s;
    }
}

// ---------------------------------------------------------------------------
// MFMA chunked linear attention, self-contained per block (c,h,b):
//   H = sum_{c'<c} V_c'^T K_c'        (bf16 MFMA from kt/vt, fp32 acc)
//   St[s][t] = mfma(V, Q), masked s<=t; packed -> Sl[t][s]
//   Yt[n][t] = mfma(Kc, Sl-rows-t) + mfma(Hl-rows-n, Q)
//   gate fused: gx = bf16( xt + (Y - xt) * sigmoid(g) )
// ---------------------------------------------------------------------------
__global__ __launch_bounds__(256) void k_attn(const unsigned short* __restrict__ qbf,
                                              const unsigned short* __restrict__ vbf,
                                              const unsigned short* __restrict__ ktb,
                                              const unsigned short* __restrict__ vtb,
                                              const float* __restrict__ xt,
                                              const float* __restrict__ g,
                                              unsigned short* __restrict__ gx) {
    const int c = blockIdx.x, h = blockIdx.y, b = blockIdx.z;
    __shared__ unsigned short Qs[64 * 64];
    __shared__ unsigned short Vs[64 * 64];
    __shared__ unsigned short Kc[64 * 64];
    __shared__ unsigned short Tk[64 * 64];
    __shared__ unsigned short Tv[64 * 64];
    __shared__ unsigned short Sl[64 * 72];
    __shared__ unsigned short Hl[64 * 72];

    const int tid = threadIdx.x;
    const int lane = tid & 63, wave = tid >> 6;
    const int wr = (wave >> 1) * 32, wc = (wave & 1) * 32;
    const int l15 = lane & 15, lg = lane >> 4;

    {
        const size_t rowbase = ((size_t)(b * L_ + c * CS_)) * D_ + h * HD_;
        const size_t tbase = ((size_t)(b * NH_ + h)) * 64 * (size_t)L_ + c * 64;
#pragma unroll
        for (int q2 = 0; q2 < 2; ++q2) {
            const int s = q2 * 256 + tid;
            const int row = s >> 3, c8 = s & 7;
            GLD_LDS16(qbf + rowbase + (size_t)row * D_ + c8 * 8, &Qs[s * 8]);
            GLD_LDS16(vbf + rowbase + (size_t)row * D_ + c8 * 8, &Vs[s * 8]);
            GLD_LDS16(ktb + tbase + (size_t)row * L_ + c8 * 8, &Kc[s * 8]);
        }
    }

    f32x4 hacc[2][2] = {};
    for (int cc = 0; cc < c; ++cc) {
        __syncthreads();
        const size_t tb2 = ((size_t)(b * NH_ + h)) * 64 * (size_t)L_ + cc * 64;
#pragma unroll
        for (int q2 = 0; q2 < 2; ++q2) {
            const int s = q2 * 256 + tid;
            const int row = s >> 3, c8 = s & 7;
            GLD_LDS16(ktb + tb2 + (size_t)row * L_ + c8 * 8, &Tk[s * 8]);
            GLD_LDS16(vtb + tb2 + (size_t)row * L_ + c8 * 8, &Tv[s * 8]);
        }
        __syncthreads();
#pragma unroll
        for (int ks = 0; ks < 2; ++ks) {
            const int kb = ks * 32 + lg * 8;
            bf16x8 av[2], bk[2];
#pragma unroll
            for (int f = 0; f < 2; ++f) {
                av[f] = *reinterpret_cast<const bf16x8*>(&Tv[(wr + f * 16 + l15) * 64 + kb]);
                bk[f] = *reinterpret_cast<const bf16x8*>(&Tk[(wc + f * 16 + l15) * 64 + kb]);
            }
#pragma unroll
            for (int fm = 0; fm < 2; ++fm)
#pragma unroll
                for (int fn = 0; fn < 2; ++fn)
                    hacc[fm][fn] = __builtin_amdgcn_mfma_f32_16x16x32_bf16(
                        av[fm], bk[fn], hacc[fm][fn], 0, 0, 0);
        }
    }
    __syncthreads();

    if (c > 0) {
#pragma unroll
        for (int fm = 0; fm < 2; ++fm)
#pragma unroll
            for (int fn = 0; fn < 2; ++fn) {
                const int n = wc + fn * 16 + l15;
                const int p0 = wr + fm * 16 + lg * 4;
                *reinterpret_cast<ushort4*>(&Hl[n * 72 + p0]) = pack4(hacc[fm][fn]);
            }
    }

    {
        f32x4 sacc[2][2] = {};
#pragma unroll
        for (int ks = 0; ks < 2; ++ks) {
            const int kb = ks * 32 + lg * 8;
            bf16x8 av[2], bq[2];
#pragma unroll
            for (int f = 0; f < 2; ++f) {
                av[f] = *reinterpret_cast<const bf16x8*>(&Vs[(wr + f * 16 + l15) * 64 + kb]);
                bq[f] = *reinterpret_cast<const bf16x8*>(&Qs[(wc + f * 16 + l15) * 64 + kb]);
            }
#pragma unroll
            for (int fm = 0; fm < 2; ++fm)
#pragma unroll
                for (int fn = 0; fn < 2; ++fn)
                    sacc[fm][fn] = __builtin_amdgcn_mfma_f32_16x16x32_bf16(
                        av[fm], bq[fn], sacc[fm][fn], 0, 0, 0);
        }
#pragma unroll
        for (int fm = 0; fm < 2; ++fm)
#pragma unroll
            for (int fn = 0; fn < 2; ++fn) {
                const int t = wc + fn * 16 + l15;
                const int s0 = wr + fm * 16 + lg * 4;
#pragma unroll
                for (int j = 0; j < 4; ++j)
                    if (s0 + j > t) sacc[fm][fn][j] = 0.f;
                *reinterpret_cast<ushort4*>(&Sl[t * 72 + s0]) = pack4(sacc[fm][fn]);
            }
    }
    __syncthreads();

    f32x4 yacc[2][2] = {};
#pragma unroll
    for (int ks = 0; ks < 2; ++ks) {
        const int kb = ks * 32 + lg * 8;
        bf16x8 ak[2], bs[2];
#pragma unroll
        for (int f = 0; f < 2; ++f) {
            ak[f] = *reinterpret_cast<const bf16x8*>(&Kc[(wr + f * 16 + l15) * 64 + kb]);
            bs[f] = *reinterpret_cast<const bf16x8*>(&Sl[(wc + f * 16 + l15) * 72 + kb]);
        }
#pragma unroll
        for (int fm = 0; fm < 2; ++fm)
#pragma unroll
            for (int fn = 0; fn < 2; ++fn)
                yacc[fm][fn] = __builtin_amdgcn_mfma_f32_16x16x32_bf16(
                    ak[fm], bs[fn], yacc[fm][fn], 0, 0, 0);
    }
    if (c > 0) {
#pragma unroll
        for (int ks = 0; ks < 2; ++ks) {
            const int kb = ks * 32 + lg * 8;
            bf16x8 ah[2], bq[2];
#pragma unroll
            for (int f = 0; f < 2; ++f) {
                ah[f] = *reinterpret_cast<const bf16x8*>(&Hl[(wr + f * 16 + l15) * 72 + kb]);
                bq[f] = *reinterpret_cast<const bf16x8*>(&Qs[(wc + f * 16 + l15) * 64 + kb]);
            }
#pragma unroll
            for (int fm = 0; fm < 2; ++fm)
#pragma unroll
                for (int fn = 0; fn < 2; ++fn)
                    yacc[fm][fn] = __builtin_amdgcn_mfma_f32_16x16x32_bf16(
                        ah[fm], bq[fn], yacc[fm][fn], 0, 0, 0);
        }
    }

#pragma unroll
    for (int fm = 0; fm < 2; ++fm)
#pragma unroll
        for (int fn = 0; fn < 2; ++fn) {
            const int n0 = wr + fm * 16 + lg * 4;
            const int t = wc + fn * 16 + l15;
            const size_t idx = ((size_t)(b * L_ + c * CS_ + t)) * D_ + h * HD_ + n0;
            const float4 gv = *reinterpret_cast<const float4*>(g + idx);
            const float4 xv = *reinterpret_cast<const float4*>(xt + idx);
            f32x4 y = yacc[fm][fn];
            ushort4 o;
            {
                const float s0 = 1.f / (1.f + expf(-gv.x));
                o.x = f2bf(xv.x + (y[0] - xv.x) * s0);
                const float s1 = 1.f / (1.f + expf(-gv.y));
                o.y = f2bf(xv.y + (y[1] - xv.y) * s1);
                const float s2 = 1.f / (1.f + expf(-gv.z));
                o.z = f2bf(xv.z + (y[2] - xv.z) * s2);
                const float s3 = 1.f / (1.f + expf(-gv.w));
                o.w = f2bf(xv.w + (y[3] - xv.w) * s3);
            }
            *reinterpret_cast<ushort4*>(gx + idx) = o;
        }
}

// ---------------------------------------------------------------------------
extern "C" void kernel_launch(void* const* d_in, const int* in_sizes, int n_in,
                              void* d_out, int out_size, void* d_ws, size_t ws_size,
                              hipStream_t stream) {
    const float* x    = (const float*)d_in[0];
    const float* stu  = (const float*)d_in[1];
    const float* Mi   = (const float*)d_in[2];
    const float* Mf   = (const float*)d_in[3];
    const float* wq_w = (const float*)d_in[4];
    const float* wq_b = (const float*)d_in[5];
    const float* wk_w = (const float*)d_in[6];
    const float* wk_b = (const float*)d_in[7];
    const float* wv_w = (const float*)d_in[8];
    const float* wv_b = (const float*)d_in[9];
    const float* wg_w = (const float*)d_in[10];
    const float* wg_b = (const float*)d_in[11];
    const float* wo_w = (const float*)d_in[12];
    const float* wo_b = (const float*)d_in[13];
    float* out = (float*)d_out;

    char* ws = (char*)d_ws;
    size_t o = 0;
    const size_t WSZ = (size_t)D_ * D_;
    unsigned short* wbf = (unsigned short*)(ws + o); o += 6 * WSZ * 2;
    unsigned short* xbf = (unsigned short*)(ws + o); o += (size_t)B_ * L_ * D_ * 2;
    unsigned short* gx  = (unsigned short*)(ws + o); o += (size_t)B_ * L_ * D_ * 2;
    unsigned short* qbf = (unsigned short*)(ws + o); o += (size_t)B_ * L_ * D_ * 2;
    unsigned short* vbf = (unsigned short*)(ws + o); o += (size_t)B_ * L_ * D_ * 2;
    unsigned short* ktb = (unsigned short*)(ws + o); o += (size_t)B_ * NH_ * 64 * L_ * 2;
    unsigned short* vtb = (unsigned short*)(ws + o); o += (size_t)B_ * NH_ * 64 * L_ * 2;
    float* ubuf = (float*)(ws + o); o += (size_t)B_ * L_ * R_ * 4;
    float* phi2 = (float*)(ws + o); o += (size_t)L_ * R_ * 4;
    float* xt   = (float*)(ws + o); o += (size_t)B_ * L_ * R_ * 4;
    float* gb   = (float*)(ws + o); o += (size_t)B_ * L_ * D_ * 4;

    unsigned short* wo_t = wbf + 5 * WSZ;

    const dim3 blk(256);

    k_prep<<<dim3(4704), blk, 0, stream>>>(Mi, wq_w, wk_w, wv_w, wg_w, wo_w, wbf,
                                           x, xbf, stu, Mf, phi2);

    k_gemm5<<<dim3(D_ / 128, (B_ * L_) / 128, 5), blk, 0, stream>>>(
        xbf, wbf, wq_b, wk_b, wv_b, wg_b, ubuf, qbf, ktb, vbf, vtb, gb);

    k_conv<<<dim3(L_ / 2 / 8, B_ * 2), dim3(768), 0, stream>>>(ubuf, phi2, xt);

    k_attn<<<dim3(NC_, NH_, B_), blk, 0, stream>>>(qbf, vbf, ktb, vtb, xt, gb, gx);

    k_gemm<<<dim3(D_ / 64, (B_ * L_) / 64), blk, 0, stream>>>(gx, wo_t, wo_b, out, D_, D_);
}

// Round 10
// 96.036 us; speedup vs baseline: 8.3004x; 1.0418x over previous
//
#include <hip/hip_runtime.h>
#include <math.h>

#define B_  2
#define L_  1024
#define D_  768
#define NH_ 12
#define HD_ 64
#define K_  24
#define R_  768
#define NC_ 16   // chunks
#define CS_ 64   // chunk size

typedef __bf16 bf16x8 __attribute__((ext_vector_type(8)));
typedef float f32x4 __attribute__((ext_vector_type(4)));
typedef float f32x8 __attribute__((ext_vector_type(8)));
typedef unsigned short u16x8 __attribute__((ext_vector_type(8)));

__device__ inline unsigned short f2bf(float f) {
    union { float f; unsigned u; } v; v.f = f;
    unsigned r = v.u + 0x7FFFu + ((v.u >> 16) & 1u);
    return (unsigned short)(r >> 16);
}

__device__ inline ushort4 pack4(const f32x4 v) {
    ushort4 r;
    r.x = f2bf(v[0]); r.y = f2bf(v[1]); r.z = f2bf(v[2]); r.w = f2bf(v[3]);
    return r;
}

__device__ inline u16x8 pack8(const f32x8 v) {
    u16x8 r;
#pragma unroll
    for (int e = 0; e < 8; ++e) r[e] = f2bf(v[e]);
    return r;
}

__device__ inline f32x8 bf2f8(const u16x8 v) {
    f32x8 r;
#pragma unroll
    for (int e = 0; e < 8; ++e) {
        union { float f; unsigned u; } t;
        t.u = ((unsigned)v[e]) << 16;
        r[e] = t.f;
    }
    return r;
}

// async global->LDS, 16 B per lane (literal size per guide)
#define GLD_LDS16(g, l)                                                     \
    __builtin_amdgcn_global_load_lds(                                       \
        (const __attribute__((address_space(1))) void*)(g),                 \
        (__attribute__((address_space(3))) void*)(l), 16, 0, 0)

// ---------------------------------------------------------------------------
// Fused prep: [0,864)    weight transposes (6x 768x768 fp32 -> bf16 T)
//             [864,1632) x fp32 -> bf16
//             [1632,3168) phiev[n][r] = bf16( 2 * sum_k stu[2n][k]*Mf[k][r] )
// ---------------------------------------------------------------------------
__global__ __launch_bounds__(256) void k_prep(const float* __restrict__ w0,
                                              const float* __restrict__ w1,
                                              const float* __restrict__ w2,
                                              const float* __restrict__ w3,
                                              const float* __restrict__ w4,
                                              const float* __restrict__ w5,
                                              unsigned short* __restrict__ Wt,
                                              const float* __restrict__ x,
                                              unsigned short* __restrict__ xb,
                                              const float* __restrict__ F,
                                              const float* __restrict__ Mf,
                                              unsigned short* __restrict__ phiev) {
    const int bid = blockIdx.x;
    const int tid = threadIdx.x;
    if (bid < 864) {
        const int z = bid / 144, rem = bid % 144;
        const float* W;
        switch (z) {
            case 0: W = w0; break;
            case 1: W = w1; break;
            case 2: W = w2; break;
            case 3: W = w3; break;
            case 4: W = w4; break;
            default: W = w5; break;
        }
        unsigned short* o = Wt + (size_t)z * D_ * D_;
        __shared__ float t[64][65];
        const int n0 = (rem % 12) * 64, k0 = (rem / 12) * 64;
        const int c = tid & 63, rq = tid >> 6;
#pragma unroll
        for (int i = 0; i < 16; ++i)
            t[rq + i * 4][c] = W[(size_t)(k0 + rq + i * 4) * D_ + n0 + c];
        __syncthreads();
#pragma unroll
        for (int i = 0; i < 16; ++i)
            o[(size_t)(n0 + rq + i * 4) * D_ + k0 + c] = f2bf(t[c][rq + i * 4]);
    } else if (bid < 1632) {
        const int i8 = ((bid - 864) * 256 + tid) * 8;
        float4 f0 = *reinterpret_cast<const float4*>(x + i8);
        float4 f1 = *reinterpret_cast<const float4*>(x + i8 + 4);
        u16x8 p;
        p[0] = f2bf(f0.x); p[1] = f2bf(f0.y); p[2] = f2bf(f0.z); p[3] = f2bf(f0.w);
        p[4] = f2bf(f1.x); p[5] = f2bf(f1.y); p[6] = f2bf(f1.z); p[7] = f2bf(f1.w);
        *reinterpret_cast<u16x8*>(xb + i8) = p;
    } else {
        const int idx = (bid - 1632) * 256 + tid;    // over 512*768
        const int r = idx % R_;
        const int n = idx / R_;
        float acc = 0.f;
#pragma unroll
        for (int kk = 0; kk < K_; ++kk)
            acc += F[(2 * n) * K_ + kk] * Mf[kk * R_ + r];
        phiev[idx] = f2bf(2.f * acc);
    }
}

// ---------------------------------------------------------------------------
// bf16 MFMA GEMM core, 2-phase double-buffered. BM = 2*FM*16, BN = 2*FN*16.
// mode 0: fp32 C[row*N+col] (+bias)
// mode 1: bf16 row-major cbf[row*768+col] (+bias)
// mode 2: bf16 transposed ct[((b*12+h)*64+n)*1024 + l] (+bias)
// mode 3: mode1 + mode2
// ---------------------------------------------------------------------------
template <int FM, int FN>
__device__ __forceinline__ void gemm_core(const unsigned short* __restrict__ A,
                                          const unsigned short* __restrict__ Bt,
                                          const float* __restrict__ bias,
                                          int mode,
                                          float* __restrict__ cf,
                                          unsigned short* __restrict__ cbf,
                                          unsigned short* __restrict__ ct,
                                          int N, int Kd,
                                          int bm, int bn, int tid) {
    constexpr int BM = 2 * FM * 16;
    constexpr int BN = 2 * FN * 16;
    __shared__ unsigned short As[2][BM * 64];
    __shared__ unsigned short Bs[2][BN * 64];
    const int lane = tid & 63, wave = tid >> 6;
    const int wm = (wave >> 1) * (FM * 16), wn = (wave & 1) * (FN * 16);
    const int l15 = lane & 15, lg = lane >> 4;

    f32x4 acc[FM][FN] = {};

    auto stage = [&](int buf, int k0) {
#pragma unroll
        for (int q = 0; q < FM; ++q) {
            const int s = q * 256 + tid;
            GLD_LDS16(A + (size_t)(bm + (s >> 3)) * Kd + k0 + (s & 7) * 8,
                      &As[buf][s * 8]);
        }
#pragma unroll
        for (int q = 0; q < FN; ++q) {
            const int s = q * 256 + tid;
            GLD_LDS16(Bt + (size_t)(bn + (s >> 3)) * Kd + k0 + (s & 7) * 8,
                      &Bs[buf][s * 8]);
        }
    };

    stage(0, 0);
    __syncthreads();
    int cur = 0;
    const int nt = Kd / 64;
    for (int t = 0; t < nt; ++t) {
        if (t + 1 < nt) stage(cur ^ 1, (t + 1) * 64);
#pragma unroll
        for (int ks = 0; ks < 2; ++ks) {
            const int kb = ks * 32 + lg * 8;
            bf16x8 a[FM], b[FN];
#pragma unroll
            for (int f = 0; f < FM; ++f)
                a[f] = *reinterpret_cast<const bf16x8*>(
                    &As[cur][(wm + f * 16 + l15) * 64 + kb]);
#pragma unroll
            for (int f = 0; f < FN; ++f)
                b[f] = *reinterpret_cast<const bf16x8*>(
                    &Bs[cur][(wn + f * 16 + l15) * 64 + kb]);
#pragma unroll
            for (int fm = 0; fm < FM; ++fm)
#pragma unroll
                for (int fn = 0; fn < FN; ++fn)
                    acc[fm][fn] = __builtin_amdgcn_mfma_f32_16x16x32_bf16(
                        a[fm], b[fn], acc[fm][fn], 0, 0, 0);
        }
        __syncthreads();
        cur ^= 1;
    }

#pragma unroll
    for (int fm = 0; fm < FM; ++fm)
#pragma unroll
        for (int fn = 0; fn < FN; ++fn) {
            const int col = bn + wn + fn * 16 + l15;
            const float bv = bias ? bias[col] : 0.f;
            const int r0 = bm + wm + fm * 16 + lg * 4;
            f32x4 v = acc[fm][fn];
            v[0] += bv; v[1] += bv; v[2] += bv; v[3] += bv;
            if (mode == 0) {
#pragma unroll
                for (int j = 0; j < 4; ++j)
                    cf[(size_t)(r0 + j) * N + col] = v[j];
            }
            if (mode & 1) {
#pragma unroll
                for (int j = 0; j < 4; ++j)
                    cbf[(size_t)(r0 + j) * D_ + col] = f2bf(v[j]);
            }
            if (mode & 2) {
                const int h = col >> 6, n = col & 63;
                const int bI = r0 >> 10, l0 = r0 & 1023;
                *reinterpret_cast<ushort4*>(
                    ct + (((size_t)bI * NH_ + h) * 64 + n) * (size_t)L_ + l0) =
                    pack4(v);
            }
        }
}

// output projection: fp32 out, 64x64 tile
__global__ __launch_bounds__(256) void k_gemm(const unsigned short* __restrict__ A,
                                              const unsigned short* __restrict__ Bt,
                                              const float* __restrict__ bias,
                                              float* __restrict__ C,
                                              int N, int Kd) {
    gemm_core<2, 2>(A, Bt, bias, 0, C, nullptr, nullptr, N, Kd,
                    blockIdx.y * 64, blockIdx.x * 64, threadIdx.x);
}

// 5 x-projections; z selects output format:
// z=0: u bf16 row; z=1: q bf16 row; z=2: kt transposed; z=3: v bf16 row + vt;
// z=4: g bf16 row
__global__ __launch_bounds__(256) void k_gemm5(const unsigned short* __restrict__ A,
                                               const unsigned short* __restrict__ wt,
                                               const float* __restrict__ bq,
                                               const float* __restrict__ bk,
                                               const float* __restrict__ bv,
                                               const float* __restrict__ bg,
                                               unsigned short* __restrict__ ubf,
                                               unsigned short* __restrict__ qbf,
                                               unsigned short* __restrict__ ktb,
                                               unsigned short* __restrict__ vbf,
                                               unsigned short* __restrict__ vtb,
                                               unsigned short* __restrict__ gbf) {
    const int z = blockIdx.z;
    const float* bias = nullptr;
    int mode = 1;
    unsigned short* cbf = nullptr; unsigned short* ct = nullptr;
    switch (z) {
        case 0: mode = 1; cbf = ubf; bias = nullptr; break;
        case 1: mode = 1; cbf = qbf; bias = bq; break;
        case 2: mode = 2; ct = ktb; bias = bk; break;
        case 3: mode = 3; cbf = vbf; ct = vtb; bias = bv; break;
        default: mode = 1; cbf = gbf; bias = bg; break;
    }
    const unsigned short* Bt = wt + (size_t)z * D_ * D_;
    gemm_core<4, 4>(A, Bt, bias, mode, nullptr, cbf, ct, D_, D_,
                    blockIdx.y * 128, blockIdx.x * 128, threadIdx.x);
}

// ---------------------------------------------------------------------------
// MFMA chunked linear attention (pre-gate): per block (c,h,b):
//   H = sum_{c'<c} V^T K ; St = mfma(V,Q) masked; Y = mfma(Kc,S) + mfma(H,Q)
//   writes ya bf16 row-major.
// ---------------------------------------------------------------------------
__global__ __launch_bounds__(256) void k_attn(const unsigned short* __restrict__ qbf,
                                              const unsigned short* __restrict__ vbf,
                                              const unsigned short* __restrict__ ktb,
                                              const unsigned short* __restrict__ vtb,
                                              unsigned short* __restrict__ yab) {
    const int c = blockIdx.x, h = blockIdx.y, b = blockIdx.z;
    __shared__ unsigned short Qs[64 * 64];
    __shared__ unsigned short Vs[64 * 64];
    __shared__ unsigned short Kc[64 * 64];
    __shared__ unsigned short Tk[64 * 64];
    __shared__ unsigned short Tv[64 * 64];
    __shared__ unsigned short Sl[64 * 72];
    __shared__ unsigned short Hl[64 * 72];

    const int tid = threadIdx.x;
    const int lane = tid & 63, wave = tid >> 6;
    const int wr = (wave >> 1) * 32, wc = (wave & 1) * 32;
    const int l15 = lane & 15, lg = lane >> 4;

    {
        const size_t rowbase = ((size_t)(b * L_ + c * CS_)) * D_ + h * HD_;
        const size_t tbase = ((size_t)(b * NH_ + h)) * 64 * (size_t)L_ + c * 64;
#pragma unroll
        for (int q2 = 0; q2 < 2; ++q2) {
            const int s = q2 * 256 + tid;
            const int row = s >> 3, c8 = s & 7;
            GLD_LDS16(qbf + rowbase + (size_t)row * D_ + c8 * 8, &Qs[s * 8]);
            GLD_LDS16(vbf + rowbase + (size_t)row * D_ + c8 * 8, &Vs[s * 8]);
            GLD_LDS16(ktb + tbase + (size_t)row * L_ + c8 * 8, &Kc[s * 8]);
        }
    }

    f32x4 hacc[2][2] = {};
    for (int cc = 0; cc < c; ++cc) {
        __syncthreads();
        const size_t tb2 = ((size_t)(b * NH_ + h)) * 64 * (size_t)L_ + cc * 64;
#pragma unroll
        for (int q2 = 0; q2 < 2; ++q2) {
            const int s = q2 * 256 + tid;
            const int row = s >> 3, c8 = s & 7;
            GLD_LDS16(ktb + tb2 + (size_t)row * L_ + c8 * 8, &Tk[s * 8]);
            GLD_LDS16(vtb + tb2 + (size_t)row * L_ + c8 * 8, &Tv[s * 8]);
        }
        __syncthreads();
#pragma unroll
        for (int ks = 0; ks < 2; ++ks) {
            const int kb = ks * 32 + lg * 8;
            bf16x8 av[2], bk[2];
#pragma unroll
            for (int f = 0; f < 2; ++f) {
                av[f] = *reinterpret_cast<const bf16x8*>(&Tv[(wr + f * 16 + l15) * 64 + kb]);
                bk[f] = *reinterpret_cast<const bf16x8*>(&Tk[(wc + f * 16 + l15) * 64 + kb]);
            }
#pragma unroll
            for (int fm = 0; fm < 2; ++fm)
#pragma unroll
                for (int fn = 0; fn < 2; ++fn)
                    hacc[fm][fn] = __builtin_amdgcn_mfma_f32_16x16x32_bf16(
                        av[fm], bk[fn], hacc[fm][fn], 0, 0, 0);
        }
    }
    __syncthreads();

    if (c > 0) {
#pragma unroll
        for (int fm = 0; fm < 2; ++fm)
#pragma unroll
            for (int fn = 0; fn < 2; ++fn) {
                const int n = wc + fn * 16 + l15;
                const int p0 = wr + fm * 16 + lg * 4;
                *reinterpret_cast<ushort4*>(&Hl[n * 72 + p0]) = pack4(hacc[fm][fn]);
            }
    }

    {
        f32x4 sacc[2][2] = {};
#pragma unroll
        for (int ks = 0; ks < 2; ++ks) {
            const int kb = ks * 32 + lg * 8;
            bf16x8 av[2], bq[2];
#pragma unroll
            for (int f = 0; f < 2; ++f) {
                av[f] = *reinterpret_cast<const bf16x8*>(&Vs[(wr + f * 16 + l15) * 64 + kb]);
                bq[f] = *reinterpret_cast<const bf16x8*>(&Qs[(wc + f * 16 + l15) * 64 + kb]);
            }
#pragma unroll
            for (int fm = 0; fm < 2; ++fm)
#pragma unroll
                for (int fn = 0; fn < 2; ++fn)
                    sacc[fm][fn] = __builtin_amdgcn_mfma_f32_16x16x32_bf16(
                        av[fm], bq[fn], sacc[fm][fn], 0, 0, 0);
        }
#pragma unroll
        for (int fm = 0; fm < 2; ++fm)
#pragma unroll
            for (int fn = 0; fn < 2; ++fn) {
                const int t = wc + fn * 16 + l15;
                const int s0 = wr + fm * 16 + lg * 4;
#pragma unroll
                for (int j = 0; j < 4; ++j)
                    if (s0 + j > t) sacc[fm][fn][j] = 0.f;
                *reinterpret_cast<ushort4*>(&Sl[t * 72 + s0]) = pack4(sacc[fm][fn]);
            }
    }
    __syncthreads();

    f32x4 yacc[2][2] = {};
#pragma unroll
    for (int ks = 0; ks < 2; ++ks) {
        const int kb = ks * 32 + lg * 8;
        bf16x8 ak[2], bs[2];
#pragma unroll
        for (int f = 0; f < 2; ++f) {
            ak[f] = *reinterpret_cast<const bf16x8*>(&Kc[(wr + f * 16 + l15) * 64 + kb]);
            bs[f] = *reinterpret_cast<const bf16x8*>(&Sl[(wc + f * 16 + l15) * 72 + kb]);
        }
#pragma unroll
        for (int fm = 0; fm < 2; ++fm)
#pragma unroll
            for (int fn = 0; fn < 2; ++fn)
                yacc[fm][fn] = __builtin_amdgcn_mfma_f32_16x16x32_bf16(
                    ak[fm], bs[fn], yacc[fm][fn], 0, 0, 0);
    }
    if (c > 0) {
#pragma unroll
        for (int ks = 0; ks < 2; ++ks) {
            const int kb = ks * 32 + lg * 8;
            bf16x8 ah[2], bq[2];
#pragma unroll
            for (int f = 0; f < 2; ++f) {
                ah[f] = *reinterpret_cast<const bf16x8*>(&Hl[(wr + f * 16 + l15) * 72 + kb]);
                bq[f] = *reinterpret_cast<const bf16x8*>(&Qs[(wc + f * 16 + l15) * 64 + kb]);
            }
#pragma unroll
            for (int fm = 0; fm < 2; ++fm)
#pragma unroll
                for (int fn = 0; fn < 2; ++fn)
                    yacc[fm][fn] = __builtin_amdgcn_mfma_f32_16x16x32_bf16(
                        ah[fm], bq[fn], yacc[fm][fn], 0, 0, 0);
        }
    }

#pragma unroll
    for (int fm = 0; fm < 2; ++fm)
#pragma unroll
        for (int fn = 0; fn < 2; ++fn) {
            const int n0 = wr + fm * 16 + lg * 4;
            const int t = wc + fn * 16 + l15;
            const size_t idx = ((size_t)(b * L_ + c * CS_ + t)) * D_ + h * HD_ + n0;
            *reinterpret_cast<ushort4*>(yab + idx) = pack4(yacc[fm][fn]);
        }
}

// ---------------------------------------------------------------------------
// Parity-split causal conv, bf16x8, 8-way n-split, fused gate epilogue:
// xt[2m+p,r] = sum_{n<=m} phiev[n,r]*u[2(m-n)+p,r]  (f32 acc, bf16 partials)
// gx = bf16( xt + (ya - xt) * sigmoid(g) )
// ---------------------------------------------------------------------------
__global__ __launch_bounds__(768) void k_conv(const unsigned short* __restrict__ ubf,
                                              const unsigned short* __restrict__ phiev,
                                              const unsigned short* __restrict__ yab,
                                              const unsigned short* __restrict__ gbf,
                                              unsigned short* __restrict__ gx) {
    __shared__ u16x8 red[8][8][96];             // 98304 B
    const int tid = threadIdx.x;
    const int g   = tid / 96;                   // n-split group 0..7
    const int lr  = tid % 96;                   // r8 channel group
    const int r   = lr * 8;
    const int m0  = blockIdx.x * 8;
    const int bp  = blockIdx.y;
    const int b   = bp >> 1, p = bp & 1;

    f32x8 acc[8] = {};
    f32x8 w[8]   = {};

    const int ns = g * 64;
    const int ne = min(ns + 64, m0 + 8);

    if (ns < ne) {
        if (g > 0) {
#pragma unroll
            for (int j = 1; j <= 7; ++j)
                w[(8 - j) & 7] = bf2f8(
                    *reinterpret_cast<const u16x8*>(phiev + (size_t)(ns - j) * R_ + r));
        }
        const unsigned short* pp = phiev + (size_t)ns * R_ + r;
        const unsigned short* up =
            ubf + ((size_t)(b * L_) + (size_t)(2 * (m0 + 7 - ns) + p)) * R_ + r;
        for (int i = ns; i < ne; i += 8) {
#pragma unroll
            for (int k = 0; k < 8; ++k) {
                const u16x8 pv = *reinterpret_cast<const u16x8*>(pp);
                const u16x8 uv = *reinterpret_cast<const u16x8*>(up);
                w[k] = bf2f8(pv);
                const f32x8 fu = bf2f8(uv);
#pragma unroll
                for (int a = 0; a < 8; ++a)
                    acc[a] += w[(k + a + 1) & 7] * fu;
                pp += R_;
                up -= 2 * R_;
            }
        }
    }

#pragma unroll
    for (int a = 0; a < 8; ++a) red[g][a][lr] = pack8(acc[a]);
    __syncthreads();

    // one output row-slice per thread: a2 = tid/96, l2 = tid%96
    const int a2 = tid / 96, l2 = tid % 96;
    f32x8 s = {};
#pragma unroll
    for (int g2 = 0; g2 < 8; ++g2) s += bf2f8(red[g2][a2][l2]);

    const size_t idx = ((size_t)(b * L_) + (size_t)(2 * (m0 + a2) + p)) * R_ + l2 * 8;
    const f32x8 yf = bf2f8(*reinterpret_cast<const u16x8*>(yab + idx));
    const f32x8 gf = bf2f8(*reinterpret_cast<const u16x8*>(gbf + idx));
    u16x8 o;
#pragma unroll
    for (int e = 0; e < 8; ++e) {
        const float sg = 1.f / (1.f + expf(-gf[e]));
        o[e] = f2bf(s[e] + (yf[e] - s[e]) * sg);
    }
    *reinterpret_cast<u16x8*>(gx + idx) = o;
}

// ---------------------------------------------------------------------------
extern "C" void kernel_launch(void* const* d_in, const int* in_sizes, int n_in,
                              void* d_out, int out_size, void* d_ws, size_t ws_size,
                              hipStream_t stream) {
    const float* x    = (const float*)d_in[0];
    const float* stu  = (const float*)d_in[1];
    const float* Mi   = (const float*)d_in[2];
    const float* Mf   = (const float*)d_in[3];
    const float* wq_w = (const float*)d_in[4];
    const float* wq_b = (const float*)d_in[5];
    const float* wk_w = (const float*)d_in[6];
    const float* wk_b = (const float*)d_in[7];
    const float* wv_w = (const float*)d_in[8];
    const float* wv_b = (const float*)d_in[9];
    const float* wg_w = (const float*)d_in[10];
    const float* wg_b = (const float*)d_in[11];
    const float* wo_w = (const float*)d_in[12];
    const float* wo_b = (const float*)d_in[13];
    float* out = (float*)d_out;

    char* ws = (char*)d_ws;
    size_t o = 0;
    const size_t WSZ = (size_t)D_ * D_;
    unsigned short* wbf   = (unsigned short*)(ws + o); o += 6 * WSZ * 2;
    unsigned short* xbf   = (unsigned short*)(ws + o); o += (size_t)B_ * L_ * D_ * 2;
    unsigned short* gx    = (unsigned short*)(ws + o); o += (size_t)B_ * L_ * D_ * 2;
    unsigned short* qbf   = (unsigned short*)(ws + o); o += (size_t)B_ * L_ * D_ * 2;
    unsigned short* vbf   = (unsigned short*)(ws + o); o += (size_t)B_ * L_ * D_ * 2;
    unsigned short* ubf   = (unsigned short*)(ws + o); o += (size_t)B_ * L_ * D_ * 2;
    unsigned short* gbf   = (unsigned short*)(ws + o); o += (size_t)B_ * L_ * D_ * 2;
    unsigned short* yab   = (unsigned short*)(ws + o); o += (size_t)B_ * L_ * D_ * 2;
    unsigned short* ktb   = (unsigned short*)(ws + o); o += (size_t)B_ * NH_ * 64 * L_ * 2;
    unsigned short* vtb   = (unsigned short*)(ws + o); o += (size_t)B_ * NH_ * 64 * L_ * 2;
    unsigned short* phiev = (unsigned short*)(ws + o); o += (size_t)(L_ / 2) * R_ * 2;

    unsigned short* wo_t = wbf + 5 * WSZ;

    const dim3 blk(256);

    k_prep<<<dim3(3168), blk, 0, stream>>>(Mi, wq_w, wk_w, wv_w, wg_w, wo_w, wbf,
                                           x, xbf, stu, Mf, phiev);

    k_gemm5<<<dim3(D_ / 128, (B_ * L_) / 128, 5), blk, 0, stream>>>(
        xbf, wbf, wq_b, wk_b, wv_b, wg_b, ubf, qbf, ktb, vbf, vtb, gbf);

    k_attn<<<dim3(NC_, NH_, B_), blk, 0, stream>>>(qbf, vbf, ktb, vtb, yab);

    k_conv<<<dim3(L_ / 2 / 8, B_ * 2), dim3(768), 0, stream>>>(ubf, phiev, yab, gbf, gx);

    k_gemm<<<dim3(D_ / 64, (B_ * L_) / 64), blk, 0, stream>>>(gx, wo_t, wo_b, out, D_, D_);
}

// Round 11
// 91.939 us; speedup vs baseline: 8.6703x; 1.0446x over previous
//
#include <hip/hip_runtime.h>
#include <math.h>

#define B_  2
#define L_  1024
#define D_  768
#define NH_ 12
#define HD_ 64
#define K_  24
#define R_  768
#define NC_ 16   // chunks
#define CS_ 64   // chunk size

typedef __bf16 bf16x8 __attribute__((ext_vector_type(8)));
typedef float f32x4 __attribute__((ext_vector_type(4)));
typedef float f32x8 __attribute__((ext_vector_type(8)));
typedef unsigned short u16x8 __attribute__((ext_vector_type(8)));

__device__ inline unsigned short f2bf(float f) {
    union { float f; unsigned u; } v; v.f = f;
    unsigned r = v.u + 0x7FFFu + ((v.u >> 16) & 1u);
    return (unsigned short)(r >> 16);
}

__device__ inline ushort4 pack4(const f32x4 v) {
    ushort4 r;
    r.x = f2bf(v[0]); r.y = f2bf(v[1]); r.z = f2bf(v[2]); r.w = f2bf(v[3]);
    return r;
}

__device__ inline u16x8 pack8(const f32x8 v) {
    u16x8 r;
#pragma unroll
    for (int e = 0; e < 8; ++e) r[e] = f2bf(v[e]);
    return r;
}

__device__ inline f32x8 bf2f8(const u16x8 v) {
    f32x8 r;
#pragma unroll
    for (int e = 0; e < 8; ++e) {
        union { float f; unsigned u; } t;
        t.u = ((unsigned)v[e]) << 16;
        r[e] = t.f;
    }
    return r;
}

// async global->LDS, 16 B per lane (literal size per guide)
#define GLD_LDS16(g, l)                                                     \
    __builtin_amdgcn_global_load_lds(                                       \
        (const __attribute__((address_space(1))) void*)(g),                 \
        (__attribute__((address_space(3))) void*)(l), 16, 0, 0)

// ---------------------------------------------------------------------------
// Fused prep: [0,864)    weight transposes (6x 768x768 fp32 -> bf16 T)
//             [864,1632) x fp32 -> bf16
// (phiev moved into k_attn's grid tail)
// ---------------------------------------------------------------------------
__global__ __launch_bounds__(256) void k_prep(const float* __restrict__ w0,
                                              const float* __restrict__ w1,
                                              const float* __restrict__ w2,
                                              const float* __restrict__ w3,
                                              const float* __restrict__ w4,
                                              const float* __restrict__ w5,
                                              unsigned short* __restrict__ Wt,
                                              const float* __restrict__ x,
                                              unsigned short* __restrict__ xb) {
    const int bid = blockIdx.x;
    const int tid = threadIdx.x;
    if (bid < 864) {
        const int z = bid / 144, rem = bid % 144;
        const float* W;
        switch (z) {
            case 0: W = w0; break;
            case 1: W = w1; break;
            case 2: W = w2; break;
            case 3: W = w3; break;
            case 4: W = w4; break;
            default: W = w5; break;
        }
        unsigned short* o = Wt + (size_t)z * D_ * D_;
        __shared__ float t[64][69];       // t[kk][nn] = W[k0+kk][n0+nn]
        const int n0 = (rem % 12) * 64, k0 = (rem / 12) * 64;
        const int row = tid >> 4, c4 = (tid & 15) * 4;
#pragma unroll
        for (int i = 0; i < 4; ++i) {
            const float4 v = *reinterpret_cast<const float4*>(
                W + (size_t)(k0 + row + i * 16) * D_ + n0 + c4);
            t[row + i * 16][c4 + 0] = v.x;
            t[row + i * 16][c4 + 1] = v.y;
            t[row + i * 16][c4 + 2] = v.z;
            t[row + i * 16][c4 + 3] = v.w;
        }
        __syncthreads();
        const int orow = tid >> 4, oc4 = (tid & 15) * 4;
#pragma unroll
        for (int i = 0; i < 4; ++i) {
            const int nn = orow + i * 16;
            ushort4 o4;
            o4.x = f2bf(t[oc4 + 0][nn]);
            o4.y = f2bf(t[oc4 + 1][nn]);
            o4.z = f2bf(t[oc4 + 2][nn]);
            o4.w = f2bf(t[oc4 + 3][nn]);
            *reinterpret_cast<ushort4*>(o + (size_t)(n0 + nn) * D_ + k0 + oc4) = o4;
        }
    } else {
        const int i8 = ((bid - 864) * 256 + tid) * 8;
        float4 f0 = *reinterpret_cast<const float4*>(x + i8);
        float4 f1 = *reinterpret_cast<const float4*>(x + i8 + 4);
        u16x8 p;
        p[0] = f2bf(f0.x); p[1] = f2bf(f0.y); p[2] = f2bf(f0.z); p[3] = f2bf(f0.w);
        p[4] = f2bf(f1.x); p[5] = f2bf(f1.y); p[6] = f2bf(f1.z); p[7] = f2bf(f1.w);
        *reinterpret_cast<u16x8*>(xb + i8) = p;
    }
}

// ---------------------------------------------------------------------------
// bf16 MFMA GEMM core, 2-phase double-buffered. BM = 2*FM*16, BN = 2*FN*16.
// mode 0: fp32 C[row*N+col] (+bias)
// mode 1: bf16 row-major cbf[row*768+col] (+bias)
// mode 2: bf16 transposed ct[((b*12+h)*64+n)*1024 + l] (+bias) via LDS
//         transpose stage -> fully coalesced 256B runs (BM==BN==128 only)
// mode 3: mode1 + mode2
// ---------------------------------------------------------------------------
template <int FM, int FN>
__device__ __forceinline__ void gemm_core(const unsigned short* __restrict__ A,
                                          const unsigned short* __restrict__ Bt,
                                          const float* __restrict__ bias,
                                          int mode,
                                          float* __restrict__ cf,
                                          unsigned short* __restrict__ cbf,
                                          unsigned short* __restrict__ ct,
                                          int N, int Kd,
                                          int bm, int bn, int tid) {
    constexpr int BM = 2 * FM * 16;
    constexpr int BN = 2 * FN * 16;
    constexpr int CTS = BM + 4;                 // padded transpose stride
    __shared__ unsigned short smem[2 * BM * 64 + 2 * BN * 64];
    unsigned short (*As)[BM * 64] = (unsigned short (*)[BM * 64])smem;
    unsigned short (*Bs)[BN * 64] = (unsigned short (*)[BN * 64])(smem + 2 * BM * 64);
    const int lane = tid & 63, wave = tid >> 6;
    const int wm = (wave >> 1) * (FM * 16), wn = (wave & 1) * (FN * 16);
    const int l15 = lane & 15, lg = lane >> 4;

    f32x4 acc[FM][FN] = {};

    auto stage = [&](int buf, int k0) {
#pragma unroll
        for (int q = 0; q < FM; ++q) {
            const int s = q * 256 + tid;
            GLD_LDS16(A + (size_t)(bm + (s >> 3)) * Kd + k0 + (s & 7) * 8,
                      &As[buf][s * 8]);
        }
#pragma unroll
        for (int q = 0; q < FN; ++q) {
            const int s = q * 256 + tid;
            GLD_LDS16(Bt + (size_t)(bn + (s >> 3)) * Kd + k0 + (s & 7) * 8,
                      &Bs[buf][s * 8]);
        }
    };

    stage(0, 0);
    __syncthreads();
    int cur = 0;
    const int nt = Kd / 64;
    for (int t = 0; t < nt; ++t) {
        if (t + 1 < nt) stage(cur ^ 1, (t + 1) * 64);
#pragma unroll
        for (int ks = 0; ks < 2; ++ks) {
            const int kb = ks * 32 + lg * 8;
            bf16x8 a[FM], b[FN];
#pragma unroll
            for (int f = 0; f < FM; ++f)
                a[f] = *reinterpret_cast<const bf16x8*>(
                    &As[cur][(wm + f * 16 + l15) * 64 + kb]);
#pragma unroll
            for (int f = 0; f < FN; ++f)
                b[f] = *reinterpret_cast<const bf16x8*>(
                    &Bs[cur][(wn + f * 16 + l15) * 64 + kb]);
#pragma unroll
            for (int fm = 0; fm < FM; ++fm)
#pragma unroll
                for (int fn = 0; fn < FN; ++fn)
                    acc[fm][fn] = __builtin_amdgcn_mfma_f32_16x16x32_bf16(
                        a[fm], b[fn], acc[fm][fn], 0, 0, 0);
        }
        __syncthreads();
        cur ^= 1;
    }

    // epilogue: direct stores for mode0/mode1; LDS-transposed pack for mode2
#pragma unroll
    for (int fm = 0; fm < FM; ++fm)
#pragma unroll
        for (int fn = 0; fn < FN; ++fn) {
            const int cl = wn + fn * 16 + l15;      // col within tile
            const int col = bn + cl;
            const float bv = bias ? bias[col] : 0.f;
            const int rl = wm + fm * 16 + lg * 4;   // row within tile
            const int r0 = bm + rl;
            f32x4 v = acc[fm][fn];
            v[0] += bv; v[1] += bv; v[2] += bv; v[3] += bv;
            if (mode == 0) {
#pragma unroll
                for (int j = 0; j < 4; ++j)
                    cf[(size_t)(r0 + j) * N + col] = v[j];
            }
            if (mode & 1) {
#pragma unroll
                for (int j = 0; j < 4; ++j)
                    cbf[(size_t)(r0 + j) * D_ + col] = f2bf(v[j]);
            }
            if (mode & 2) {
                *reinterpret_cast<ushort4*>(&smem[cl * CTS + rl]) = pack4(v);
            }
        }

    if (mode & 2) {
        __syncthreads();
        const int bI = bm >> 10, l0 = bm & 1023;
        // BN cols x BM rows, 16B (8 elems) per slot
#pragma unroll
        for (int q = 0; q < BN * BM / 8 / 256; ++q) {
            const int slot = q * 256 + tid;
            const int cl = slot / (BM / 8), seg = slot % (BM / 8);
            const int gcol = bn + cl;
            const int h = gcol >> 6, n = gcol & 63;
            *reinterpret_cast<u16x8*>(
                ct + (((size_t)bI * NH_ + h) * 64 + n) * (size_t)L_ + l0 + seg * 8) =
                *reinterpret_cast<const u16x8*>(&smem[cl * CTS + seg * 8]);
        }
    }
}

// output projection: fp32 out, 32x64 tile (768 blocks -> 3/CU, latency-bound regime)
__global__ __launch_bounds__(256) void k_gemm(const unsigned short* __restrict__ A,
                                              const unsigned short* __restrict__ Bt,
                                              const float* __restrict__ bias,
                                              float* __restrict__ C,
                                              int N, int Kd) {
    gemm_core<1, 2>(A, Bt, bias, 0, C, nullptr, nullptr, N, Kd,
                    blockIdx.y * 32, blockIdx.x * 64, threadIdx.x);
}

// 5 x-projections; z selects output format:
// z=0: u bf16 row; z=1: q bf16 row; z=2: kt transposed; z=3: v bf16 row + vt;
// z=4: g bf16 row
__global__ __launch_bounds__(256) void k_gemm5(const unsigned short* __restrict__ A,
                                               const unsigned short* __restrict__ wt,
                                               const float* __restrict__ bq,
                                               const float* __restrict__ bk,
                                               const float* __restrict__ bv,
                                               const float* __restrict__ bg,
                                               unsigned short* __restrict__ ubf,
                                               unsigned short* __restrict__ qbf,
                                               unsigned short* __restrict__ ktb,
                                               unsigned short* __restrict__ vbf,
                                               unsigned short* __restrict__ vtb,
                                               unsigned short* __restrict__ gbf) {
    const int z = blockIdx.z;
    const float* bias = nullptr;
    int mode = 1;
    unsigned short* cbf = nullptr; unsigned short* ct = nullptr;
    switch (z) {
        case 0: mode = 1; cbf = ubf; bias = nullptr; break;
        case 1: mode = 1; cbf = qbf; bias = bq; break;
        case 2: mode = 2; ct = ktb; bias = bk; break;
        case 3: mode = 3; cbf = vbf; ct = vtb; bias = bv; break;
        default: mode = 1; cbf = gbf; bias = bg; break;
    }
    const unsigned short* Bt = wt + (size_t)z * D_ * D_;
    gemm_core<4, 4>(A, Bt, bias, mode, nullptr, cbf, ct, D_, D_,
                    blockIdx.y * 128, blockIdx.x * 128, threadIdx.x);
}

// ---------------------------------------------------------------------------
// MFMA chunked linear attention (pre-gate) + phiev tail segment.
// Blocks [0,384): per (c,h,b): H = prefix V^T K (double-buffered staging);
//   St = mfma(V,Q) masked; Y = mfma(Kc,S) + mfma(H,Q); writes ya bf16.
// Blocks [384,1920): phiev[n][r] = bf16(2 * sum_k stu[2n][k]*Mf[k][r])
// ---------------------------------------------------------------------------
__global__ __launch_bounds__(256) void k_attn(const unsigned short* __restrict__ qbf,
                                              const unsigned short* __restrict__ vbf,
                                              const unsigned short* __restrict__ ktb,
                                              const unsigned short* __restrict__ vtb,
                                              unsigned short* __restrict__ yab,
                                              const float* __restrict__ F,
                                              const float* __restrict__ Mf,
                                              unsigned short* __restrict__ phiev) {
    const int tid = threadIdx.x;
    if (blockIdx.x >= 384) {
        const int idx = ((int)blockIdx.x - 384) * 256 + tid;   // over 512*768
        const int r = idx % R_;
        const int n = idx / R_;
        float acc = 0.f;
#pragma unroll
        for (int kk = 0; kk < K_; ++kk)
            acc += F[(2 * n) * K_ + kk] * Mf[kk * R_ + r];
        phiev[idx] = f2bf(2.f * acc);
        return;
    }
    const int c = blockIdx.x & 15, h = (blockIdx.x >> 4) % NH_, b = blockIdx.x / (16 * NH_);
    __shared__ unsigned short Qs[64 * 64];
    __shared__ unsigned short Vs[64 * 64];
    __shared__ unsigned short Kc[64 * 64];
    __shared__ unsigned short Tk[2][64 * 64];
    __shared__ unsigned short Tv[2][64 * 64];
    __shared__ unsigned short Sl[64 * 72];
    __shared__ unsigned short Hl[64 * 72];

    const int lane = tid & 63, wave = tid >> 6;
    const int wr = (wave >> 1) * 32, wc = (wave & 1) * 32;
    const int l15 = lane & 15, lg = lane >> 4;

    {
        const size_t rowbase = ((size_t)(b * L_ + c * CS_)) * D_ + h * HD_;
        const size_t tbase = ((size_t)(b * NH_ + h)) * 64 * (size_t)L_ + c * 64;
#pragma unroll
        for (int q2 = 0; q2 < 2; ++q2) {
            const int s = q2 * 256 + tid;
            const int row = s >> 3, c8 = s & 7;
            GLD_LDS16(qbf + rowbase + (size_t)row * D_ + c8 * 8, &Qs[s * 8]);
            GLD_LDS16(vbf + rowbase + (size_t)row * D_ + c8 * 8, &Vs[s * 8]);
            GLD_LDS16(ktb + tbase + (size_t)row * L_ + c8 * 8, &Kc[s * 8]);
        }
    }

    auto stage_t = [&](int buf, int cc) {
        const size_t tb2 = ((size_t)(b * NH_ + h)) * 64 * (size_t)L_ + cc * 64;
#pragma unroll
        for (int q2 = 0; q2 < 2; ++q2) {
            const int s = q2 * 256 + tid;
            const int row = s >> 3, c8 = s & 7;
            GLD_LDS16(ktb + tb2 + (size_t)row * L_ + c8 * 8, &Tk[buf][s * 8]);
            GLD_LDS16(vtb + tb2 + (size_t)row * L_ + c8 * 8, &Tv[buf][s * 8]);
        }
    };

    if (c > 0) stage_t(0, 0);
    __syncthreads();                 // drains Qs/Vs/Kc (+Tk/Tv[0] if staged)

    f32x4 hacc[2][2] = {};
    int cur = 0;
    for (int cc = 0; cc < c; ++cc) {
        if (cc + 1 < c) stage_t(cur ^ 1, cc + 1);   // prefetch under compute
#pragma unroll
        for (int ks = 0; ks < 2; ++ks) {
            const int kb = ks * 32 + lg * 8;
            bf16x8 av[2], bk[2];
#pragma unroll
            for (int f = 0; f < 2; ++f) {
                av[f] = *reinterpret_cast<const bf16x8*>(&Tv[cur][(wr + f * 16 + l15) * 64 + kb]);
                bk[f] = *reinterpret_cast<const bf16x8*>(&Tk[cur][(wc + f * 16 + l15) * 64 + kb]);
            }
#pragma unroll
            for (int fm = 0; fm < 2; ++fm)
#pragma unroll
                for (int fn = 0; fn < 2; ++fn)
                    hacc[fm][fn] = __builtin_amdgcn_mfma_f32_16x16x32_bf16(
                        av[fm], bk[fn], hacc[fm][fn], 0, 0, 0);
        }
        __syncthreads();             // prefetch landed
        cur ^= 1;
    }

    if (c > 0) {
#pragma unroll
        for (int fm = 0; fm < 2; ++fm)
#pragma unroll
            for (int fn = 0; fn < 2; ++fn) {
                const int n = wc + fn * 16 + l15;
                const int p0 = wr + fm * 16 + lg * 4;
                *reinterpret_cast<ushort4*>(&Hl[n * 72 + p0]) = pack4(hacc[fm][fn]);
            }
    }

    {
        f32x4 sacc[2][2] = {};
#pragma unroll
        for (int ks = 0; ks < 2; ++ks) {
            const int kb = ks * 32 + lg * 8;
            bf16x8 av[2], bq[2];
#pragma unroll
            for (int f = 0; f < 2; ++f) {
                av[f] = *reinterpret_cast<const bf16x8*>(&Vs[(wr + f * 16 + l15) * 64 + kb]);
                bq[f] = *reinterpret_cast<const bf16x8*>(&Qs[(wc + f * 16 + l15) * 64 + kb]);
            }
#pragma unroll
            for (int fm = 0; fm < 2; ++fm)
#pragma unroll
                for (int fn = 0; fn < 2; ++fn)
                    sacc[fm][fn] = __builtin_amdgcn_mfma_f32_16x16x32_bf16(
                        av[fm], bq[fn], sacc[fm][fn], 0, 0, 0);
        }
#pragma unroll
        for (int fm = 0; fm < 2; ++fm)
#pragma unroll
            for (int fn = 0; fn < 2; ++fn) {
                const int t = wc + fn * 16 + l15;
                const int s0 = wr + fm * 16 + lg * 4;
#pragma unroll
                for (int j = 0; j < 4; ++j)
                    if (s0 + j > t) sacc[fm][fn][j] = 0.f;
                *reinterpret_cast<ushort4*>(&Sl[t * 72 + s0]) = pack4(sacc[fm][fn]);
            }
    }
    __syncthreads();

    f32x4 yacc[2][2] = {};
#pragma unroll
    for (int ks = 0; ks < 2; ++ks) {
        const int kb = ks * 32 + lg * 8;
        bf16x8 ak[2], bs[2];
#pragma unroll
        for (int f = 0; f < 2; ++f) {
            ak[f] = *reinterpret_cast<const bf16x8*>(&Kc[(wr + f * 16 + l15) * 64 + kb]);
            bs[f] = *reinterpret_cast<const bf16x8*>(&Sl[(wc + f * 16 + l15) * 72 + kb]);
        }
#pragma unroll
        for (int fm = 0; fm < 2; ++fm)
#pragma unroll
            for (int fn = 0; fn < 2; ++fn)
                yacc[fm][fn] = __builtin_amdgcn_mfma_f32_16x16x32_bf16(
                    ak[fm], bs[fn], yacc[fm][fn], 0, 0, 0);
    }
    if (c > 0) {
#pragma unroll
        for (int ks = 0; ks < 2; ++ks) {
            const int kb = ks * 32 + lg * 8;
            bf16x8 ah[2], bq[2];
#pragma unroll
            for (int f = 0; f < 2; ++f) {
                ah[f] = *reinterpret_cast<const bf16x8*>(&Hl[(wr + f * 16 + l15) * 72 + kb]);
                bq[f] = *reinterpret_cast<const bf16x8*>(&Qs[(wc + f * 16 + l15) * 64 + kb]);
            }
#pragma unroll
            for (int fm = 0; fm < 2; ++fm)
#pragma unroll
                for (int fn = 0; fn < 2; ++fn)
                    yacc[fm][fn] = __builtin_amdgcn_mfma_f32_16x16x32_bf16(
                        ah[fm], bq[fn], yacc[fm][fn], 0, 0, 0);
        }
    }

#pragma unroll
    for (int fm = 0; fm < 2; ++fm)
#pragma unroll
        for (int fn = 0; fn < 2; ++fn) {
            const int n0 = wr + fm * 16 + lg * 4;
            const int t = wc + fn * 16 + l15;
            const size_t idx = ((size_t)(b * L_ + c * CS_ + t)) * D_ + h * HD_ + n0;
            *reinterpret_cast<ushort4*>(yab + idx) = pack4(yacc[fm][fn]);
        }
}

// ---------------------------------------------------------------------------
// Parity-split causal conv, bf16x8, 8-way n-split, fused gate epilogue:
// xt[2m+p,r] = sum_{n<=m} phiev[n,r]*u[2(m-n)+p,r]  (f32 acc, bf16 partials)
// gx = bf16( xt + (ya - xt) * sigmoid(g) )
// ---------------------------------------------------------------------------
__global__ __launch_bounds__(768) void k_conv(const unsigned short* __restrict__ ubf,
                                              const unsigned short* __restrict__ phiev,
                                              const unsigned short* __restrict__ yab,
                                              const unsigned short* __restrict__ gbf,
                                              unsigned short* __restrict__ gx) {
    __shared__ u16x8 red[8][8][96];             // 98304 B
    const int tid = threadIdx.x;
    const int g   = tid / 96;                   // n-split group 0..7
    const int lr  = tid % 96;                   // r8 channel group
    const int r   = lr * 8;
    const int m0  = blockIdx.x * 8;
    const int bp  = blockIdx.y;
    const int b   = bp >> 1, p = bp & 1;

    f32x8 acc[8] = {};
    f32x8 w[8]   = {};

    const int ns = g * 64;
    const int ne = min(ns + 64, m0 + 8);

    if (ns < ne) {
        if (g > 0) {
#pragma unroll
            for (int j = 1; j <= 7; ++j)
                w[(8 - j) & 7] = bf2f8(
                    *reinterpret_cast<const u16x8*>(phiev + (size_t)(ns - j) * R_ + r));
        }
        const unsigned short* pp = phiev + (size_t)ns * R_ + r;
        const unsigned short* up =
            ubf + ((size_t)(b * L_) + (size_t)(2 * (m0 + 7 - ns) + p)) * R_ + r;
        for (int i = ns; i < ne; i += 8) {
#pragma unroll
            for (int k = 0; k < 8; ++k) {
                const u16x8 pv = *reinterpret_cast<const u16x8*>(pp);
                const u16x8 uv = *reinterpret_cast<const u16x8*>(up);
                w[k] = bf2f8(pv);
                const f32x8 fu = bf2f8(uv);
#pragma unroll
                for (int a = 0; a < 8; ++a)
                    acc[a] += w[(k + a + 1) & 7] * fu;
                pp += R_;
                up -= 2 * R_;
            }
        }
    }

#pragma unroll
    for (int a = 0; a < 8; ++a) red[g][a][lr] = pack8(acc[a]);
    __syncthreads();

    const int a2 = tid / 96, l2 = tid % 96;
    f32x8 s = {};
#pragma unroll
    for (int g2 = 0; g2 < 8; ++g2) s += bf2f8(red[g2][a2][l2]);

    const size_t idx = ((size_t)(b * L_) + (size_t)(2 * (m0 + a2) + p)) * R_ + l2 * 8;
    const f32x8 yf = bf2f8(*reinterpret_cast<const u16x8*>(yab + idx));
    const f32x8 gf = bf2f8(*reinterpret_cast<const u16x8*>(gbf + idx));
    u16x8 o;
#pragma unroll
    for (int e = 0; e < 8; ++e) {
        const float sg = 1.f / (1.f + expf(-gf[e]));
        o[e] = f2bf(s[e] + (yf[e] - s[e]) * sg);
    }
    *reinterpret_cast<u16x8*>(gx + idx) = o;
}

// ---------------------------------------------------------------------------
extern "C" void kernel_launch(void* const* d_in, const int* in_sizes, int n_in,
                              void* d_out, int out_size, void* d_ws, size_t ws_size,
                              hipStream_t stream) {
    const float* x    = (const float*)d_in[0];
    const float* stu  = (const float*)d_in[1];
    const float* Mi   = (const float*)d_in[2];
    const float* Mf   = (const float*)d_in[3];
    const float* wq_w = (const float*)d_in[4];
    const float* wq_b = (const float*)d_in[5];
    const float* wk_w = (const float*)d_in[6];
    const float* wk_b = (const float*)d_in[7];
    const float* wv_w = (const float*)d_in[8];
    const float* wv_b = (const float*)d_in[9];
    const float* wg_w = (const float*)d_in[10];
    const float* wg_b = (const float*)d_in[11];
    const float* wo_w = (const float*)d_in[12];
    const float* wo_b = (const float*)d_in[13];
    float* out = (float*)d_out;

    char* ws = (char*)d_ws;
    size_t o = 0;
    const size_t WSZ = (size_t)D_ * D_;
    unsigned short* wbf   = (unsigned short*)(ws + o); o += 6 * WSZ * 2;
    unsigned short* xbf   = (unsigned short*)(ws + o); o += (size_t)B_ * L_ * D_ * 2;
    unsigned short* gx    = (unsigned short*)(ws + o); o += (size_t)B_ * L_ * D_ * 2;
    unsigned short* qbf   = (unsigned short*)(ws + o); o += (size_t)B_ * L_ * D_ * 2;
    unsigned short* vbf   = (unsigned short*)(ws + o); o += (size_t)B_ * L_ * D_ * 2;
    unsigned short* ubf   = (unsigned short*)(ws + o); o += (size_t)B_ * L_ * D_ * 2;
    unsigned short* gbf   = (unsigned short*)(ws + o); o += (size_t)B_ * L_ * D_ * 2;
    unsigned short* yab   = (unsigned short*)(ws + o); o += (size_t)B_ * L_ * D_ * 2;
    unsigned short* ktb   = (unsigned short*)(ws + o); o += (size_t)B_ * NH_ * 64 * L_ * 2;
    unsigned short* vtb   = (unsigned short*)(ws + o); o += (size_t)B_ * NH_ * 64 * L_ * 2;
    unsigned short* phiev = (unsigned short*)(ws + o); o += (size_t)(L_ / 2) * R_ * 2;

    unsigned short* wo_t = wbf + 5 * WSZ;

    const dim3 blk(256);

    k_prep<<<dim3(1632), blk, 0, stream>>>(Mi, wq_w, wk_w, wv_w, wg_w, wo_w, wbf,
                                           x, xbf);

    k_gemm5<<<dim3(D_ / 128, (B_ * L_) / 128, 5), blk, 0, stream>>>(
        xbf, wbf, wq_b, wk_b, wv_b, wg_b, ubf, qbf, ktb, vbf, vtb, gbf);

    k_attn<<<dim3(384 + 1536), blk, 0, stream>>>(qbf, vbf, ktb, vtb, yab,
                                                 stu, Mf, phiev);

    k_conv<<<dim3(L_ / 2 / 8, B_ * 2), dim3(768), 0, stream>>>(ubf, phiev, yab, gbf, gx);

    k_gemm<<<dim3(D_ / 64, (B_ * L_) / 32), blk, 0, stream>>>(gx, wo_t, wo_b, out, D_, D_);
}